// Round 2
// baseline (1246.396 us; speedup 1.0000x reference)
//
#include <hip/hip_runtime.h>
#include <hip/hip_cooperative_groups.h>
#include <stdint.h>

namespace cg = cooperative_groups;

#define TT   12
#define BB   2
#define NN   1024
#define MM   2048
#define TM   24576      // TT*MM
#define DIN  64
#define DH   128
#define DOUT 32
#define CAP  64
#define OUTSZ 786432
#define KS   4          // split-K factor for attention
#define PWB  324        // prepw blocks inside merged prep_edges kernel (fallback path)
#define GRID 768        // cooperative grid: 3 blocks/CU x 256 CUs

typedef __attribute__((ext_vector_type(8))) short short8;
typedef __attribute__((ext_vector_type(4))) short short4v;
typedef __attribute__((ext_vector_type(4))) float f32x4;

#define MFMA(a,b,c) __builtin_amdgcn_mfma_f32_16x16x32_bf16((a),(b),(c),0,0,0)

__device__ __forceinline__ float bf2f(unsigned short u){
  union { uint32_t i; float f; } x; x.i = ((uint32_t)u) << 16; return x.f;
}
__device__ __forceinline__ unsigned short f2bf(float f){
  union { float f; uint32_t i; } x; x.f = f;
  uint32_t u = x.i + 0x7FFFu + ((x.i >> 16) & 1u);   // RNE
  return (unsigned short)(u >> 16);
}
__device__ __forceinline__ float LD(const void* p, size_t i, int mode){
  return mode ? ((const float*)p)[i] : bf2f(((const unsigned short*)p)[i]);
}
// gather-load 8 input elements as bf16 (mode 1 = fp32 source)
__device__ __forceinline__ short8 ldx8(const void* x, size_t off, int md){
  if(md){
    const float4* xf = (const float4*)((const float*)x + off);
    float4 a = xf[0], b = xf[1];
    short8 o;
    o[0]=(short)f2bf(a.x); o[1]=(short)f2bf(a.y); o[2]=(short)f2bf(a.z); o[3]=(short)f2bf(a.w);
    o[4]=(short)f2bf(b.x); o[5]=(short)f2bf(b.y); o[6]=(short)f2bf(b.z); o[7]=(short)f2bf(b.w);
    return o;
  }
  return *(const short8*)((const unsigned short*)x + off);
}

// ================= shared per-item / per-tile device bodies =================

__device__ __forceinline__ void dev_mask_item(int idx, int mode, int lane,
    const void* egom, int* cnt, int* nact, int* aidx, int* inv){
  int t = idx / MM, node = idx % MM;               // wave = 64 consecutive nodes, one t
  int b = node / NN, n = node % NN;
  int src = (b*TT + t)*NN + n;
  int v;
  if(mode==0)      v = ((const int*)egom)[src] != 0;
  else if(mode==1) v = ((const unsigned char*)egom)[src] != 0;
  else if(mode==2) v = ((const unsigned short*)egom)[src] != 0;
  else if(mode==3) v = ((const float*)egom)[src] != 0.f;
  else if(mode==4) v = ((const long long*)egom)[src] != 0;
  else             v = ((const double*)egom)[src] != 0.0;
  cnt[idx] = 0;
  unsigned long long bal = __ballot(v != 0);
  int base = 0;
  if(lane == 0 && bal) base = atomicAdd(&nact[t], __popcll(bal));
  base = __shfl(base, 0, 64);
  int ic = -1;
  if(v){
    int pfx = __popcll(bal & ((1ULL << lane) - 1ULL));
    ic = base + pfx;
    aidx[(size_t)t*MM + ic] = node;
  }
  inv[idx] = ic;
}

__device__ __forceinline__ void dev_prepw_item(int id, int md,
  const void* w1, const void* w2,
  const void* qw, const void* kw, const void* vw,
  const void* qb0, const void* kb0, const void* vb0,
  const void* ow, const void* ob, const void* fw, const void* fb,
  const void* tw, const void* tb, const void* b1, const void* b2,
  unsigned short* W1t, unsigned short* W2t,
  unsigned short* Wqt, unsigned short* Wkt,
  unsigned short* Wvt, unsigned short* Wct,
  float* qbf, float* kbf, float* vbf,
  float* bcf, float* b1f, float* b2f)
{
  if(id < 8192){  // coalesced read: consecutive id -> consecutive n
    int n=id&127, k2=id>>7; W1t[n*64+k2]=f2bf(LD(w1,(size_t)k2*128+n,md)); return; }
  id -= 8192;
  if(id < 16384){ int n=id&127,k2=id>>7; W2t[n*128+k2]=f2bf(LD(w2,(size_t)k2*128+n,md)); return; }
  id -= 16384;
  if(id < 16384){ int n=id&127,k2=id>>7; Wqt[n*128+k2]=f2bf(LD(qw,(size_t)k2*128+n,md)); return; }
  id -= 16384;
  if(id < 16384){ int n=id&127,k2=id>>7; Wkt[n*128+k2]=f2bf(LD(kw,(size_t)k2*128+n,md)); return; }
  id -= 16384;
  if(id < 16384){ int n=id&127,k2=id>>7; Wvt[n*128+k2]=f2bf(LD(vw,(size_t)k2*128+n,md)); return; }
  id -= 16384;
  if(id < 4096){  // Wc = o_w @ fc_w, stored [oc][c]
    int oc=id&31, c=id>>5; float s=0.f;
    for(int r=0;r<128;r++) s += LD(ow,(size_t)c*128+r,md)*LD(fw,(size_t)r*32+oc,md);
    Wct[oc*128+c]=f2bf(s); return;
  }
  id -= 4096;
  if(id < 32){    // bc = o_b @ fc_w + fc_b
    float s = LD(fb,id,md);
    for(int r=0;r<128;r++) s += LD(ob,r,md)*LD(fw,(size_t)r*32+id,md);
    bcf[id]=s; return;
  }
  id -= 32;
  if(id < 4608){  // per-t fused QKV bias: b + t_vec @ W[128:144]
    int which = id/1536, rem=id%1536, t=rem/128, n=rem%128;
    const void* W  = which==0?qw:(which==1?kw:vw);
    const void* Bs = which==0?qb0:(which==1?kb0:vb0);
    float s = LD(Bs,n,md);
    for(int d=0;d<16;d++){
      float tv = sinf((float)t*LD(tw,d,md) + LD(tb,d,md));
      s += tv * LD(W,(size_t)(128+d)*128+n,md);
    }
    float* dst = which==0?qbf:(which==1?kbf:vbf);
    dst[t*128+n]=s; return;
  }
  id -= 4608;
  if(id < 256){   // GCN biases to fp32
    if(id<128) b1f[id] = LD(b1,id,md);
    else       b2f[id-128] = LD(b2,id-128,md);
    return;
  }
}

__device__ __forceinline__ void dev_edges_item(int id, int md,
    const void* A, const int* inv, int* cnt, int* edges){
  int seg = id & 63; int row = id >> 6;           // row = t*MM + j (orig)
  int t = row / MM;
  int jc = inv[row];
  if(jc < 0) return;                              // inactive source
  const int* invt = inv + (size_t)t*MM;
  int* cb = cnt + (size_t)t*MM;
  int* eb = edges + (size_t)t*MM*CAP;
  if(md){   // fp32 adjacency
    const float4* p4 = (const float4*)((const float*)A + (size_t)row*MM + seg*32);
    #pragma unroll
    for(int u=0;u<8;u++){
      float4 v = p4[u];
      float wd[4]={v.x,v.y,v.z,v.w};
      #pragma unroll
      for(int q=0;q<4;q++){
        if(wd[q]!=0.f){
          int ibc = invt[seg*32 + u*4 + q];
          if(ibc >= 0){ int s=atomicAdd(&cb[ibc],1); if(s<CAP) eb[(size_t)ibc*CAP+s]=jc; }
        }
      }
    }
  } else {    // bf16 adjacency
    const uint4* p4 = (const uint4*)((const unsigned short*)A + (size_t)row*MM + seg*32);
    #pragma unroll
    for(int u=0;u<4;u++){
      uint4 v = p4[u];
      unsigned wd[4]={v.x,v.y,v.z,v.w};
      #pragma unroll
      for(int q=0;q<4;q++){
        int ib = seg*32 + u*8 + q*2;
        if(wd[q] & 0xFFFFu){
          int ibc = invt[ib];
          if(ibc >= 0){ int s=atomicAdd(&cb[ibc],1); if(s<CAP) eb[(size_t)ibc*CAP+s]=jc; }
        }
        if(wd[q] >> 16){
          int ibc = invt[ib+1];
          if(ibc >= 0){ int s=atomicAdd(&cb[ibc],1); if(s<CAP) eb[(size_t)ibc*CAP+s]=jc; }
        }
      }
    }
  }
}

__device__ __forceinline__ void dev_gemm_x_tile(int tileIdx, int md, int tid,
    const void* x, const int* nact, const int* aidx,
    const unsigned short* Wt, float* g)
{
  const int tile = tileIdx*64;
  const int t = tile / MM, il = tile % MM;
  const int na = nact[t];
  if(il >= ((na+63)&~63)) return;
  const int wv=tid>>6, lane=tid&63, l15=lane&15, quad=lane>>4;
  const int r0 = tile + (wv>>1)*32;          // global compact row base
  const int c0 = (wv&1)*64;
  short8 bf[2][4];
  #pragma unroll
  for(int kk=0;kk<2;kk++)
    #pragma unroll
    for(int nt=0;nt<4;nt++)
      bf[kk][nt] = *(const short8*)(Wt + (size_t)(c0+nt*16+l15)*DIN + kk*32 + quad*8);
  const int il0 = (r0 % MM) + l15, il1 = (r0 % MM) + 16 + l15;
  const int n0 = aidx[(size_t)t*MM + (il0 < na ? il0 : 0)];
  const int n1 = aidx[(size_t)t*MM + (il1 < na ? il1 : 0)];
  const size_t xb0 = ((size_t)t*MM + n0)*DIN;
  const size_t xb1 = ((size_t)t*MM + n1)*DIN;
  f32x4 z = {0.f,0.f,0.f,0.f};
  f32x4 acc[2][4];
  #pragma unroll
  for(int i=0;i<2;i++){ acc[i][0]=z; acc[i][1]=z; acc[i][2]=z; acc[i][3]=z; }
  #pragma unroll
  for(int kk=0;kk<2;kk++){
    short8 a0 = ldx8(x, xb0 + kk*32 + quad*8, md);
    short8 a1 = ldx8(x, xb1 + kk*32 + quad*8, md);
    #pragma unroll
    for(int nt=0;nt<4;nt++){
      acc[0][nt]=MFMA(a0,bf[kk][nt],acc[0][nt]);
      acc[1][nt]=MFMA(a1,bf[kk][nt],acc[1][nt]);
    }
  }
  #pragma unroll
  for(int mt=0;mt<2;mt++)
    #pragma unroll
    for(int nt=0;nt<4;nt++){
      int col = c0+nt*16+l15;
      #pragma unroll
      for(int r=0;r<4;r++){
        int row = r0 + mt*16 + quad*4 + r;
        g[(size_t)row*DH + col] = acc[mt][nt][r];
      }
    }
}

__device__ __forceinline__ void dev_gemm_h_tile(int tileIdx, int tid,
    const unsigned short* X, const unsigned short* Wt, float* g, const int* nact)
{
  const int tile = tileIdx*64;
  const int t = tile / MM, il = tile % MM;
  const int na = nact[t];
  if(il >= ((na+63)&~63)) return;
  const int wv=tid>>6, lane=tid&63, l15=lane&15, quad=lane>>4;
  const int r0 = tile + (wv>>1)*32;
  const int c0 = (wv&1)*64;
  short8 bf[4][4];
  #pragma unroll
  for(int kk=0;kk<4;kk++)
    #pragma unroll
    for(int nt=0;nt<4;nt++)
      bf[kk][nt] = *(const short8*)(Wt + (size_t)(c0+nt*16+l15)*DH + kk*32 + quad*8);
  f32x4 z = {0.f,0.f,0.f,0.f};
  f32x4 acc[2][4];
  #pragma unroll
  for(int i=0;i<2;i++){ acc[i][0]=z; acc[i][1]=z; acc[i][2]=z; acc[i][3]=z; }
  #pragma unroll
  for(int kk=0;kk<4;kk++){
    short8 a0 = *(const short8*)(X + (size_t)(r0+l15)*DH    + kk*32 + quad*8);
    short8 a1 = *(const short8*)(X + (size_t)(r0+16+l15)*DH + kk*32 + quad*8);
    #pragma unroll
    for(int nt=0;nt<4;nt++){
      acc[0][nt]=MFMA(a0,bf[kk][nt],acc[0][nt]);
      acc[1][nt]=MFMA(a1,bf[kk][nt],acc[1][nt]);
    }
  }
  #pragma unroll
  for(int mt=0;mt<2;mt++)
    #pragma unroll
    for(int nt=0;nt<4;nt++){
      int col = c0+nt*16+l15;
      #pragma unroll
      for(int r=0;r<4;r++){
        int row = r0 + mt*16 + quad*4 + r;
        g[(size_t)row*DH + col] = acc[mt][nt][r];
      }
    }
}

__device__ __forceinline__ void dev_gather_task(int gi, int lane,
    const float* g, const int* edges, const int* cnt,
    const int* nact, const float* bias, unsigned short* h)
{
  int t = gi / MM, ic = gi % MM;
  int na = nact[t];
  if(ic >= ((na+63)&~63)) return;
  unsigned int* hp = (unsigned int*)(h + (size_t)gi*DH) + lane;
  if(ic >= na){ *hp = 0; return; }      // pad row: finite zeros
  float a0=0.f, a1=0.f;
  int cn = cnt[gi]; if(cn>CAP) cn=CAP;
  const int* eb = edges + (size_t)gi*CAP;
  #pragma unroll 2
  for(int e=0;e<cn;e++){
    int jc = eb[e];
    float nj = rsqrtf((float)cnt[(size_t)t*MM+jc] + 1.f);
    float2 gr2 = *(const float2*)(g + ((size_t)t*MM + jc)*DH + 2*lane);
    a0 += nj*gr2.x; a1 += nj*gr2.y;
  }
  float ni = rsqrtf((float)cn + 1.f);
  float2 gs2 = *(const float2*)(g + (size_t)gi*DH + 2*lane);
  float h0 = ni*(a0 + ni*gs2.x) + bias[2*lane];
  float h1 = ni*(a1 + ni*gs2.y) + bias[2*lane+1];
  h0 = h0>0.f?h0:0.f; h1 = h1>0.f?h1:0.f;
  *hp = (unsigned int)f2bf(h0) | ((unsigned int)f2bf(h1) << 16);
}

__device__ __forceinline__ void dev_qkv_tile(int tileIdx, int which, int tid,
    const unsigned short* X,
    const unsigned short* Wq, const unsigned short* Wk, const unsigned short* Wv,
    const float* qb, const float* kb, const float* vb,
    unsigned short* Qo, unsigned short* Ko, unsigned short* Vtc, const int* nact)
{
  const int tile = tileIdx*64;
  const int t = tile / MM, il = tile % MM;
  const int na = nact[t];
  if(il >= ((na+63)&~63)) return;
  const unsigned short* Wt = which==0?Wq:(which==1?Wk:Wv);
  const float* bias = which==0?qb:(which==1?kb:vb);
  const int wv=tid>>6, lane=tid&63, l15=lane&15, quad=lane>>4;
  const int r0 = tile + (wv>>1)*32;
  const int c0 = (wv&1)*64;
  short8 bf[4][4];
  #pragma unroll
  for(int kk=0;kk<4;kk++)
    #pragma unroll
    for(int nt=0;nt<4;nt++)
      bf[kk][nt] = *(const short8*)(Wt + (size_t)(c0+nt*16+l15)*DH + kk*32 + quad*8);
  f32x4 z = {0.f,0.f,0.f,0.f};
  f32x4 acc[2][4];
  #pragma unroll
  for(int i=0;i<2;i++){ acc[i][0]=z; acc[i][1]=z; acc[i][2]=z; acc[i][3]=z; }
  #pragma unroll
  for(int kk=0;kk<4;kk++){
    short8 a0 = *(const short8*)(X + (size_t)(r0+l15)*DH    + kk*32 + quad*8);
    short8 a1 = *(const short8*)(X + (size_t)(r0+16+l15)*DH + kk*32 + quad*8);
    #pragma unroll
    for(int nt=0;nt<4;nt++){
      acc[0][nt]=MFMA(a0,bf[kk][nt],acc[0][nt]);
      acc[1][nt]=MFMA(a1,bf[kk][nt],acc[1][nt]);
    }
  }
  if(which < 2){
    unsigned short* o = which==0 ? Qo : Ko;
    #pragma unroll
    for(int mt=0;mt<2;mt++)
      #pragma unroll
      for(int nt=0;nt<4;nt++){
        int col = c0+nt*16+l15;
        float bb = bias[t*DH+col];
        #pragma unroll
        for(int r=0;r<4;r++){
          int row = r0 + mt*16 + quad*4 + r;
          o[(size_t)row*DH + col] = f2bf(acc[mt][nt][r] + bb);
        }
      }
  } else {
    #pragma unroll
    for(int mt=0;mt<2;mt++)
      #pragma unroll
      for(int nt=0;nt<4;nt++){
        int col = c0+nt*16+l15;
        float bb = bias[t*DH+col];
        int node0 = il + (wv>>1)*32 + mt*16 + quad*4;   // compact local row
        short4v pk;
        #pragma unroll
        for(int r=0;r<4;r++) pk[r] = (short)f2bf(acc[mt][nt][r] + bb);
        *(short4v*)(Vtc + ((size_t)t*DH + col)*MM + node0) = pk;
      }
  }
}

// LDS layout (45056 B): Kl[64][136]us @0 (17408) | Vl[128][72]us @17408 (18432)
//                       | Pl[4][16][72]s @35840 (9216).  Al[4][16][136]s overlays @0.
__device__ __forceinline__ void dev_attn_part_task(int qx, int t, int s, int tid,
  unsigned char* smem,
  const unsigned short* Q, const unsigned short* Kc, const unsigned short* Vtc,
  const int* nact, float* pacc, float* plr)
{
  unsigned short (*Kl)[136] = (unsigned short(*)[136])smem;
  unsigned short (*Vl)[72]  = (unsigned short(*)[72])(smem + 17408);
  short (*Pl)[16][72]       = (short(*)[16][72])(smem + 35840);
  const int wv=tid>>6, lane=tid&63, l15=lane&15, quad=lane>>4;
  const int na = nact[t];
  const int qblk = qx*64;
  if(qblk >= na) return;                 // block-uniform (before any barrier)
  const int qbase = qblk + wv*16;
  const float scale = 0.088388347648318447f;  // 1/sqrt(128)
  const int nkt = (na + 63) >> 6;

  short8 bq[4];
  #pragma unroll
  for(int kk=0;kk<4;kk++)
    bq[kk] = *(const short8*)(Q + ((size_t)t*MM + qbase + l15)*DH + kk*32 + quad*8);

  f32x4 zz = {0.f,0.f,0.f,0.f};
  f32x4 accPV[8];
  #pragma unroll
  for(int i=0;i<8;i++) accPV[i]=zz;
  float l_run = 0.f;

  const int srow = tid >> 2, sseg = tid & 3;   // K stage: 64 rows x 4 segs
  const int vch  = tid >> 1, vhalf = tid & 1;  // V stage: 128 ch x 2 halves

  short8 kreg[4], vreg[4];
  if(s < nkt){  // preload this split's first tile
    const unsigned short* gk = Kc + ((size_t)t*MM + s*64 + srow)*DH + sseg*32;
    const unsigned short* gv = Vtc + ((size_t)t*DH + vch)*MM + s*64 + vhalf*32;
    #pragma unroll
    for(int j=0;j<4;j++){ kreg[j] = *(const short8*)(gk + j*8);
                          vreg[j] = *(const short8*)(gv + j*8); }
  }

  for(int kt=s; kt<nkt; kt+=KS){
    const int key0 = kt*64;
    __syncthreads();   // previous tile fully consumed before restage
    {  // write prefetched registers to LDS
      short8* kd = (short8*)&Kl[srow][sseg*32];
      short8* vd = (short8*)&Vl[vch][vhalf*32];
      #pragma unroll
      for(int j=0;j<4;j++){ kd[j] = kreg[j]; vd[j] = vreg[j]; }
    }
    __syncthreads();
    if(kt+KS < nkt){   // issue next tile's global loads; overlap compute below
      const int key1 = key0 + KS*64;
      const unsigned short* gk = Kc + ((size_t)t*MM + key1 + srow)*DH + sseg*32;
      const unsigned short* gv = Vtc + ((size_t)t*DH + vch)*MM + key1 + vhalf*32;
      #pragma unroll
      for(int j=0;j<4;j++){ kreg[j] = *(const short8*)(gk + j*8);
                            vreg[j] = *(const short8*)(gv + j*8); }
    }
    // S^T = K · Q^T from LDS
    #pragma unroll
    for(int mt=0;mt<4;mt++){
      f32x4 sv4 = zz;
      #pragma unroll
      for(int kk=0;kk<4;kk++){
        short8 ak = *(const short8*)&Kl[mt*16+l15][kk*32 + quad*8];
        sv4 = MFMA(ak, bq[kk], sv4);
      }
      short4v pk;
      #pragma unroll
      for(int r=0;r<4;r++){
        float sv = fminf(fmaxf(sv4[r]*scale, -15.f), 15.f);
        float valid = (key0 + mt*16 + quad*4 + r < na) ? 1.f : 0.f;
        float p = __expf(sv) * valid;
        pk[r] = (short)f2bf(p);
        l_run += bf2f((unsigned short)pk[r]);
      }
      *(short4v*)&Pl[wv][l15][mt*16 + quad*4] = pk;
    }
    // PV from LDS
    #pragma unroll
    for(int kk=0;kk<2;kk++){
      short8 ap = *(const short8*)&Pl[wv][l15][kk*32 + quad*8];
      #pragma unroll
      for(int nt=0;nt<8;nt++){
        short8 bv = *(const short8*)&Vl[nt*16+l15][kk*32 + quad*8];
        accPV[nt] = MFMA(ap, bv, accPV[nt]);
      }
    }
  }
  // dump raw per-lane partials (coalesced, layout-agnostic)
  float* pb = pacc + ((((size_t)s*TT + t)*32 + qx)*256 + tid)*32;
  #pragma unroll
  for(int i=0;i<8;i++) *(f32x4*)(pb + i*4) = accPV[i];
  plr[(((size_t)s*TT + t)*32 + qx)*256 + tid] = l_run;
}

__device__ __forceinline__ void dev_attn_fin_task(int qx, int t, int tid,
  unsigned char* smem,
  const float* pacc, const float* plr,
  const int* nact, const int* aidx,
  const unsigned short* Wct, const float* bc, float* out)
{
  short (*Al)[16][136] = (short(*)[16][136])smem;   // per-wave slice, wave-private
  const int wv=tid>>6, lane=tid&63, l15=lane&15, quad=lane>>4;
  const int na = nact[t];
  const int qblk = qx*64;
  if(qblk >= na) return;
  const int qbase = qblk + wv*16;

  f32x4 zz = {0.f,0.f,0.f,0.f};
  f32x4 acc[8];
  #pragma unroll
  for(int i=0;i<8;i++) acc[i]=zz;
  float l_run = 0.f;
  #pragma unroll
  for(int s=0;s<KS;s++){
    const f32x4* p = (const f32x4*)(pacc + ((((size_t)s*TT + t)*32 + qx)*256 + tid)*32);
    #pragma unroll
    for(int i=0;i<8;i++) acc[i] += p[i];
    l_run += plr[(((size_t)s*TT + t)*32 + qx)*256 + tid];
  }
  l_run += __shfl_xor(l_run, 16, 64);
  l_run += __shfl_xor(l_run, 32, 64);

  #pragma unroll
  for(int nt=0;nt<8;nt++)
    #pragma unroll
    for(int r=0;r<4;r++){
      float av = fminf(fmaxf(acc[nt][r], -1e30f), 1e30f);
      Al[wv][quad*4+r][nt*16+l15] = (short)f2bf(av);
    }

  const int qc = qbase + l15;
  const bool qok = (qc < na);
  const float linv = (l_run > 0.f) ? 1.f/l_run : 0.f;
  const int node = aidx[(size_t)t*MM + (qok ? qc : 0)];
  #pragma unroll
  for(int mt2=0;mt2<2;mt2++){
    f32x4 d = zz;
    #pragma unroll
    for(int kk=0;kk<4;kk++){
      short8 aw = *(const short8*)(Wct + (size_t)(mt2*16+l15)*DH + kk*32 + quad*8);
      short8 bl = *(const short8*)&Al[wv][l15][kk*32 + quad*8];
      d = MFMA(aw, bl, d);
    }
    f32x4 bcv = *(const f32x4*)(bc + mt2*16 + quad*4);
    f32x4 o4;
    #pragma unroll
    for(int r=0;r<4;r++) o4[r] = d[r]*linv + bcv[r];
    if(qok)
      *(f32x4*)(out + (size_t)node*(TT*DOUT) + (size_t)t*DOUT + mt2*16 + quad*4) = o4;
  }
}

// ================= standalone kernels (fallback path) =================

__global__ void k_fill(float* __restrict__ out, int n, float val){
  int i = blockIdx.x*blockDim.x + threadIdx.x;
  if(i < n) out[i] = val;
}

__global__ void k_detect2(const unsigned short* __restrict__ x,
                          const unsigned char* __restrict__ eg,
                          int* __restrict__ dtf, int* __restrict__ flag,
                          int* __restrict__ nact){
  if(blockIdx.x == 0){
    __shared__ int cnt_s;
    if(threadIdx.x==0) cnt_s = 0;
    if(threadIdx.x < TT) nact[threadIdx.x] = 0;
    __syncthreads();
    int c = 0;
    for(int i=threadIdx.x; i<6144; i+=blockDim.x){
      unsigned short h = x[i*2];
      unsigned e = (h >> 7) & 0xFF;
      if(h==0 || (e >= 0x60 && e <= 0x9F)) c++;
    }
    atomicAdd(&cnt_s, c);
    __syncthreads();
    if(threadIdx.x==0) *dtf = (cnt_s > 4000) ? 0 : 1;   // 0=bf16, 1=fp32
  } else {
    __shared__ int pres_s, ge2_s;
    if(threadIdx.x==0){ pres_s=0; ge2_s=0; }
    __syncthreads();
    int pres=0, ge2=0;
    for(int i=threadIdx.x; i<24576; i+=blockDim.x){
      unsigned v = eg[i];
      if(v){ pres |= 1 << (i & 7); if(v >= 2u) ge2 = 1; }
    }
    if(pres) atomicOr(&pres_s, pres);
    if(ge2)  atomicOr(&ge2_s, 1);
    __syncthreads();
    if(threadIdx.x==0){
      int pr = pres_s, g2 = ge2_s, mode;
      if(!g2){
        if((pr & ~0x01) == 0)      mode = 4;   // i64
        else if((pr & ~0x11) == 0) mode = 0;   // i32
        else                       mode = 1;   // u8
      } else {
        if((pr & ~0xC0) == 0)      mode = 5;   // f64
        else if((pr & ~0xCC) == 0) mode = 3;   // f32
        else                       mode = 2;   // bf16
      }
      *flag = mode;
    }
  }
}

__global__ void k_mask(const void* __restrict__ egom, const int* __restrict__ flag,
                       int* __restrict__ cnt, int* __restrict__ nact,
                       int* __restrict__ aidx, int* __restrict__ inv,
                       float* __restrict__ out){
  int idx = blockIdx.x*blockDim.x + threadIdx.x;   // < OUTSZ
  out[idx] = 0.f;
  if(idx >= TM) return;
  dev_mask_item(idx, *flag, threadIdx.x & 63, egom, cnt, nact, aidx, inv);
}

__global__ __launch_bounds__(256) void k_prep_edges(
  const void* __restrict__ w1, const void* __restrict__ w2,
  const void* __restrict__ qw, const void* __restrict__ kw, const void* __restrict__ vw,
  const void* __restrict__ qb0, const void* __restrict__ kb0, const void* __restrict__ vb0,
  const void* __restrict__ ow, const void* __restrict__ ob,
  const void* __restrict__ fw, const void* __restrict__ fb,
  const void* __restrict__ tw, const void* __restrict__ tb,
  const void* __restrict__ b1, const void* __restrict__ b2,
  const int* __restrict__ dtf,
  unsigned short* __restrict__ W1t, unsigned short* __restrict__ W2t,
  unsigned short* __restrict__ Wqt, unsigned short* __restrict__ Wkt,
  unsigned short* __restrict__ Wvt, unsigned short* __restrict__ Wct,
  float* __restrict__ qbf, float* __restrict__ kbf, float* __restrict__ vbf,
  float* __restrict__ bcf, float* __restrict__ b1f, float* __restrict__ b2f,
  const void* __restrict__ A, const int* __restrict__ inv,
  int* __restrict__ cnt, int* __restrict__ edges)
{
  const int md = *dtf;
  if(blockIdx.x < PWB){
    int id = blockIdx.x*blockDim.x + threadIdx.x;
    dev_prepw_item(id, md, w1,w2,qw,kw,vw,qb0,kb0,vb0,ow,ob,fw,fb,tw,tb,b1,b2,
                   W1t,W2t,Wqt,Wkt,Wvt,Wct,qbf,kbf,vbf,bcf,b1f,b2f);
  } else {
    int id = (blockIdx.x - PWB)*blockDim.x + threadIdx.x;
    dev_edges_item(id, md, A, inv, cnt, edges);
  }
}

__global__ __launch_bounds__(256) void k_gemm_x(const void* __restrict__ x,
    const int* __restrict__ dtf, const int* __restrict__ nact,
    const int* __restrict__ aidx, const unsigned short* __restrict__ Wt,
    float* __restrict__ g)
{
  dev_gemm_x_tile(blockIdx.x, *dtf, threadIdx.x, x, nact, aidx, Wt, g);
}

__global__ __launch_bounds__(256) void k_gemm_h(const unsigned short* __restrict__ X,
    const unsigned short* __restrict__ Wt, float* __restrict__ g,
    const int* __restrict__ nact)
{
  dev_gemm_h_tile(blockIdx.x, threadIdx.x, X, Wt, g, nact);
}

__global__ __launch_bounds__(256) void k_gather(const float* __restrict__ g,
    const int* __restrict__ edges, const int* __restrict__ cnt,
    const int* __restrict__ nact, const float* __restrict__ bias,
    unsigned short* __restrict__ h)
{
  int wv = threadIdx.x>>6, lane = threadIdx.x&63;
  dev_gather_task(blockIdx.x*4 + wv, lane, g, edges, cnt, nact, bias, h);
}

__global__ __launch_bounds__(256) void k_gemm_qkv(const unsigned short* __restrict__ X,
    const unsigned short* __restrict__ Wq, const unsigned short* __restrict__ Wk,
    const unsigned short* __restrict__ Wv,
    const float* __restrict__ qb, const float* __restrict__ kb, const float* __restrict__ vb,
    unsigned short* __restrict__ Qo, unsigned short* __restrict__ Ko,
    unsigned short* __restrict__ Vtc, const int* __restrict__ nact)
{
  dev_qkv_tile(blockIdx.x, blockIdx.z, threadIdx.x, X, Wq,Wk,Wv, qb,kb,vb, Qo,Ko,Vtc, nact);
}

__global__ __launch_bounds__(256) void k_attn_part(
  const unsigned short* __restrict__ Q, const unsigned short* __restrict__ Kc,
  const unsigned short* __restrict__ Vtc, const int* __restrict__ nact,
  float* __restrict__ pacc, float* __restrict__ plr)
{
  __shared__ alignas(16) unsigned char smem[45056];
  dev_attn_part_task(blockIdx.x, blockIdx.y, blockIdx.z, threadIdx.x, smem,
                     Q, Kc, Vtc, nact, pacc, plr);
}

__global__ __launch_bounds__(256) void k_attn_fin(
  const float* __restrict__ pacc, const float* __restrict__ plr,
  const int* __restrict__ nact, const int* __restrict__ aidx,
  const unsigned short* __restrict__ Wct, const float* __restrict__ bc,
  float* __restrict__ out)
{
  __shared__ alignas(16) unsigned char smem[17408];
  dev_attn_fin_task(blockIdx.x, blockIdx.y, threadIdx.x, smem,
                    pacc, plr, nact, aidx, Wct, bc, out);
}

// ================= cooperative mega-kernel =================

struct MegaArgs {
  const void *x, *A, *eg;
  const void *w1, *b1, *w2, *b2, *tw, *tb;
  const void *qw, *qb0, *kw, *kb0, *vw, *vb0, *ow, *ob, *fw, *fb;
  int *nact, *cnt, *aidx, *inv, *edges;
  float* g; unsigned short* h; unsigned short* Vtc;
  unsigned short *W1t,*W2t,*Wqt,*Wkt,*Wvt,*Wct;
  float *qbf,*kbf,*vbf,*bcf,*b1f,*b2f;
  float *pacc,*plr;
  unsigned short *Qb,*Kb;
  float* out;
};

__global__ __launch_bounds__(256, 3) void k_mega(MegaArgs a){
  cg::grid_group grid = cg::this_grid();
  __shared__ alignas(16) unsigned char smem[45056];
  const int tid = threadIdx.x, bid = blockIdx.x, G = gridDim.x;
  const int lane = tid & 63;

  // ---- Pd: redundant per-block dtype detection (36KB scan, L2-resident) ----
  int md, mode;
  {
    int* sh = (int*)smem;            // [0]=cnt, [1]=pres, [2]=ge2
    if(tid < 3) sh[tid] = 0;
    __syncthreads();
    int c = 0;
    const unsigned short* xs = (const unsigned short*)a.x;
    for(int i=tid; i<6144; i+=256){
      unsigned short hh = xs[i*2];
      unsigned e = (hh >> 7) & 0xFF;
      if(hh==0 || (e >= 0x60 && e <= 0x9F)) c++;
    }
    if(c) atomicAdd(&sh[0], c);
    int pres=0, ge2=0;
    const unsigned char* egp = (const unsigned char*)a.eg;
    for(int i=tid; i<24576; i+=256){
      unsigned v = egp[i];
      if(v){ pres |= 1 << (i & 7); if(v >= 2u) ge2 = 1; }
    }
    if(pres) atomicOr(&sh[1], pres);
    if(ge2)  atomicOr(&sh[2], 1);
    __syncthreads();
    md = (sh[0] > 4000) ? 0 : 1;
    int pr = sh[1], g2 = sh[2];
    if(!g2){
      if((pr & ~0x01) == 0)      mode = 4;
      else if((pr & ~0x11) == 0) mode = 0;
      else                       mode = 1;
    } else {
      if((pr & ~0xC0) == 0)      mode = 5;
      else if((pr & ~0xCC) == 0) mode = 3;
      else                       mode = 2;
    }
    if(bid == 0 && tid < TT) a.nact[tid] = 0;
    __syncthreads();
  }
  grid.sync();

  // ---- P0: mask decode (TM) + weight prep (82720) + out zero (196608 f4) ----
  {
    const int D0 = TM, D1 = TM + 82720, DTOT = D1 + OUTSZ/4;
    for(int base = bid*256; base < DTOT; base += G*256){
      int id = base + tid;
      if(id < D0){
        dev_mask_item(id, mode, lane, a.eg, a.cnt, a.nact, a.aidx, a.inv);
      } else if(id < D1){
        dev_prepw_item(id - D0, md, a.w1,a.w2,a.qw,a.kw,a.vw,a.qb0,a.kb0,a.vb0,
                       a.ow,a.ob,a.fw,a.fb,a.tw,a.tb,a.b1,a.b2,
                       a.W1t,a.W2t,a.Wqt,a.Wkt,a.Wvt,a.Wct,
                       a.qbf,a.kbf,a.vbf,a.bcf,a.b1f,a.b2f);
      } else if(id < DTOT){
        float4 z4; z4.x=0.f; z4.y=0.f; z4.z=0.f; z4.w=0.f;
        ((float4*)a.out)[id - D1] = z4;
      }
    }
  }
  grid.sync();

  // ---- P1: edges (6144 block-slices) + gemm_x (384 tiles) ----
  {
    const int EB = TM*64/256;   // 6144
    for(int task = bid; task < EB + 384; task += G){
      if(task < EB) dev_edges_item(task*256 + tid, md, a.A, a.inv, a.cnt, a.edges);
      else          dev_gemm_x_tile(task - EB, md, tid, a.x, a.nact, a.aidx, a.W1t, a.g);
    }
  }
  grid.sync();

  // ---- P2: gather1 ----
  {
    const int wv = tid >> 6;
    for(int task = bid; task < TM/4; task += G)
      dev_gather_task(task*4 + wv, lane, a.g, a.edges, a.cnt, a.nact, a.b1f, a.h);
  }
  grid.sync();

  // ---- P3: gemm_h ----
  for(int task = bid; task < TM/64; task += G)
    dev_gemm_h_tile(task, tid, a.h, a.W2t, a.g, a.nact);
  grid.sync();

  // ---- P4: gather2 ----
  {
    const int wv = tid >> 6;
    for(int task = bid; task < TM/4; task += G)
      dev_gather_task(task*4 + wv, lane, a.g, a.edges, a.cnt, a.nact, a.b2f, a.h);
  }
  grid.sync();

  // ---- P5: QKV ----
  for(int task = bid; task < 3*(TM/64); task += G)
    dev_qkv_tile(task % (TM/64), task / (TM/64), tid, a.h,
                 a.Wqt, a.Wkt, a.Wvt, a.qbf, a.kbf, a.vbf, a.Qb, a.Kb, a.Vtc, a.nact);
  grid.sync();

  // ---- P6: attention partials (task = ((qx*TT)+t)*KS + s -> active tasks first) ----
  for(int task = bid; task < 32*TT*KS; task += G){
    int qx = task / (TT*KS), rem = task % (TT*KS);
    dev_attn_part_task(qx, rem / KS, rem % KS, tid, smem,
                       a.Qb, a.Kb, a.Vtc, a.nact, a.pacc, a.plr);
  }
  grid.sync();

  // ---- P7: combine + projection ----
  for(int task = bid; task < 32*TT; task += G)
    dev_attn_fin_task(task / TT, task % TT, tid, smem,
                      a.pacc, a.plr, a.nact, a.aidx, a.Wct, a.bcf, a.out);
}

// ================= launch =================

extern "C" void kernel_launch(void* const* d_in, const int* in_sizes, int n_in,
                              void* d_out, int out_size, void* d_ws, size_t ws_size,
                              hipStream_t stream)
{
  float* outp = (float*)d_out;
  static const int EXP[19] = {1572864,50331648,24576,8192,128,16384,128,16,16,
                              18432,128,18432,128,18432,128,16384,128,4096,32};
  bool ok = (n_in >= 19) && (out_size == OUTSZ);
  if(ok) for(int i=0;i<19;i++) if(in_sizes[i] != EXP[i]) { ok = false; break; }
  if(!ok){
    k_fill<<<(out_size+255)/256,256,0,stream>>>(outp, out_size, 1000.f);
    return;
  }
  const void* x   = d_in[0];
  const void* A   = d_in[1];
  const void* eg  = d_in[2];
  const void* w1  = d_in[3];
  const void* b1  = d_in[4];
  const void* w2  = d_in[5];
  const void* b2  = d_in[6];
  const void* tw  = d_in[7];
  const void* tb  = d_in[8];
  const void* qw  = d_in[9];
  const void* qb0 = d_in[10];
  const void* kw  = d_in[11];
  const void* kb0 = d_in[12];
  const void* vw  = d_in[13];
  const void* vb0 = d_in[14];
  const void* ow  = d_in[15];
  const void* ob  = d_in[16];
  const void* fw  = d_in[17];
  const void* fb  = d_in[18];

  char* w = (char*)d_ws;
  size_t off = 0;
  auto alloc = [&](size_t sz)->char*{
    char* p = w + off; off = (off + sz + 255) & ~(size_t)255; return p; };
  int*   flag  = (int*)  alloc(4);
  int*   dtf   = (int*)  alloc(4);
  int*   nactb = (int*)  alloc(TT*4);
  int*   cnt   = (int*)  alloc((size_t)TM*4);
  int*   aidx  = (int*)  alloc((size_t)TM*4);
  int*   inv   = (int*)  alloc((size_t)TM*4);
  int*   edges = (int*)  alloc((size_t)TM*CAP*4);
  float* g     = (float*)alloc((size_t)TM*DH*4);   // reused as Qb+Kb after 2nd gather
  unsigned short* h   = (unsigned short*)alloc((size_t)TM*DH*2);
  unsigned short* Vtc = (unsigned short*)alloc((size_t)TT*DH*MM*2);
  unsigned short* W1t = (unsigned short*)alloc(DH*DIN*2);
  unsigned short* W2t = (unsigned short*)alloc(DH*DH*2);
  unsigned short* Wqt = (unsigned short*)alloc(DH*DH*2);
  unsigned short* Wkt = (unsigned short*)alloc(DH*DH*2);
  unsigned short* Wvt = (unsigned short*)alloc(DH*DH*2);
  unsigned short* Wct = (unsigned short*)alloc(DOUT*DH*2);
  float* qbf = (float*)alloc(TT*DH*4);
  float* kbf = (float*)alloc(TT*DH*4);
  float* vbf = (float*)alloc(TT*DH*4);
  float* bcf = (float*)alloc(DOUT*4);
  float* b1f = (float*)alloc(DH*4);
  float* b2f = (float*)alloc(DH*4);
  float* pacc = (float*)alloc((size_t)KS*TT*32*256*32*4);  // split-K PV partials (~50MB)
  float* plr  = (float*)alloc((size_t)KS*TT*32*256*4);     // split-K l partials
  if(off > ws_size){
    k_fill<<<(out_size+255)/256,256,0,stream>>>(outp, out_size, 500.f);
    return;
  }

  unsigned short* Qb = (unsigned short*)g;                       // TM*DH*2 bytes
  unsigned short* Kb = (unsigned short*)((char*)g + (size_t)TM*DH*2);

  // ---- preferred path: single cooperative kernel ----
  MegaArgs ma;
  ma.x=x; ma.A=A; ma.eg=eg;
  ma.w1=w1; ma.b1=b1; ma.w2=w2; ma.b2=b2; ma.tw=tw; ma.tb=tb;
  ma.qw=qw; ma.qb0=qb0; ma.kw=kw; ma.kb0=kb0; ma.vw=vw; ma.vb0=vb0;
  ma.ow=ow; ma.ob=ob; ma.fw=fw; ma.fb=fb;
  ma.nact=nactb; ma.cnt=cnt; ma.aidx=aidx; ma.inv=inv; ma.edges=edges;
  ma.g=g; ma.h=h; ma.Vtc=Vtc;
  ma.W1t=W1t; ma.W2t=W2t; ma.Wqt=Wqt; ma.Wkt=Wkt; ma.Wvt=Wvt; ma.Wct=Wct;
  ma.qbf=qbf; ma.kbf=kbf; ma.vbf=vbf; ma.bcf=bcf; ma.b1f=b1f; ma.b2f=b2f;
  ma.pacc=pacc; ma.plr=plr; ma.Qb=Qb; ma.Kb=Kb; ma.out=outp;
  void* kp[] = { (void*)&ma };
  hipError_t err = hipLaunchCooperativeKernel((const void*)k_mega,
                                              dim3(GRID), dim3(256), kp, 0, stream);
  if(err == hipSuccess) return;
  (void)hipGetLastError();   // clear error state; fall back to multi-kernel path

  // ---- fallback: verified round-1 pipeline ----
  k_detect2<<<2,256,0,stream>>>((const unsigned short*)x, (const unsigned char*)eg,
                                dtf, flag, nactb);
  k_mask<<<OUTSZ/256,256,0,stream>>>(eg, flag, cnt, nactb, aidx, inv, outp);
  k_prep_edges<<<PWB + TM*64/256,256,0,stream>>>(w1,w2,qw,kw,vw,qb0,kb0,vb0,ow,ob,fw,fb,tw,tb,
                                                 b1,b2,dtf,
                                                 W1t,W2t,Wqt,Wkt,Wvt,Wct,qbf,kbf,vbf,bcf,b1f,b2f,
                                                 A, inv, cnt, edges);
  k_gemm_x<<<TM/64,256,0,stream>>>(x, dtf, nactb, aidx, W1t, g);
  k_gather<<<TM/4,256,0,stream>>>(g, edges, cnt, nactb, b1f, h);
  k_gemm_h<<<TM/64,256,0,stream>>>(h, W2t, g, nactb);
  k_gather<<<TM/4,256,0,stream>>>(g, edges, cnt, nactb, b2f, h);
  k_gemm_qkv<<<dim3(TM/64,1,3),256,0,stream>>>(h, Wqt,Wkt,Wvt, qbf,kbf,vbf, Qb,Kb,Vtc, nactb);
  k_attn_part<<<dim3(MM/64,TT,KS),256,0,stream>>>(Qb, Kb, Vtc, nactb, pacc, plr);
  k_attn_fin<<<dim3(MM/64,TT),256,0,stream>>>(pacc, plr, nactb, aidx, Wct, bcf, outp);
}

// Round 3
// 904.619 us; speedup vs baseline: 1.3778x; 1.3778x over previous
//
#include <hip/hip_runtime.h>
#include <stdint.h>

#define TT   12
#define BB   2
#define NN   1024
#define MM   2048
#define TM   24576      // TT*MM
#define DIN  64
#define DH   128
#define DOUT 32
#define CAP  64
#define OUTSZ 786432
#define KS   2          // split-K factor for attention
#define PWB  324        // prepw blocks inside merged prep_edges kernel (fallback path)
#define GRID 512        // cooperative grid: 2 blocks/CU x 256 CUs

typedef __attribute__((ext_vector_type(8))) short short8;
typedef __attribute__((ext_vector_type(4))) short short4v;
typedef __attribute__((ext_vector_type(4))) float f32x4;

#define MFMA(a,b,c) __builtin_amdgcn_mfma_f32_16x16x32_bf16((a),(b),(c),0,0,0)

__device__ __forceinline__ float bf2f(unsigned short u){
  union { uint32_t i; float f; } x; x.i = ((uint32_t)u) << 16; return x.f;
}
__device__ __forceinline__ unsigned short f2bf(float f){
  union { float f; uint32_t i; } x; x.f = f;
  uint32_t u = x.i + 0x7FFFu + ((x.i >> 16) & 1u);   // RNE
  return (unsigned short)(u >> 16);
}
__device__ __forceinline__ float LD(const void* p, size_t i, int mode){
  return mode ? ((const float*)p)[i] : bf2f(((const unsigned short*)p)[i]);
}
// gather-load 8 input elements as bf16 (mode 1 = fp32 source)
__device__ __forceinline__ short8 ldx8(const void* x, size_t off, int md){
  if(md){
    const float4* xf = (const float4*)((const float*)x + off);
    float4 a = xf[0], b = xf[1];
    short8 o;
    o[0]=(short)f2bf(a.x); o[1]=(short)f2bf(a.y); o[2]=(short)f2bf(a.z); o[3]=(short)f2bf(a.w);
    o[4]=(short)f2bf(b.x); o[5]=(short)f2bf(b.y); o[6]=(short)f2bf(b.z); o[7]=(short)f2bf(b.w);
    return o;
  }
  return *(const short8*)((const unsigned short*)x + off);
}

// ---- lightweight agent-scope grid barrier (one atomic per block, monotonic) ----
// __syncthreads() drains each wave's stores to L2; the release fence (thread 0)
// writes the XCD's L2 back; relaxed polling avoids re-invalidating L2 per poll;
// one acquire fence after the spin invalidates stale lines. Avoids cg::sync's
// ~120us system-scope protocol (round-2 measurement: 8 syncs ~= 950us idle).
__device__ __forceinline__ void gbar(int* bar, int target){
  __syncthreads();
  if(threadIdx.x == 0){
    __builtin_amdgcn_fence(__ATOMIC_RELEASE, "agent");
    __hip_atomic_fetch_add(bar, 1, __ATOMIC_RELAXED, __HIP_MEMORY_SCOPE_AGENT);
    while(__hip_atomic_load(bar, __ATOMIC_RELAXED, __HIP_MEMORY_SCOPE_AGENT) < target)
      __builtin_amdgcn_s_sleep(2);
    __builtin_amdgcn_fence(__ATOMIC_ACQUIRE, "agent");
  }
  __syncthreads();
}

// ================= shared per-item / per-tile device bodies =================

__device__ __forceinline__ void dev_mask_item(int idx, int mode, int lane,
    const void* egom, int* cnt, int* nact, int* aidx, int* inv){
  int t = idx / MM, node = idx % MM;               // wave = 64 consecutive nodes, one t
  int b = node / NN, n = node % NN;
  int src = (b*TT + t)*NN + n;
  int v;
  if(mode==0)      v = ((const int*)egom)[src] != 0;
  else if(mode==1) v = ((const unsigned char*)egom)[src] != 0;
  else if(mode==2) v = ((const unsigned short*)egom)[src] != 0;
  else if(mode==3) v = ((const float*)egom)[src] != 0.f;
  else if(mode==4) v = ((const long long*)egom)[src] != 0;
  else             v = ((const double*)egom)[src] != 0.0;
  cnt[idx] = 0;
  unsigned long long bal = __ballot(v != 0);
  int base = 0;
  if(lane == 0 && bal) base = atomicAdd(&nact[t], __popcll(bal));
  base = __shfl(base, 0, 64);
  int ic = -1;
  if(v){
    int pfx = __popcll(bal & ((1ULL << lane) - 1ULL));
    ic = base + pfx;
    aidx[(size_t)t*MM + ic] = node;
  }
  inv[idx] = ic;
}

__device__ __forceinline__ void dev_prepw_item(int id, int md,
  const void* w1, const void* w2,
  const void* qw, const void* kw, const void* vw,
  const void* qb0, const void* kb0, const void* vb0,
  const void* ow, const void* ob, const void* fw, const void* fb,
  const void* tw, const void* tb, const void* b1, const void* b2,
  unsigned short* W1t, unsigned short* W2t,
  unsigned short* Wqt, unsigned short* Wkt,
  unsigned short* Wvt, unsigned short* Wct,
  float* qbf, float* kbf, float* vbf,
  float* bcf, float* b1f, float* b2f)
{
  if(id < 8192){  // coalesced read: consecutive id -> consecutive n
    int n=id&127, k2=id>>7; W1t[n*64+k2]=f2bf(LD(w1,(size_t)k2*128+n,md)); return; }
  id -= 8192;
  if(id < 16384){ int n=id&127,k2=id>>7; W2t[n*128+k2]=f2bf(LD(w2,(size_t)k2*128+n,md)); return; }
  id -= 16384;
  if(id < 16384){ int n=id&127,k2=id>>7; Wqt[n*128+k2]=f2bf(LD(qw,(size_t)k2*128+n,md)); return; }
  id -= 16384;
  if(id < 16384){ int n=id&127,k2=id>>7; Wkt[n*128+k2]=f2bf(LD(kw,(size_t)k2*128+n,md)); return; }
  id -= 16384;
  if(id < 16384){ int n=id&127,k2=id>>7; Wvt[n*128+k2]=f2bf(LD(vw,(size_t)k2*128+n,md)); return; }
  id -= 16384;
  if(id < 4096){  // Wc = o_w @ fc_w, stored [oc][c]
    int oc=id&31, c=id>>5; float s=0.f;
    for(int r=0;r<128;r++) s += LD(ow,(size_t)c*128+r,md)*LD(fw,(size_t)r*32+oc,md);
    Wct[oc*128+c]=f2bf(s); return;
  }
  id -= 4096;
  if(id < 32){    // bc = o_b @ fc_w + fc_b
    float s = LD(fb,id,md);
    for(int r=0;r<128;r++) s += LD(ob,r,md)*LD(fw,(size_t)r*32+id,md);
    bcf[id]=s; return;
  }
  id -= 32;
  if(id < 4608){  // per-t fused QKV bias: b + t_vec @ W[128:144]
    int which = id/1536, rem=id%1536, t=rem/128, n=rem%128;
    const void* W  = which==0?qw:(which==1?kw:vw);
    const void* Bs = which==0?qb0:(which==1?kb0:vb0);
    float s = LD(Bs,n,md);
    for(int d=0;d<16;d++){
      float tv = sinf((float)t*LD(tw,d,md) + LD(tb,d,md));
      s += tv * LD(W,(size_t)(128+d)*128+n,md);
    }
    float* dst = which==0?qbf:(which==1?kbf:vbf);
    dst[t*128+n]=s; return;
  }
  id -= 4608;
  if(id < 256){   // GCN biases to fp32
    if(id<128) b1f[id] = LD(b1,id,md);
    else       b2f[id-128] = LD(b2,id-128,md);
    return;
  }
}

__device__ __forceinline__ void dev_edges_item(int id, int md,
    const void* A, const int* inv, int* cnt, int* edges){
  int seg = id & 63; int row = id >> 6;           // row = t*MM + j (orig)
  int t = row / MM;
  int jc = inv[row];
  if(jc < 0) return;                              // inactive source
  const int* invt = inv + (size_t)t*MM;
  int* cb = cnt + (size_t)t*MM;
  int* eb = edges + (size_t)t*MM*CAP;
  if(md){   // fp32 adjacency
    const float4* p4 = (const float4*)((const float*)A + (size_t)row*MM + seg*32);
    #pragma unroll
    for(int u=0;u<8;u++){
      float4 v = p4[u];
      float wd[4]={v.x,v.y,v.z,v.w};
      #pragma unroll
      for(int q=0;q<4;q++){
        if(wd[q]!=0.f){
          int ibc = invt[seg*32 + u*4 + q];
          if(ibc >= 0){ int s=atomicAdd(&cb[ibc],1); if(s<CAP) eb[(size_t)ibc*CAP+s]=jc; }
        }
      }
    }
  } else {    // bf16 adjacency
    const uint4* p4 = (const uint4*)((const unsigned short*)A + (size_t)row*MM + seg*32);
    #pragma unroll
    for(int u=0;u<4;u++){
      uint4 v = p4[u];
      unsigned wd[4]={v.x,v.y,v.z,v.w};
      #pragma unroll
      for(int q=0;q<4;q++){
        int ib = seg*32 + u*8 + q*2;
        if(wd[q] & 0xFFFFu){
          int ibc = invt[ib];
          if(ibc >= 0){ int s=atomicAdd(&cb[ibc],1); if(s<CAP) eb[(size_t)ibc*CAP+s]=jc; }
        }
        if(wd[q] >> 16){
          int ibc = invt[ib+1];
          if(ibc >= 0){ int s=atomicAdd(&cb[ibc],1); if(s<CAP) eb[(size_t)ibc*CAP+s]=jc; }
        }
      }
    }
  }
}

__device__ __forceinline__ void dev_gemm_x_tile(int tileIdx, int md, int tid,
    const void* x, const int* nact, const int* aidx,
    const unsigned short* Wt, float* g)
{
  const int tile = tileIdx*64;
  const int t = tile / MM, il = tile % MM;
  const int na = nact[t];
  if(il >= ((na+63)&~63)) return;
  const int wv=tid>>6, lane=tid&63, l15=lane&15, quad=lane>>4;
  const int r0 = tile + (wv>>1)*32;          // global compact row base
  const int c0 = (wv&1)*64;
  short8 bf[2][4];
  #pragma unroll
  for(int kk=0;kk<2;kk++)
    #pragma unroll
    for(int nt=0;nt<4;nt++)
      bf[kk][nt] = *(const short8*)(Wt + (size_t)(c0+nt*16+l15)*DIN + kk*32 + quad*8);
  const int il0 = (r0 % MM) + l15, il1 = (r0 % MM) + 16 + l15;
  const int n0 = aidx[(size_t)t*MM + (il0 < na ? il0 : 0)];
  const int n1 = aidx[(size_t)t*MM + (il1 < na ? il1 : 0)];
  const size_t xb0 = ((size_t)t*MM + n0)*DIN;
  const size_t xb1 = ((size_t)t*MM + n1)*DIN;
  f32x4 z = {0.f,0.f,0.f,0.f};
  f32x4 acc[2][4];
  #pragma unroll
  for(int i=0;i<2;i++){ acc[i][0]=z; acc[i][1]=z; acc[i][2]=z; acc[i][3]=z; }
  #pragma unroll
  for(int kk=0;kk<2;kk++){
    short8 a0 = ldx8(x, xb0 + kk*32 + quad*8, md);
    short8 a1 = ldx8(x, xb1 + kk*32 + quad*8, md);
    #pragma unroll
    for(int nt=0;nt<4;nt++){
      acc[0][nt]=MFMA(a0,bf[kk][nt],acc[0][nt]);
      acc[1][nt]=MFMA(a1,bf[kk][nt],acc[1][nt]);
    }
  }
  #pragma unroll
  for(int mt=0;mt<2;mt++)
    #pragma unroll
    for(int nt=0;nt<4;nt++){
      int col = c0+nt*16+l15;
      #pragma unroll
      for(int r=0;r<4;r++){
        int row = r0 + mt*16 + quad*4 + r;
        g[(size_t)row*DH + col] = acc[mt][nt][r];
      }
    }
}

__device__ __forceinline__ void dev_gemm_h_tile(int tileIdx, int tid,
    const unsigned short* X, const unsigned short* Wt, float* g, const int* nact)
{
  const int tile = tileIdx*64;
  const int t = tile / MM, il = tile % MM;
  const int na = nact[t];
  if(il >= ((na+63)&~63)) return;
  const int wv=tid>>6, lane=tid&63, l15=lane&15, quad=lane>>4;
  const int r0 = tile + (wv>>1)*32;
  const int c0 = (wv&1)*64;
  short8 bf[4][4];
  #pragma unroll
  for(int kk=0;kk<4;kk++)
    #pragma unroll
    for(int nt=0;nt<4;nt++)
      bf[kk][nt] = *(const short8*)(Wt + (size_t)(c0+nt*16+l15)*DH + kk*32 + quad*8);
  f32x4 z = {0.f,0.f,0.f,0.f};
  f32x4 acc[2][4];
  #pragma unroll
  for(int i=0;i<2;i++){ acc[i][0]=z; acc[i][1]=z; acc[i][2]=z; acc[i][3]=z; }
  #pragma unroll
  for(int kk=0;kk<4;kk++){
    short8 a0 = *(const short8*)(X + (size_t)(r0+l15)*DH    + kk*32 + quad*8);
    short8 a1 = *(const short8*)(X + (size_t)(r0+16+l15)*DH + kk*32 + quad*8);
    #pragma unroll
    for(int nt=0;nt<4;nt++){
      acc[0][nt]=MFMA(a0,bf[kk][nt],acc[0][nt]);
      acc[1][nt]=MFMA(a1,bf[kk][nt],acc[1][nt]);
    }
  }
  #pragma unroll
  for(int mt=0;mt<2;mt++)
    #pragma unroll
    for(int nt=0;nt<4;nt++){
      int col = c0+nt*16+l15;
      #pragma unroll
      for(int r=0;r<4;r++){
        int row = r0 + mt*16 + quad*4 + r;
        g[(size_t)row*DH + col] = acc[mt][nt][r];
      }
    }
}

__device__ __forceinline__ void dev_gather_task(int gi, int lane,
    const float* g, const int* edges, const int* cnt,
    const int* nact, const float* bias, unsigned short* h)
{
  int t = gi / MM, ic = gi % MM;
  int na = nact[t];
  if(ic >= ((na+63)&~63)) return;
  unsigned int* hp = (unsigned int*)(h + (size_t)gi*DH) + lane;
  if(ic >= na){ *hp = 0; return; }      // pad row: finite zeros
  float a0=0.f, a1=0.f;
  int cn = cnt[gi]; if(cn>CAP) cn=CAP;
  const int* eb = edges + (size_t)gi*CAP;
  #pragma unroll 2
  for(int e=0;e<cn;e++){
    int jc = eb[e];
    float nj = rsqrtf((float)cnt[(size_t)t*MM+jc] + 1.f);
    float2 gr2 = *(const float2*)(g + ((size_t)t*MM + jc)*DH + 2*lane);
    a0 += nj*gr2.x; a1 += nj*gr2.y;
  }
  float ni = rsqrtf((float)cn + 1.f);
  float2 gs2 = *(const float2*)(g + (size_t)gi*DH + 2*lane);
  float h0 = ni*(a0 + ni*gs2.x) + bias[2*lane];
  float h1 = ni*(a1 + ni*gs2.y) + bias[2*lane+1];
  h0 = h0>0.f?h0:0.f; h1 = h1>0.f?h1:0.f;
  *hp = (unsigned int)f2bf(h0) | ((unsigned int)f2bf(h1) << 16);
}

__device__ __forceinline__ void dev_qkv_tile(int tileIdx, int which, int tid,
    const unsigned short* X,
    const unsigned short* Wq, const unsigned short* Wk, const unsigned short* Wv,
    const float* qb, const float* kb, const float* vb,
    unsigned short* Qo, unsigned short* Ko, unsigned short* Vtc, const int* nact)
{
  const int tile = tileIdx*64;
  const int t = tile / MM, il = tile % MM;
  const int na = nact[t];
  if(il >= ((na+63)&~63)) return;
  const unsigned short* Wt = which==0?Wq:(which==1?Wk:Wv);
  const float* bias = which==0?qb:(which==1?kb:vb);
  const int wv=tid>>6, lane=tid&63, l15=lane&15, quad=lane>>4;
  const int r0 = tile + (wv>>1)*32;
  const int c0 = (wv&1)*64;
  short8 bf[4][4];
  #pragma unroll
  for(int kk=0;kk<4;kk++)
    #pragma unroll
    for(int nt=0;nt<4;nt++)
      bf[kk][nt] = *(const short8*)(Wt + (size_t)(c0+nt*16+l15)*DH + kk*32 + quad*8);
  f32x4 z = {0.f,0.f,0.f,0.f};
  f32x4 acc[2][4];
  #pragma unroll
  for(int i=0;i<2;i++){ acc[i][0]=z; acc[i][1]=z; acc[i][2]=z; acc[i][3]=z; }
  #pragma unroll
  for(int kk=0;kk<4;kk++){
    short8 a0 = *(const short8*)(X + (size_t)(r0+l15)*DH    + kk*32 + quad*8);
    short8 a1 = *(const short8*)(X + (size_t)(r0+16+l15)*DH + kk*32 + quad*8);
    #pragma unroll
    for(int nt=0;nt<4;nt++){
      acc[0][nt]=MFMA(a0,bf[kk][nt],acc[0][nt]);
      acc[1][nt]=MFMA(a1,bf[kk][nt],acc[1][nt]);
    }
  }
  if(which < 2){
    unsigned short* o = which==0 ? Qo : Ko;
    #pragma unroll
    for(int mt=0;mt<2;mt++)
      #pragma unroll
      for(int nt=0;nt<4;nt++){
        int col = c0+nt*16+l15;
        float bb = bias[t*DH+col];
        #pragma unroll
        for(int r=0;r<4;r++){
          int row = r0 + mt*16 + quad*4 + r;
          o[(size_t)row*DH + col] = f2bf(acc[mt][nt][r] + bb);
        }
      }
  } else {
    #pragma unroll
    for(int mt=0;mt<2;mt++)
      #pragma unroll
      for(int nt=0;nt<4;nt++){
        int col = c0+nt*16+l15;
        float bb = bias[t*DH+col];
        int node0 = il + (wv>>1)*32 + mt*16 + quad*4;   // compact local row
        short4v pk;
        #pragma unroll
        for(int r=0;r<4;r++) pk[r] = (short)f2bf(acc[mt][nt][r] + bb);
        *(short4v*)(Vtc + ((size_t)t*DH + col)*MM + node0) = pk;
      }
  }
}

// LDS layout (45056 B): Kl[64][136]us @0 (17408) | Vl[128][72]us @17408 (18432)
//                       | Pl[4][16][72]s @35840 (9216).  Al[4][16][136]s overlays @0.
__device__ __forceinline__ void dev_attn_part_task(int qx, int t, int s, int tid,
  unsigned char* smem,
  const unsigned short* Q, const unsigned short* Kc, const unsigned short* Vtc,
  const int* nact, float* pacc, float* plr)
{
  unsigned short (*Kl)[136] = (unsigned short(*)[136])smem;
  unsigned short (*Vl)[72]  = (unsigned short(*)[72])(smem + 17408);
  short (*Pl)[16][72]       = (short(*)[16][72])(smem + 35840);
  const int wv=tid>>6, lane=tid&63, l15=lane&15, quad=lane>>4;
  const int na = nact[t];
  const int qblk = qx*64;
  if(qblk >= na) return;                 // task-uniform exit (barriers are outside)
  const int qbase = qblk + wv*16;
  const float scale = 0.088388347648318447f;  // 1/sqrt(128)
  const int nkt = (na + 63) >> 6;

  short8 bq[4];
  #pragma unroll
  for(int kk=0;kk<4;kk++)
    bq[kk] = *(const short8*)(Q + ((size_t)t*MM + qbase + l15)*DH + kk*32 + quad*8);

  f32x4 zz = {0.f,0.f,0.f,0.f};
  f32x4 accPV[8];
  #pragma unroll
  for(int i=0;i<8;i++) accPV[i]=zz;
  float l_run = 0.f;

  const int srow = tid >> 2, sseg = tid & 3;   // K stage: 64 rows x 4 segs
  const int vch  = tid >> 1, vhalf = tid & 1;  // V stage: 128 ch x 2 halves

  short8 kreg[4], vreg[4];
  if(s < nkt){  // preload this split's first tile
    const unsigned short* gk = Kc + ((size_t)t*MM + s*64 + srow)*DH + sseg*32;
    const unsigned short* gv = Vtc + ((size_t)t*DH + vch)*MM + s*64 + vhalf*32;
    #pragma unroll
    for(int j=0;j<4;j++){ kreg[j] = *(const short8*)(gk + j*8);
                          vreg[j] = *(const short8*)(gv + j*8); }
  }

  for(int kt=s; kt<nkt; kt+=KS){
    const int key0 = kt*64;
    __syncthreads();   // previous tile fully consumed before restage
    {  // write prefetched registers to LDS
      short8* kd = (short8*)&Kl[srow][sseg*32];
      short8* vd = (short8*)&Vl[vch][vhalf*32];
      #pragma unroll
      for(int j=0;j<4;j++){ kd[j] = kreg[j]; vd[j] = vreg[j]; }
    }
    __syncthreads();
    if(kt+KS < nkt){   // issue next tile's global loads; overlap compute below
      const int key1 = key0 + KS*64;
      const unsigned short* gk = Kc + ((size_t)t*MM + key1 + srow)*DH + sseg*32;
      const unsigned short* gv = Vtc + ((size_t)t*DH + vch)*MM + key1 + vhalf*32;
      #pragma unroll
      for(int j=0;j<4;j++){ kreg[j] = *(const short8*)(gk + j*8);
                            vreg[j] = *(const short8*)(gv + j*8); }
    }
    // S^T = K · Q^T from LDS
    #pragma unroll
    for(int mt=0;mt<4;mt++){
      f32x4 sv4 = zz;
      #pragma unroll
      for(int kk=0;kk<4;kk++){
        short8 ak = *(const short8*)&Kl[mt*16+l15][kk*32 + quad*8];
        sv4 = MFMA(ak, bq[kk], sv4);
      }
      short4v pk;
      #pragma unroll
      for(int r=0;r<4;r++){
        float sv = fminf(fmaxf(sv4[r]*scale, -15.f), 15.f);
        float valid = (key0 + mt*16 + quad*4 + r < na) ? 1.f : 0.f;
        float p = __expf(sv) * valid;
        pk[r] = (short)f2bf(p);
        l_run += bf2f((unsigned short)pk[r]);
      }
      *(short4v*)&Pl[wv][l15][mt*16 + quad*4] = pk;
    }
    // PV from LDS
    #pragma unroll
    for(int kk=0;kk<2;kk++){
      short8 ap = *(const short8*)&Pl[wv][l15][kk*32 + quad*8];
      #pragma unroll
      for(int nt=0;nt<8;nt++){
        short8 bv = *(const short8*)&Vl[nt*16+l15][kk*32 + quad*8];
        accPV[nt] = MFMA(ap, bv, accPV[nt]);
      }
    }
  }
  // dump raw per-lane partials (coalesced, layout-agnostic)
  float* pb = pacc + ((((size_t)s*TT + t)*32 + qx)*256 + tid)*32;
  #pragma unroll
  for(int i=0;i<8;i++) *(f32x4*)(pb + i*4) = accPV[i];
  plr[(((size_t)s*TT + t)*32 + qx)*256 + tid] = l_run;
}

__device__ __forceinline__ void dev_attn_fin_task(int qx, int t, int tid,
  unsigned char* smem,
  const float* pacc, const float* plr,
  const int* nact, const int* aidx,
  const unsigned short* Wct, const float* bc, float* out)
{
  short (*Al)[16][136] = (short(*)[16][136])smem;   // per-wave slice, wave-private
  const int wv=tid>>6, lane=tid&63, l15=lane&15, quad=lane>>4;
  const int na = nact[t];
  const int qblk = qx*64;
  if(qblk >= na) return;
  const int qbase = qblk + wv*16;

  f32x4 zz = {0.f,0.f,0.f,0.f};
  f32x4 acc[8];
  #pragma unroll
  for(int i=0;i<8;i++) acc[i]=zz;
  float l_run = 0.f;
  #pragma unroll
  for(int s=0;s<KS;s++){
    const f32x4* p = (const f32x4*)(pacc + ((((size_t)s*TT + t)*32 + qx)*256 + tid)*32);
    #pragma unroll
    for(int i=0;i<8;i++) acc[i] += p[i];
    l_run += plr[(((size_t)s*TT + t)*32 + qx)*256 + tid];
  }
  l_run += __shfl_xor(l_run, 16, 64);
  l_run += __shfl_xor(l_run, 32, 64);

  #pragma unroll
  for(int nt=0;nt<8;nt++)
    #pragma unroll
    for(int r=0;r<4;r++){
      float av = fminf(fmaxf(acc[nt][r], -1e30f), 1e30f);
      Al[wv][quad*4+r][nt*16+l15] = (short)f2bf(av);
    }

  const int qc = qbase + l15;
  const bool qok = (qc < na);
  const float linv = (l_run > 0.f) ? 1.f/l_run : 0.f;
  const int node = aidx[(size_t)t*MM + (qok ? qc : 0)];
  #pragma unroll
  for(int mt2=0;mt2<2;mt2++){
    f32x4 d = zz;
    #pragma unroll
    for(int kk=0;kk<4;kk++){
      short8 aw = *(const short8*)(Wct + (size_t)(mt2*16+l15)*DH + kk*32 + quad*8);
      short8 bl = *(const short8*)&Al[wv][l15][kk*32 + quad*8];
      d = MFMA(aw, bl, d);
    }
    f32x4 bcv = *(const f32x4*)(bc + mt2*16 + quad*4);
    f32x4 o4;
    #pragma unroll
    for(int r=0;r<4;r++) o4[r] = d[r]*linv + bcv[r];
    if(qok)
      *(f32x4*)(out + (size_t)node*(TT*DOUT) + (size_t)t*DOUT + mt2*16 + quad*4) = o4;
  }
}

// ================= standalone kernels (init + fallback path) =================

__global__ void k_fill(float* __restrict__ out, int n, float val){
  int i = blockIdx.x*blockDim.x + threadIdx.x;
  if(i < n) out[i] = val;
}

__global__ void k_init(int* __restrict__ bar, int* __restrict__ nact){
  if(threadIdx.x == 0) *bar = 0;
  if(threadIdx.x < TT) nact[threadIdx.x] = 0;
}

__global__ void k_detect2(const unsigned short* __restrict__ x,
                          const unsigned char* __restrict__ eg,
                          int* __restrict__ dtf, int* __restrict__ flag,
                          int* __restrict__ nact){
  if(blockIdx.x == 0){
    __shared__ int cnt_s;
    if(threadIdx.x==0) cnt_s = 0;
    if(threadIdx.x < TT) nact[threadIdx.x] = 0;
    __syncthreads();
    int c = 0;
    for(int i=threadIdx.x; i<6144; i+=blockDim.x){
      unsigned short h = x[i*2];
      unsigned e = (h >> 7) & 0xFF;
      if(h==0 || (e >= 0x60 && e <= 0x9F)) c++;
    }
    atomicAdd(&cnt_s, c);
    __syncthreads();
    if(threadIdx.x==0) *dtf = (cnt_s > 4000) ? 0 : 1;   // 0=bf16, 1=fp32
  } else {
    __shared__ int pres_s, ge2_s;
    if(threadIdx.x==0){ pres_s=0; ge2_s=0; }
    __syncthreads();
    int pres=0, ge2=0;
    for(int i=threadIdx.x; i<24576; i+=blockDim.x){
      unsigned v = eg[i];
      if(v){ pres |= 1 << (i & 7); if(v >= 2u) ge2 = 1; }
    }
    if(pres) atomicOr(&pres_s, pres);
    if(ge2)  atomicOr(&ge2_s, 1);
    __syncthreads();
    if(threadIdx.x==0){
      int pr = pres_s, g2 = ge2_s, mode;
      if(!g2){
        if((pr & ~0x01) == 0)      mode = 4;   // i64
        else if((pr & ~0x11) == 0) mode = 0;   // i32
        else                       mode = 1;   // u8
      } else {
        if((pr & ~0xC0) == 0)      mode = 5;   // f64
        else if((pr & ~0xCC) == 0) mode = 3;   // f32
        else                       mode = 2;   // bf16
      }
      *flag = mode;
    }
  }
}

__global__ void k_mask(const void* __restrict__ egom, const int* __restrict__ flag,
                       int* __restrict__ cnt, int* __restrict__ nact,
                       int* __restrict__ aidx, int* __restrict__ inv,
                       float* __restrict__ out){
  int idx = blockIdx.x*blockDim.x + threadIdx.x;   // < OUTSZ
  out[idx] = 0.f;
  if(idx >= TM) return;
  dev_mask_item(idx, *flag, threadIdx.x & 63, egom, cnt, nact, aidx, inv);
}

__global__ __launch_bounds__(256) void k_prep_edges(
  const void* __restrict__ w1, const void* __restrict__ w2,
  const void* __restrict__ qw, const void* __restrict__ kw, const void* __restrict__ vw,
  const void* __restrict__ qb0, const void* __restrict__ kb0, const void* __restrict__ vb0,
  const void* __restrict__ ow, const void* __restrict__ ob,
  const void* __restrict__ fw, const void* __restrict__ fb,
  const void* __restrict__ tw, const void* __restrict__ tb,
  const void* __restrict__ b1, const void* __restrict__ b2,
  const int* __restrict__ dtf,
  unsigned short* __restrict__ W1t, unsigned short* __restrict__ W2t,
  unsigned short* __restrict__ Wqt, unsigned short* __restrict__ Wkt,
  unsigned short* __restrict__ Wvt, unsigned short* __restrict__ Wct,
  float* __restrict__ qbf, float* __restrict__ kbf, float* __restrict__ vbf,
  float* __restrict__ bcf, float* __restrict__ b1f, float* __restrict__ b2f,
  const void* __restrict__ A, const int* __restrict__ inv,
  int* __restrict__ cnt, int* __restrict__ edges)
{
  const int md = *dtf;
  if(blockIdx.x < PWB){
    int id = blockIdx.x*blockDim.x + threadIdx.x;
    dev_prepw_item(id, md, w1,w2,qw,kw,vw,qb0,kb0,vb0,ow,ob,fw,fb,tw,tb,b1,b2,
                   W1t,W2t,Wqt,Wkt,Wvt,Wct,qbf,kbf,vbf,bcf,b1f,b2f);
  } else {
    int id = (blockIdx.x - PWB)*blockDim.x + threadIdx.x;
    dev_edges_item(id, md, A, inv, cnt, edges);
  }
}

__global__ __launch_bounds__(256) void k_gemm_x(const void* __restrict__ x,
    const int* __restrict__ dtf, const int* __restrict__ nact,
    const int* __restrict__ aidx, const unsigned short* __restrict__ Wt,
    float* __restrict__ g)
{
  dev_gemm_x_tile(blockIdx.x, *dtf, threadIdx.x, x, nact, aidx, Wt, g);
}

__global__ __launch_bounds__(256) void k_gemm_h(const unsigned short* __restrict__ X,
    const unsigned short* __restrict__ Wt, float* __restrict__ g,
    const int* __restrict__ nact)
{
  dev_gemm_h_tile(blockIdx.x, threadIdx.x, X, Wt, g, nact);
}

__global__ __launch_bounds__(256) void k_gather(const float* __restrict__ g,
    const int* __restrict__ edges, const int* __restrict__ cnt,
    const int* __restrict__ nact, const float* __restrict__ bias,
    unsigned short* __restrict__ h)
{
  int wv = threadIdx.x>>6, lane = threadIdx.x&63;
  dev_gather_task(blockIdx.x*4 + wv, lane, g, edges, cnt, nact, bias, h);
}

__global__ __launch_bounds__(256) void k_gemm_qkv(const unsigned short* __restrict__ X,
    const unsigned short* __restrict__ Wq, const unsigned short* __restrict__ Wk,
    const unsigned short* __restrict__ Wv,
    const float* __restrict__ qb, const float* __restrict__ kb, const float* __restrict__ vb,
    unsigned short* __restrict__ Qo, unsigned short* __restrict__ Ko,
    unsigned short* __restrict__ Vtc, const int* __restrict__ nact)
{
  dev_qkv_tile(blockIdx.x, blockIdx.z, threadIdx.x, X, Wq,Wk,Wv, qb,kb,vb, Qo,Ko,Vtc, nact);
}

__global__ __launch_bounds__(256) void k_attn_part(
  const unsigned short* __restrict__ Q, const unsigned short* __restrict__ Kc,
  const unsigned short* __restrict__ Vtc, const int* __restrict__ nact,
  float* __restrict__ pacc, float* __restrict__ plr)
{
  __shared__ alignas(16) unsigned char smem[45056];
  dev_attn_part_task(blockIdx.x, blockIdx.y, blockIdx.z, threadIdx.x, smem,
                     Q, Kc, Vtc, nact, pacc, plr);
}

__global__ __launch_bounds__(256) void k_attn_fin(
  const float* __restrict__ pacc, const float* __restrict__ plr,
  const int* __restrict__ nact, const int* __restrict__ aidx,
  const unsigned short* __restrict__ Wct, const float* __restrict__ bc,
  float* __restrict__ out)
{
  __shared__ alignas(16) unsigned char smem[17408];
  dev_attn_fin_task(blockIdx.x, blockIdx.y, threadIdx.x, smem,
                    pacc, plr, nact, aidx, Wct, bc, out);
}

// ================= cooperative mega-kernel =================

struct MegaArgs {
  const void *x, *A, *eg;
  const void *w1, *b1, *w2, *b2, *tw, *tb;
  const void *qw, *qb0, *kw, *kb0, *vw, *vb0, *ow, *ob, *fw, *fb;
  int *nact, *cnt, *aidx, *inv, *edges;
  float* g; unsigned short* h; unsigned short* Vtc;
  unsigned short *W1t,*W2t,*Wqt,*Wkt,*Wvt,*Wct;
  float *qbf,*kbf,*vbf,*bcf,*b1f,*b2f;
  float *pacc,*plr;
  unsigned short *Qb,*Kb;
  float* out;
  int* bar;
};

__global__ __launch_bounds__(256, 3) void k_mega(MegaArgs a){
  __shared__ alignas(16) unsigned char smem[45056];
  const int tid = threadIdx.x, bid = blockIdx.x, G = gridDim.x;
  const int lane = tid & 63;

  // ---- Pd: redundant per-block dtype detection (36KB scan, L2-resident) ----
  // No grid barrier needed: every block computes md/mode itself.
  int md, mode;
  {
    int* sh = (int*)smem;            // [0]=cnt, [1]=pres, [2]=ge2
    if(tid < 3) sh[tid] = 0;
    __syncthreads();
    int c = 0;
    const unsigned short* xs = (const unsigned short*)a.x;
    for(int i=tid; i<6144; i+=256){
      unsigned short hh = xs[i*2];
      unsigned e = (hh >> 7) & 0xFF;
      if(hh==0 || (e >= 0x60 && e <= 0x9F)) c++;
    }
    if(c) atomicAdd(&sh[0], c);
    int pres=0, ge2=0;
    const unsigned char* egp = (const unsigned char*)a.eg;
    for(int i=tid; i<24576; i+=256){
      unsigned v = egp[i];
      if(v){ pres |= 1 << (i & 7); if(v >= 2u) ge2 = 1; }
    }
    if(pres) atomicOr(&sh[1], pres);
    if(ge2)  atomicOr(&sh[2], 1);
    __syncthreads();
    md = (sh[0] > 4000) ? 0 : 1;
    int pr = sh[1], g2 = sh[2];
    if(!g2){
      if((pr & ~0x01) == 0)      mode = 4;
      else if((pr & ~0x11) == 0) mode = 0;
      else                       mode = 1;
    } else {
      if((pr & ~0xC0) == 0)      mode = 5;
      else if((pr & ~0xCC) == 0) mode = 3;
      else                       mode = 2;
    }
    __syncthreads();
  }

  // ---- P0: mask decode (TM) + weight prep (82720) + out zero (196608 f4) ----
  {
    const int D0 = TM, D1 = TM + 82720, DTOT = D1 + OUTSZ/4;
    for(int base = bid*256; base < DTOT; base += G*256){
      int id = base + tid;
      if(id < D0){
        dev_mask_item(id, mode, lane, a.eg, a.cnt, a.nact, a.aidx, a.inv);
      } else if(id < D1){
        dev_prepw_item(id - D0, md, a.w1,a.w2,a.qw,a.kw,a.vw,a.qb0,a.kb0,a.vb0,
                       a.ow,a.ob,a.fw,a.fb,a.tw,a.tb,a.b1,a.b2,
                       a.W1t,a.W2t,a.Wqt,a.Wkt,a.Wvt,a.Wct,
                       a.qbf,a.kbf,a.vbf,a.bcf,a.b1f,a.b2f);
      } else if(id < DTOT){
        float4 z4; z4.x=0.f; z4.y=0.f; z4.z=0.f; z4.w=0.f;
        ((float4*)a.out)[id - D1] = z4;
      }
    }
  }
  gbar(a.bar, 1*G);

  // ---- P1: edges (6144 block-slices) + gemm_x (384 tiles) ----
  {
    const int EB = TM*64/256;   // 6144
    for(int task = bid; task < EB + 384; task += G){
      if(task < EB) dev_edges_item(task*256 + tid, md, a.A, a.inv, a.cnt, a.edges);
      else          dev_gemm_x_tile(task - EB, md, tid, a.x, a.nact, a.aidx, a.W1t, a.g);
    }
  }
  gbar(a.bar, 2*G);

  // ---- P2: gather1 ----
  {
    const int wv = tid >> 6;
    for(int task = bid; task < TM/4; task += G)
      dev_gather_task(task*4 + wv, lane, a.g, a.edges, a.cnt, a.nact, a.b1f, a.h);
  }
  gbar(a.bar, 3*G);

  // ---- P3: gemm_h ----
  for(int task = bid; task < TM/64; task += G)
    dev_gemm_h_tile(task, tid, a.h, a.W2t, a.g, a.nact);
  gbar(a.bar, 4*G);

  // ---- P4: gather2 ----
  {
    const int wv = tid >> 6;
    for(int task = bid; task < TM/4; task += G)
      dev_gather_task(task*4 + wv, lane, a.g, a.edges, a.cnt, a.nact, a.b2f, a.h);
  }
  gbar(a.bar, 5*G);

  // ---- P5: QKV ----
  for(int task = bid; task < 3*(TM/64); task += G)
    dev_qkv_tile(task % (TM/64), task / (TM/64), tid, a.h,
                 a.Wqt, a.Wkt, a.Wvt, a.qbf, a.kbf, a.vbf, a.Qb, a.Kb, a.Vtc, a.nact);
  gbar(a.bar, 6*G);

  // ---- P6: attention partials (768 tasks at KS=2 -> exactly one per block) ----
  for(int task = bid; task < 32*TT*KS; task += G){
    int qx = task / (TT*KS), rem = task % (TT*KS);
    dev_attn_part_task(qx, rem / KS, rem % KS, tid, smem,
                       a.Qb, a.Kb, a.Vtc, a.nact, a.pacc, a.plr);
  }
  gbar(a.bar, 7*G);

  // ---- P7: combine + projection ----
  for(int task = bid; task < 32*TT; task += G)
    dev_attn_fin_task(task / TT, task % TT, tid, smem,
                      a.pacc, a.plr, a.nact, a.aidx, a.Wct, a.bcf, a.out);
}

// ================= launch =================

extern "C" void kernel_launch(void* const* d_in, const int* in_sizes, int n_in,
                              void* d_out, int out_size, void* d_ws, size_t ws_size,
                              hipStream_t stream)
{
  float* outp = (float*)d_out;
  static const int EXP[19] = {1572864,50331648,24576,8192,128,16384,128,16,16,
                              18432,128,18432,128,18432,128,16384,128,4096,32};
  bool ok = (n_in >= 19) && (out_size == OUTSZ);
  if(ok) for(int i=0;i<19;i++) if(in_sizes[i] != EXP[i]) { ok = false; break; }
  if(!ok){
    k_fill<<<(out_size+255)/256,256,0,stream>>>(outp, out_size, 1000.f);
    return;
  }
  const void* x   = d_in[0];
  const void* A   = d_in[1];
  const void* eg  = d_in[2];
  const void* w1  = d_in[3];
  const void* b1  = d_in[4];
  const void* w2  = d_in[5];
  const void* b2  = d_in[6];
  const void* tw  = d_in[7];
  const void* tb  = d_in[8];
  const void* qw  = d_in[9];
  const void* qb0 = d_in[10];
  const void* kw  = d_in[11];
  const void* kb0 = d_in[12];
  const void* vw  = d_in[13];
  const void* vb0 = d_in[14];
  const void* ow  = d_in[15];
  const void* ob  = d_in[16];
  const void* fw  = d_in[17];
  const void* fb  = d_in[18];

  char* w = (char*)d_ws;
  size_t off = 0;
  auto alloc = [&](size_t sz)->char*{
    char* p = w + off; off = (off + sz + 255) & ~(size_t)255; return p; };
  int*   flag  = (int*)  alloc(4);
  int*   dtf   = (int*)  alloc(4);
  int*   barp  = (int*)  alloc(4);
  int*   nactb = (int*)  alloc(TT*4);
  int*   cnt   = (int*)  alloc((size_t)TM*4);
  int*   aidx  = (int*)  alloc((size_t)TM*4);
  int*   inv   = (int*)  alloc((size_t)TM*4);
  int*   edges = (int*)  alloc((size_t)TM*CAP*4);
  float* g     = (float*)alloc((size_t)TM*DH*4);   // reused as Qb+Kb after 2nd gather
  unsigned short* h   = (unsigned short*)alloc((size_t)TM*DH*2);
  unsigned short* Vtc = (unsigned short*)alloc((size_t)TT*DH*MM*2);
  unsigned short* W1t = (unsigned short*)alloc(DH*DIN*2);
  unsigned short* W2t = (unsigned short*)alloc(DH*DH*2);
  unsigned short* Wqt = (unsigned short*)alloc(DH*DH*2);
  unsigned short* Wkt = (unsigned short*)alloc(DH*DH*2);
  unsigned short* Wvt = (unsigned short*)alloc(DH*DH*2);
  unsigned short* Wct = (unsigned short*)alloc(DOUT*DH*2);
  float* qbf = (float*)alloc(TT*DH*4);
  float* kbf = (float*)alloc(TT*DH*4);
  float* vbf = (float*)alloc(TT*DH*4);
  float* bcf = (float*)alloc(DOUT*4);
  float* b1f = (float*)alloc(DH*4);
  float* b2f = (float*)alloc(DH*4);
  float* pacc = (float*)alloc((size_t)KS*TT*32*256*32*4);  // split-K PV partials (~25MB)
  float* plr  = (float*)alloc((size_t)KS*TT*32*256*4);     // split-K l partials
  if(off > ws_size){
    k_fill<<<(out_size+255)/256,256,0,stream>>>(outp, out_size, 500.f);
    return;
  }

  unsigned short* Qb = (unsigned short*)g;                       // TM*DH*2 bytes
  unsigned short* Kb = (unsigned short*)((char*)g + (size_t)TM*DH*2);

  // ---- preferred path: init + single cooperative kernel ----
  k_init<<<1,64,0,stream>>>(barp, nactb);

  MegaArgs ma;
  ma.x=x; ma.A=A; ma.eg=eg;
  ma.w1=w1; ma.b1=b1; ma.w2=w2; ma.b2=b2; ma.tw=tw; ma.tb=tb;
  ma.qw=qw; ma.qb0=qb0; ma.kw=kw; ma.kb0=kb0; ma.vw=vw; ma.vb0=vb0;
  ma.ow=ow; ma.ob=ob; ma.fw=fw; ma.fb=fb;
  ma.nact=nactb; ma.cnt=cnt; ma.aidx=aidx; ma.inv=inv; ma.edges=edges;
  ma.g=g; ma.h=h; ma.Vtc=Vtc;
  ma.W1t=W1t; ma.W2t=W2t; ma.Wqt=Wqt; ma.Wkt=Wkt; ma.Wvt=Wvt; ma.Wct=Wct;
  ma.qbf=qbf; ma.kbf=kbf; ma.vbf=vbf; ma.bcf=bcf; ma.b1f=b1f; ma.b2f=b2f;
  ma.pacc=pacc; ma.plr=plr; ma.Qb=Qb; ma.Kb=Kb; ma.out=outp;
  ma.bar=barp;
  void* kp[] = { (void*)&ma };
  hipError_t err = hipLaunchCooperativeKernel((const void*)k_mega,
                                              dim3(GRID), dim3(256), kp, 0, stream);
  if(err == hipSuccess) return;
  (void)hipGetLastError();   // clear error state; fall back to multi-kernel path

  // ---- fallback: verified round-1 pipeline (KS=2 variants) ----
  k_detect2<<<2,256,0,stream>>>((const unsigned short*)x, (const unsigned char*)eg,
                                dtf, flag, nactb);
  k_mask<<<OUTSZ/256,256,0,stream>>>(eg, flag, cnt, nactb, aidx, inv, outp);
  k_prep_edges<<<PWB + TM*64/256,256,0,stream>>>(w1,w2,qw,kw,vw,qb0,kb0,vb0,ow,ob,fw,fb,tw,tb,
                                                 b1,b2,dtf,
                                                 W1t,W2t,Wqt,Wkt,Wvt,Wct,qbf,kbf,vbf,bcf,b1f,b2f,
                                                 A, inv, cnt, edges);
  k_gemm_x<<<TM/64,256,0,stream>>>(x, dtf, nactb, aidx, W1t, g);
  k_gather<<<TM/4,256,0,stream>>>(g, edges, cnt, nactb, b1f, h);
  k_gemm_h<<<TM/64,256,0,stream>>>(h, W2t, g, nactb);
  k_gather<<<TM/4,256,0,stream>>>(g, edges, cnt, nactb, b2f, h);
  k_gemm_qkv<<<dim3(TM/64,1,3),256,0,stream>>>(h, Wqt,Wkt,Wvt, qbf,kbf,vbf, Qb,Kb,Vtc, nactb);
  k_attn_part<<<dim3(MM/64,TT,KS),256,0,stream>>>(Qb, Kb, Vtc, nactb, pacc, plr);
  k_attn_fin<<<dim3(MM/64,TT),256,0,stream>>>(pacc, plr, nactb, aidx, Wct, bcf, outp);
}

// Round 5
// 780.144 us; speedup vs baseline: 1.5976x; 1.1596x over previous
//
#include <hip/hip_runtime.h>
#include <stdint.h>

#define TT   12
#define BB   2
#define NN   1024
#define MM   2048
#define TM   24576      // TT*MM
#define DIN  64
#define DH   128
#define DOUT 32
#define CAP  64
#define OUTSZ 786432
#define KS   2          // split-K factor for attention
#define PWB  324        // prepw blocks inside merged prep_edges kernel (fallback path)
#define GBLK 64         // blocks per timestep group
#define GRID (TT*GBLK)  // 768 = 3 blocks/CU x 256 CUs (co-resident at 45KB LDS)

typedef __attribute__((ext_vector_type(8))) short short8;
typedef __attribute__((ext_vector_type(4))) short short4v;
typedef __attribute__((ext_vector_type(4))) float f32x4;

#define MFMA(a,b,c) __builtin_amdgcn_mfma_f32_16x16x32_bf16((a),(b),(c),0,0,0)

__device__ __forceinline__ float bf2f(unsigned short u){
  union { uint32_t i; float f; } x; x.i = ((uint32_t)u) << 16; return x.f;
}
__device__ __forceinline__ unsigned short f2bf(float f){
  union { float f; uint32_t i; } x; x.f = f;
  uint32_t u = x.i + 0x7FFFu + ((x.i >> 16) & 1u);   // RNE
  return (unsigned short)(u >> 16);
}
__device__ __forceinline__ float LD(const void* p, size_t i, int mode){
  return mode ? ((const float*)p)[i] : bf2f(((const unsigned short*)p)[i]);
}
// gather-load 8 input elements as bf16 (mode 1 = fp32 source)
__device__ __forceinline__ short8 ldx8(const void* x, size_t off, int md){
  if(md){
    const float4* xf = (const float4*)((const float*)x + off);
    float4 a = xf[0], b = xf[1];
    short8 o;
    o[0]=(short)f2bf(a.x); o[1]=(short)f2bf(a.y); o[2]=(short)f2bf(a.z); o[3]=(short)f2bf(a.w);
    o[4]=(short)f2bf(b.x); o[5]=(short)f2bf(b.y); o[6]=(short)f2bf(b.z); o[7]=(short)f2bf(b.w);
    return o;
  }
  return *(const short8*)((const unsigned short*)x + off);
}

// ---- lightweight agent-scope group barrier (verified under graph replay, r3) ----
// __syncthreads() drains the block; release fence (thread 0) writes the XCD L2
// back; relaxed polling avoids re-invalidating per poll; one acquire fence after
// the spin invalidates stale lines. Group-local: only GBLK arrivals per barrier.
__device__ __forceinline__ void gbar(int* bar, int target){
  __syncthreads();
  if(threadIdx.x == 0){
    __builtin_amdgcn_fence(__ATOMIC_RELEASE, "agent");
    __hip_atomic_fetch_add(bar, 1, __ATOMIC_RELAXED, __HIP_MEMORY_SCOPE_AGENT);
    while(__hip_atomic_load(bar, __ATOMIC_RELAXED, __HIP_MEMORY_SCOPE_AGENT) < target)
      __builtin_amdgcn_s_sleep(2);
    __builtin_amdgcn_fence(__ATOMIC_ACQUIRE, "agent");
  }
  __syncthreads();
}

// ================= shared per-item / per-tile device bodies =================

__device__ __forceinline__ void dev_mask_item(int idx, int mode, int lane,
    const void* egom, int* cnt, int* nact, int* aidx, int* inv){
  int t = idx / MM, node = idx % MM;               // wave = 64 consecutive nodes, one t
  int b = node / NN, n = node % NN;
  int src = (b*TT + t)*NN + n;
  int v;
  if(mode==0)      v = ((const int*)egom)[src] != 0;
  else if(mode==1) v = ((const unsigned char*)egom)[src] != 0;
  else if(mode==2) v = ((const unsigned short*)egom)[src] != 0;
  else if(mode==3) v = ((const float*)egom)[src] != 0.f;
  else if(mode==4) v = ((const long long*)egom)[src] != 0;
  else             v = ((const double*)egom)[src] != 0.0;
  cnt[idx] = 0;
  unsigned long long bal = __ballot(v != 0);
  int base = 0;
  if(lane == 0 && bal) base = atomicAdd(&nact[t], __popcll(bal));
  base = __shfl(base, 0, 64);
  int ic = -1;
  if(v){
    int pfx = __popcll(bal & ((1ULL << lane) - 1ULL));
    ic = base + pfx;
    aidx[(size_t)t*MM + ic] = node;
  }
  inv[idx] = ic;
}

__device__ __forceinline__ void dev_prepw_item(int id, int md,
  const void* w1, const void* w2,
  const void* qw, const void* kw, const void* vw,
  const void* qb0, const void* kb0, const void* vb0,
  const void* ow, const void* ob, const void* fw, const void* fb,
  const void* tw, const void* tb, const void* b1, const void* b2,
  unsigned short* W1t, unsigned short* W2t,
  unsigned short* Wqt, unsigned short* Wkt,
  unsigned short* Wvt, unsigned short* Wct,
  float* qbf, float* kbf, float* vbf,
  float* bcf, float* b1f, float* b2f)
{
  if(id < 8192){  // coalesced read: consecutive id -> consecutive n
    int n=id&127, k2=id>>7; W1t[n*64+k2]=f2bf(LD(w1,(size_t)k2*128+n,md)); return; }
  id -= 8192;
  if(id < 16384){ int n=id&127,k2=id>>7; W2t[n*128+k2]=f2bf(LD(w2,(size_t)k2*128+n,md)); return; }
  id -= 16384;
  if(id < 16384){ int n=id&127,k2=id>>7; Wqt[n*128+k2]=f2bf(LD(qw,(size_t)k2*128+n,md)); return; }
  id -= 16384;
  if(id < 16384){ int n=id&127,k2=id>>7; Wkt[n*128+k2]=f2bf(LD(kw,(size_t)k2*128+n,md)); return; }
  id -= 16384;
  if(id < 16384){ int n=id&127,k2=id>>7; Wvt[n*128+k2]=f2bf(LD(vw,(size_t)k2*128+n,md)); return; }
  id -= 16384;
  if(id < 4096){  // Wc = o_w @ fc_w, stored [oc][c]
    int oc=id&31, c=id>>5; float s=0.f;
    for(int r=0;r<128;r++) s += LD(ow,(size_t)c*128+r,md)*LD(fw,(size_t)r*32+oc,md);
    Wct[oc*128+c]=f2bf(s); return;
  }
  id -= 4096;
  if(id < 32){    // bc = o_b @ fc_w + fc_b
    float s = LD(fb,id,md);
    for(int r=0;r<128;r++) s += LD(ob,r,md)*LD(fw,(size_t)r*32+id,md);
    bcf[id]=s; return;
  }
  id -= 32;
  if(id < 4608){  // per-t fused QKV bias: b + t_vec @ W[128:144]
    int which = id/1536, rem=id%1536, t=rem/128, n=rem%128;
    const void* W  = which==0?qw:(which==1?kw:vw);
    const void* Bs = which==0?qb0:(which==1?kb0:vb0);
    float s = LD(Bs,n,md);
    for(int d=0;d<16;d++){
      float tv = sinf((float)t*LD(tw,d,md) + LD(tb,d,md));
      s += tv * LD(W,(size_t)(128+d)*128+n,md);
    }
    float* dst = which==0?qbf:(which==1?kbf:vbf);
    dst[t*128+n]=s; return;
  }
  id -= 4608;
  if(id < 256){   // GCN biases to fp32
    if(id<128) b1f[id] = LD(b1,id,md);
    else       b2f[id-128] = LD(b2,id-128,md);
    return;
  }
}

__device__ __forceinline__ void dev_edges_item(int id, int md,
    const void* A, const int* inv, int* cnt, int* edges){
  int seg = id & 63; int row = id >> 6;           // row = t*MM + j (orig)
  int t = row / MM;
  int jc = inv[row];
  if(jc < 0) return;                              // inactive source
  const int* invt = inv + (size_t)t*MM;
  int* cb = cnt + (size_t)t*MM;
  int* eb = edges + (size_t)t*MM*CAP;
  if(md){   // fp32 adjacency
    const float4* p4 = (const float4*)((const float*)A + (size_t)row*MM + seg*32);
    #pragma unroll
    for(int u=0;u<8;u++){
      float4 v = p4[u];
      float wd[4]={v.x,v.y,v.z,v.w};
      #pragma unroll
      for(int q=0;q<4;q++){
        if(wd[q]!=0.f){
          int ibc = invt[seg*32 + u*4 + q];
          if(ibc >= 0){ int s=atomicAdd(&cb[ibc],1); if(s<CAP) eb[(size_t)ibc*CAP+s]=jc; }
        }
      }
    }
  } else {    // bf16 adjacency
    const uint4* p4 = (const uint4*)((const unsigned short*)A + (size_t)row*MM + seg*32);
    #pragma unroll
    for(int u=0;u<4;u++){
      uint4 v = p4[u];
      unsigned wd[4]={v.x,v.y,v.z,v.w};
      #pragma unroll
      for(int q=0;q<4;q++){
        int ib = seg*32 + u*8 + q*2;
        if(wd[q] & 0xFFFFu){
          int ibc = invt[ib];
          if(ibc >= 0){ int s=atomicAdd(&cb[ibc],1); if(s<CAP) eb[(size_t)ibc*CAP+s]=jc; }
        }
        if(wd[q] >> 16){
          int ibc = invt[ib+1];
          if(ibc >= 0){ int s=atomicAdd(&cb[ibc],1); if(s<CAP) eb[(size_t)ibc*CAP+s]=jc; }
        }
      }
    }
  }
}

__device__ __forceinline__ void dev_gemm_x_tile(int tileIdx, int md, int tid,
    const void* x, const int* nact, const int* aidx,
    const unsigned short* Wt, float* g)
{
  const int tile = tileIdx*64;
  const int t = tile / MM, il = tile % MM;
  const int na = nact[t];
  if(il >= ((na+63)&~63)) return;
  const int wv=tid>>6, lane=tid&63, l15=lane&15, quad=lane>>4;
  const int r0 = tile + (wv>>1)*32;          // global compact row base
  const int c0 = (wv&1)*64;
  short8 bf[2][4];
  #pragma unroll
  for(int kk=0;kk<2;kk++)
    #pragma unroll
    for(int nt=0;nt<4;nt++)
      bf[kk][nt] = *(const short8*)(Wt + (size_t)(c0+nt*16+l15)*DIN + kk*32 + quad*8);
  const int il0 = (r0 % MM) + l15, il1 = (r0 % MM) + 16 + l15;
  const int n0 = aidx[(size_t)t*MM + (il0 < na ? il0 : 0)];
  const int n1 = aidx[(size_t)t*MM + (il1 < na ? il1 : 0)];
  const size_t xb0 = ((size_t)t*MM + n0)*DIN;
  const size_t xb1 = ((size_t)t*MM + n1)*DIN;
  f32x4 z = {0.f,0.f,0.f,0.f};
  f32x4 acc[2][4];
  #pragma unroll
  for(int i=0;i<2;i++){ acc[i][0]=z; acc[i][1]=z; acc[i][2]=z; acc[i][3]=z; }
  #pragma unroll
  for(int kk=0;kk<2;kk++){
    short8 a0 = ldx8(x, xb0 + kk*32 + quad*8, md);
    short8 a1 = ldx8(x, xb1 + kk*32 + quad*8, md);
    #pragma unroll
    for(int nt=0;nt<4;nt++){
      acc[0][nt]=MFMA(a0,bf[kk][nt],acc[0][nt]);
      acc[1][nt]=MFMA(a1,bf[kk][nt],acc[1][nt]);
    }
  }
  #pragma unroll
  for(int mt=0;mt<2;mt++)
    #pragma unroll
    for(int nt=0;nt<4;nt++){
      int col = c0+nt*16+l15;
      #pragma unroll
      for(int r=0;r<4;r++){
        int row = r0 + mt*16 + quad*4 + r;
        g[(size_t)row*DH + col] = acc[mt][nt][r];
      }
    }
}

__device__ __forceinline__ void dev_gemm_h_tile(int tileIdx, int tid,
    const unsigned short* X, const unsigned short* Wt, float* g, const int* nact)
{
  const int tile = tileIdx*64;
  const int t = tile / MM, il = tile % MM;
  const int na = nact[t];
  if(il >= ((na+63)&~63)) return;
  const int wv=tid>>6, lane=tid&63, l15=lane&15, quad=lane>>4;
  const int r0 = tile + (wv>>1)*32;
  const int c0 = (wv&1)*64;
  short8 bf[4][4];
  #pragma unroll
  for(int kk=0;kk<4;kk++)
    #pragma unroll
    for(int nt=0;nt<4;nt++)
      bf[kk][nt] = *(const short8*)(Wt + (size_t)(c0+nt*16+l15)*DH + kk*32 + quad*8);
  f32x4 z = {0.f,0.f,0.f,0.f};
  f32x4 acc[2][4];
  #pragma unroll
  for(int i=0;i<2;i++){ acc[i][0]=z; acc[i][1]=z; acc[i][2]=z; acc[i][3]=z; }
  #pragma unroll
  for(int kk=0;kk<4;kk++){
    short8 a0 = *(const short8*)(X + (size_t)(r0+l15)*DH    + kk*32 + quad*8);
    short8 a1 = *(const short8*)(X + (size_t)(r0+16+l15)*DH + kk*32 + quad*8);
    #pragma unroll
    for(int nt=0;nt<4;nt++){
      acc[0][nt]=MFMA(a0,bf[kk][nt],acc[0][nt]);
      acc[1][nt]=MFMA(a1,bf[kk][nt],acc[1][nt]);
    }
  }
  #pragma unroll
  for(int mt=0;mt<2;mt++)
    #pragma unroll
    for(int nt=0;nt<4;nt++){
      int col = c0+nt*16+l15;
      #pragma unroll
      for(int r=0;r<4;r++){
        int row = r0 + mt*16 + quad*4 + r;
        g[(size_t)row*DH + col] = acc[mt][nt][r];
      }
    }
}

__device__ __forceinline__ void dev_gather_task(int gi, int lane,
    const float* g, const int* edges, const int* cnt,
    const int* nact, const float* bias, unsigned short* h)
{
  int t = gi / MM, ic = gi % MM;
  int na = nact[t];
  if(ic >= ((na+63)&~63)) return;
  unsigned int* hp = (unsigned int*)(h + (size_t)gi*DH) + lane;
  if(ic >= na){ *hp = 0; return; }      // pad row: finite zeros
  float a0=0.f, a1=0.f;
  int cn = cnt[gi]; if(cn>CAP) cn=CAP;
  const int* eb = edges + (size_t)gi*CAP;
  #pragma unroll 2
  for(int e=0;e<cn;e++){
    int jc = eb[e];
    float nj = rsqrtf((float)cnt[(size_t)t*MM+jc] + 1.f);
    float2 gr2 = *(const float2*)(g + ((size_t)t*MM + jc)*DH + 2*lane);
    a0 += nj*gr2.x; a1 += nj*gr2.y;
  }
  float ni = rsqrtf((float)cn + 1.f);
  float2 gs2 = *(const float2*)(g + (size_t)gi*DH + 2*lane);
  float h0 = ni*(a0 + ni*gs2.x) + bias[2*lane];
  float h1 = ni*(a1 + ni*gs2.y) + bias[2*lane+1];
  h0 = h0>0.f?h0:0.f; h1 = h1>0.f?h1:0.f;
  *hp = (unsigned int)f2bf(h0) | ((unsigned int)f2bf(h1) << 16);
}

__device__ __forceinline__ void dev_qkv_tile(int tileIdx, int which, int tid,
    const unsigned short* X,
    const unsigned short* Wq, const unsigned short* Wk, const unsigned short* Wv,
    const float* qb, const float* kb, const float* vb,
    unsigned short* Qo, unsigned short* Ko, unsigned short* Vtc, const int* nact)
{
  const int tile = tileIdx*64;
  const int t = tile / MM, il = tile % MM;
  const int na = nact[t];
  if(il >= ((na+63)&~63)) return;
  const unsigned short* Wt = which==0?Wq:(which==1?Wk:Wv);
  const float* bias = which==0?qb:(which==1?kb:vb);
  const int wv=tid>>6, lane=tid&63, l15=lane&15, quad=lane>>4;
  const int r0 = tile + (wv>>1)*32;
  const int c0 = (wv&1)*64;
  short8 bf[4][4];
  #pragma unroll
  for(int kk=0;kk<4;kk++)
    #pragma unroll
    for(int nt=0;nt<4;nt++)
      bf[kk][nt] = *(const short8*)(Wt + (size_t)(c0+nt*16+l15)*DH + kk*32 + quad*8);
  f32x4 z = {0.f,0.f,0.f,0.f};
  f32x4 acc[2][4];
  #pragma unroll
  for(int i=0;i<2;i++){ acc[i][0]=z; acc[i][1]=z; acc[i][2]=z; acc[i][3]=z; }
  #pragma unroll
  for(int kk=0;kk<4;kk++){
    short8 a0 = *(const short8*)(X + (size_t)(r0+l15)*DH    + kk*32 + quad*8);
    short8 a1 = *(const short8*)(X + (size_t)(r0+16+l15)*DH + kk*32 + quad*8);
    #pragma unroll
    for(int nt=0;nt<4;nt++){
      acc[0][nt]=MFMA(a0,bf[kk][nt],acc[0][nt]);
      acc[1][nt]=MFMA(a1,bf[kk][nt],acc[1][nt]);
    }
  }
  if(which < 2){
    unsigned short* o = which==0 ? Qo : Ko;
    #pragma unroll
    for(int mt=0;mt<2;mt++)
      #pragma unroll
      for(int nt=0;nt<4;nt++){
        int col = c0+nt*16+l15;
        float bb = bias[t*DH+col];
        #pragma unroll
        for(int r=0;r<4;r++){
          int row = r0 + mt*16 + quad*4 + r;
          o[(size_t)row*DH + col] = f2bf(acc[mt][nt][r] + bb);
        }
      }
  } else {
    #pragma unroll
    for(int mt=0;mt<2;mt++)
      #pragma unroll
      for(int nt=0;nt<4;nt++){
        int col = c0+nt*16+l15;
        float bb = bias[t*DH+col];
        int node0 = il + (wv>>1)*32 + mt*16 + quad*4;   // compact local row
        short4v pk;
        #pragma unroll
        for(int r=0;r<4;r++) pk[r] = (short)f2bf(acc[mt][nt][r] + bb);
        *(short4v*)(Vtc + ((size_t)t*DH + col)*MM + node0) = pk;
      }
  }
}

// LDS layout (45056 B): Kl[64][136]us @0 (17408) | Vl[128][72]us @17408 (18432)
//                       | Pl[4][16][72]s @35840 (9216).  Al[4][16][136]s overlays @0.
__device__ __forceinline__ void dev_attn_part_task(int qx, int t, int s, int tid,
  unsigned char* smem,
  const unsigned short* Q, const unsigned short* Kc, const unsigned short* Vtc,
  const int* nact, float* pacc, float* plr)
{
  unsigned short (*Kl)[136] = (unsigned short(*)[136])smem;
  unsigned short (*Vl)[72]  = (unsigned short(*)[72])(smem + 17408);
  short (*Pl)[16][72]       = (short(*)[16][72])(smem + 35840);
  const int wv=tid>>6, lane=tid&63, l15=lane&15, quad=lane>>4;
  const int na = nact[t];
  const int qblk = qx*64;
  if(qblk >= na) return;                 // task-uniform exit (barriers are outside)
  const int qbase = qblk + wv*16;
  const float scale = 0.088388347648318447f;  // 1/sqrt(128)
  const int nkt = (na + 63) >> 6;

  short8 bq[4];
  #pragma unroll
  for(int kk=0;kk<4;kk++)
    bq[kk] = *(const short8*)(Q + ((size_t)t*MM + qbase + l15)*DH + kk*32 + quad*8);

  f32x4 zz = {0.f,0.f,0.f,0.f};
  f32x4 accPV[8];
  #pragma unroll
  for(int i=0;i<8;i++) accPV[i]=zz;
  float l_run = 0.f;

  const int srow = tid >> 2, sseg = tid & 3;   // K stage: 64 rows x 4 segs
  const int vch  = tid >> 1, vhalf = tid & 1;  // V stage: 128 ch x 2 halves

  short8 kreg[4], vreg[4];
  if(s < nkt){  // preload this split's first tile
    const unsigned short* gk = Kc + ((size_t)t*MM + s*64 + srow)*DH + sseg*32;
    const unsigned short* gv = Vtc + ((size_t)t*DH + vch)*MM + s*64 + vhalf*32;
    #pragma unroll
    for(int j=0;j<4;j++){ kreg[j] = *(const short8*)(gk + j*8);
                          vreg[j] = *(const short8*)(gv + j*8); }
  }

  for(int kt=s; kt<nkt; kt+=KS){
    const int key0 = kt*64;
    __syncthreads();   // previous tile fully consumed before restage
    {  // write prefetched registers to LDS
      short8* kd = (short8*)&Kl[srow][sseg*32];
      short8* vd = (short8*)&Vl[vch][vhalf*32];
      #pragma unroll
      for(int j=0;j<4;j++){ kd[j] = kreg[j]; vd[j] = vreg[j]; }
    }
    __syncthreads();
    if(kt+KS < nkt){   // issue next tile's global loads; overlap compute below
      const int key1 = key0 + KS*64;
      const unsigned short* gk = Kc + ((size_t)t*MM + key1 + srow)*DH + sseg*32;
      const unsigned short* gv = Vtc + ((size_t)t*DH + vch)*MM + key1 + vhalf*32;
      #pragma unroll
      for(int j=0;j<4;j++){ kreg[j] = *(const short8*)(gk + j*8);
                            vreg[j] = *(const short8*)(gv + j*8); }
    }
    // S^T = K · Q^T from LDS
    #pragma unroll
    for(int mt=0;mt<4;mt++){
      f32x4 sv4 = zz;
      #pragma unroll
      for(int kk=0;kk<4;kk++){
        short8 ak = *(const short8*)&Kl[mt*16+l15][kk*32 + quad*8];
        sv4 = MFMA(ak, bq[kk], sv4);
      }
      short4v pk;
      #pragma unroll
      for(int r=0;r<4;r++){
        float sv = fminf(fmaxf(sv4[r]*scale, -15.f), 15.f);
        float valid = (key0 + mt*16 + quad*4 + r < na) ? 1.f : 0.f;
        float p = __expf(sv) * valid;
        pk[r] = (short)f2bf(p);
        l_run += bf2f((unsigned short)pk[r]);
      }
      *(short4v*)&Pl[wv][l15][mt*16 + quad*4] = pk;
    }
    // PV from LDS
    #pragma unroll
    for(int kk=0;kk<2;kk++){
      short8 ap = *(const short8*)&Pl[wv][l15][kk*32 + quad*8];
      #pragma unroll
      for(int nt=0;nt<8;nt++){
        short8 bv = *(const short8*)&Vl[nt*16+l15][kk*32 + quad*8];
        accPV[nt] = MFMA(ap, bv, accPV[nt]);
      }
    }
  }
  // dump raw per-lane partials (coalesced, layout-agnostic)
  float* pb = pacc + ((((size_t)s*TT + t)*32 + qx)*256 + tid)*32;
  #pragma unroll
  for(int i=0;i<8;i++) *(f32x4*)(pb + i*4) = accPV[i];
  plr[(((size_t)s*TT + t)*32 + qx)*256 + tid] = l_run;
}

__device__ __forceinline__ void dev_attn_fin_task(int qx, int t, int tid,
  unsigned char* smem,
  const float* pacc, const float* plr,
  const int* nact, const int* aidx,
  const unsigned short* Wct, const float* bc, float* out)
{
  short (*Al)[16][136] = (short(*)[16][136])smem;   // per-wave slice, wave-private
  const int wv=tid>>6, lane=tid&63, l15=lane&15, quad=lane>>4;
  const int na = nact[t];
  const int qblk = qx*64;
  if(qblk >= na) return;
  const int qbase = qblk + wv*16;

  f32x4 zz = {0.f,0.f,0.f,0.f};
  f32x4 acc[8];
  #pragma unroll
  for(int i=0;i<8;i++) acc[i]=zz;
  float l_run = 0.f;
  #pragma unroll
  for(int s=0;s<KS;s++){
    const f32x4* p = (const f32x4*)(pacc + ((((size_t)s*TT + t)*32 + qx)*256 + tid)*32);
    #pragma unroll
    for(int i=0;i<8;i++) acc[i] += p[i];
    l_run += plr[(((size_t)s*TT + t)*32 + qx)*256 + tid];
  }
  l_run += __shfl_xor(l_run, 16, 64);
  l_run += __shfl_xor(l_run, 32, 64);

  #pragma unroll
  for(int nt=0;nt<8;nt++)
    #pragma unroll
    for(int r=0;r<4;r++){
      float av = fminf(fmaxf(acc[nt][r], -1e30f), 1e30f);
      Al[wv][quad*4+r][nt*16+l15] = (short)f2bf(av);
    }

  const int qc = qbase + l15;
  const bool qok = (qc < na);
  const float linv = (l_run > 0.f) ? 1.f/l_run : 0.f;
  const int node = aidx[(size_t)t*MM + (qok ? qc : 0)];
  #pragma unroll
  for(int mt2=0;mt2<2;mt2++){
    f32x4 d = zz;
    #pragma unroll
    for(int kk=0;kk<4;kk++){
      short8 aw = *(const short8*)(Wct + (size_t)(mt2*16+l15)*DH + kk*32 + quad*8);
      short8 bl = *(const short8*)&Al[wv][l15][kk*32 + quad*8];
      d = MFMA(aw, bl, d);
    }
    f32x4 bcv = *(const f32x4*)(bc + mt2*16 + quad*4);
    f32x4 o4;
    #pragma unroll
    for(int r=0;r<4;r++) o4[r] = d[r]*linv + bcv[r];
    if(qok)
      *(f32x4*)(out + (size_t)node*(TT*DOUT) + (size_t)t*DOUT + mt2*16 + quad*4) = o4;
  }
}

// ================= standalone kernels (init + fallback path) =================

__global__ void k_fill(float* __restrict__ out, int n, float val){
  int i = blockIdx.x*blockDim.x + threadIdx.x;
  if(i < n) out[i] = val;
}

__global__ void k_init(int* __restrict__ bar, int* __restrict__ nact){
  if(threadIdx.x < TT*16) bar[threadIdx.x] = 0;
  if(threadIdx.x < TT) nact[threadIdx.x] = 0;
}

__global__ void k_detect2(const unsigned short* __restrict__ x,
                          const unsigned char* __restrict__ eg,
                          int* __restrict__ dtf, int* __restrict__ flag,
                          int* __restrict__ nact){
  if(blockIdx.x == 0){
    __shared__ int cnt_s;
    if(threadIdx.x==0) cnt_s = 0;
    if(threadIdx.x < TT) nact[threadIdx.x] = 0;
    __syncthreads();
    int c = 0;
    for(int i=threadIdx.x; i<6144; i+=blockDim.x){
      unsigned short h = x[i*2];
      unsigned e = (h >> 7) & 0xFF;
      if(h==0 || (e >= 0x60 && e <= 0x9F)) c++;
    }
    atomicAdd(&cnt_s, c);
    __syncthreads();
    if(threadIdx.x==0) *dtf = (cnt_s > 4000) ? 0 : 1;   // 0=bf16, 1=fp32
  } else {
    __shared__ int pres_s, ge2_s;
    if(threadIdx.x==0){ pres_s=0; ge2_s=0; }
    __syncthreads();
    int pres=0, ge2=0;
    for(int i=threadIdx.x; i<24576; i+=blockDim.x){
      unsigned v = eg[i];
      if(v){ pres |= 1 << (i & 7); if(v >= 2u) ge2 = 1; }
    }
    if(pres) atomicOr(&pres_s, pres);
    if(ge2)  atomicOr(&ge2_s, 1);
    __syncthreads();
    if(threadIdx.x==0){
      int pr = pres_s, g2 = ge2_s, mode;
      if(!g2){
        if((pr & ~0x01) == 0)      mode = 4;   // i64
        else if((pr & ~0x11) == 0) mode = 0;   // i32
        else                       mode = 1;   // u8
      } else {
        if((pr & ~0xC0) == 0)      mode = 5;   // f64
        else if((pr & ~0xCC) == 0) mode = 3;   // f32
        else                       mode = 2;   // bf16
      }
      *flag = mode;
    }
  }
}

__global__ void k_mask(const void* __restrict__ egom, const int* __restrict__ flag,
                       int* __restrict__ cnt, int* __restrict__ nact,
                       int* __restrict__ aidx, int* __restrict__ inv,
                       float* __restrict__ out){
  int idx = blockIdx.x*blockDim.x + threadIdx.x;   // < OUTSZ
  out[idx] = 0.f;
  if(idx >= TM) return;
  dev_mask_item(idx, *flag, threadIdx.x & 63, egom, cnt, nact, aidx, inv);
}

__global__ __launch_bounds__(256) void k_prep_edges(
  const void* __restrict__ w1, const void* __restrict__ w2,
  const void* __restrict__ qw, const void* __restrict__ kw, const void* __restrict__ vw,
  const void* __restrict__ qb0, const void* __restrict__ kb0, const void* __restrict__ vb0,
  const void* __restrict__ ow, const void* __restrict__ ob,
  const void* __restrict__ fw, const void* __restrict__ fb,
  const void* __restrict__ tw, const void* __restrict__ tb,
  const void* __restrict__ b1, const void* __restrict__ b2,
  const int* __restrict__ dtf,
  unsigned short* __restrict__ W1t, unsigned short* __restrict__ W2t,
  unsigned short* __restrict__ Wqt, unsigned short* __restrict__ Wkt,
  unsigned short* __restrict__ Wvt, unsigned short* __restrict__ Wct,
  float* __restrict__ qbf, float* __restrict__ kbf, float* __restrict__ vbf,
  float* __restrict__ bcf, float* __restrict__ b1f, float* __restrict__ b2f,
  const void* __restrict__ A, const int* __restrict__ inv,
  int* __restrict__ cnt, int* __restrict__ edges)
{
  const int md = *dtf;
  if(blockIdx.x < PWB){
    int id = blockIdx.x*blockDim.x + threadIdx.x;
    dev_prepw_item(id, md, w1,w2,qw,kw,vw,qb0,kb0,vb0,ow,ob,fw,fb,tw,tb,b1,b2,
                   W1t,W2t,Wqt,Wkt,Wvt,Wct,qbf,kbf,vbf,bcf,b1f,b2f);
  } else {
    int id = (blockIdx.x - PWB)*blockDim.x + threadIdx.x;
    dev_edges_item(id, md, A, inv, cnt, edges);
  }
}

__global__ __launch_bounds__(256) void k_gemm_x(const void* __restrict__ x,
    const int* __restrict__ dtf, const int* __restrict__ nact,
    const int* __restrict__ aidx, const unsigned short* __restrict__ Wt,
    float* __restrict__ g)
{
  dev_gemm_x_tile(blockIdx.x, *dtf, threadIdx.x, x, nact, aidx, Wt, g);
}

__global__ __launch_bounds__(256) void k_gemm_h(const unsigned short* __restrict__ X,
    const unsigned short* __restrict__ Wt, float* __restrict__ g,
    const int* __restrict__ nact)
{
  dev_gemm_h_tile(blockIdx.x, threadIdx.x, X, Wt, g, nact);
}

__global__ __launch_bounds__(256) void k_gather(const float* __restrict__ g,
    const int* __restrict__ edges, const int* __restrict__ cnt,
    const int* __restrict__ nact, const float* __restrict__ bias,
    unsigned short* __restrict__ h)
{
  int wv = threadIdx.x>>6, lane = threadIdx.x&63;
  dev_gather_task(blockIdx.x*4 + wv, lane, g, edges, cnt, nact, bias, h);
}

__global__ __launch_bounds__(256) void k_gemm_qkv(const unsigned short* __restrict__ X,
    const unsigned short* __restrict__ Wq, const unsigned short* __restrict__ Wk,
    const unsigned short* __restrict__ Wv,
    const float* __restrict__ qb, const float* __restrict__ kb, const float* __restrict__ vb,
    unsigned short* __restrict__ Qo, unsigned short* __restrict__ Ko,
    unsigned short* __restrict__ Vtc, const int* __restrict__ nact)
{
  dev_qkv_tile(blockIdx.x, blockIdx.z, threadIdx.x, X, Wq,Wk,Wv, qb,kb,vb, Qo,Ko,Vtc, nact);
}

__global__ __launch_bounds__(256) void k_attn_part(
  const unsigned short* __restrict__ Q, const unsigned short* __restrict__ Kc,
  const unsigned short* __restrict__ Vtc, const int* __restrict__ nact,
  float* __restrict__ pacc, float* __restrict__ plr)
{
  __shared__ alignas(16) unsigned char smem[45056];
  dev_attn_part_task(blockIdx.x, blockIdx.y, blockIdx.z, threadIdx.x, smem,
                     Q, Kc, Vtc, nact, pacc, plr);
}

__global__ __launch_bounds__(256) void k_attn_fin(
  const float* __restrict__ pacc, const float* __restrict__ plr,
  const int* __restrict__ nact, const int* __restrict__ aidx,
  const unsigned short* __restrict__ Wct, const float* __restrict__ bc,
  float* __restrict__ out)
{
  __shared__ alignas(16) unsigned char smem[17408];
  dev_attn_fin_task(blockIdx.x, blockIdx.y, threadIdx.x, smem,
                    pacc, plr, nact, aidx, Wct, bc, out);
}

// ================= cooperative per-timestep-group kernel =================

struct MegaArgs {
  const void *x, *A, *eg;
  const void *w1, *b1, *w2, *b2, *tw, *tb;
  const void *qw, *qb0, *kw, *kb0, *vw, *vb0, *ow, *ob, *fw, *fb;
  int *nact, *cnt, *aidx, *inv, *edges;
  float* g; unsigned short* h; unsigned short* Vtc;
  unsigned short *W1t,*W2t,*Wqt,*Wkt,*Wvt,*Wct;
  float *qbf,*kbf,*vbf,*bcf,*b1f,*b2f;
  float *pacc,*plr;
  unsigned short *Qb,*Kb;   // DEDICATED buffers (round-4 bug: overlaying g raced
                            // across de-phased groups; group t's Qb/Kb bytes land
                            // inside other groups' live g rows)
  float* out;
  int* bar;   // TT counters, padded to 64B stride (bar[t*16])
};

// 12 independent per-t pipelines; group t = blocks [t*GBLK, (t+1)*GBLK).
// Group-local barriers only -> groups de-phase and overlap each other's
// latency-bound phases (the round-3 global-lockstep pathology).
__global__ __launch_bounds__(256, 3) void k_tg(MegaArgs a){
  __shared__ alignas(16) unsigned char smem[45056];
  const int tid = threadIdx.x, bid = blockIdx.x;
  const int t = bid / GBLK, lb = bid % GBLK;
  const int lane = tid & 63;
  int* bar = a.bar + t*16;

  // ---- Pd: redundant per-block dtype detection (36KB, L2-resident) ----
  int md, mode;
  {
    int* sh = (int*)smem;            // [0]=cnt, [1]=pres, [2]=ge2
    if(tid < 3) sh[tid] = 0;
    __syncthreads();
    int c = 0;
    const unsigned short* xs = (const unsigned short*)a.x;
    for(int i=tid; i<6144; i+=256){
      unsigned short hh = xs[i*2];
      unsigned e = (hh >> 7) & 0xFF;
      if(hh==0 || (e >= 0x60 && e <= 0x9F)) c++;
    }
    if(c) atomicAdd(&sh[0], c);
    int pres=0, ge2=0;
    const unsigned char* egp = (const unsigned char*)a.eg;
    for(int i=tid; i<24576; i+=256){
      unsigned v = egp[i];
      if(v){ pres |= 1 << (i & 7); if(v >= 2u) ge2 = 1; }
    }
    if(pres) atomicOr(&sh[1], pres);
    if(ge2)  atomicOr(&sh[2], 1);
    __syncthreads();
    md = (sh[0] > 4000) ? 0 : 1;
    int pr = sh[1], g2 = sh[2];
    if(!g2){
      if((pr & ~0x01) == 0)      mode = 4;
      else if((pr & ~0x11) == 0) mode = 0;
      else                       mode = 1;
    } else {
      if((pr & ~0xC0) == 0)      mode = 5;
      else if((pr & ~0xCC) == 0) mode = 3;
      else                       mode = 2;
    }
    __syncthreads();
  }

  // ---- P0: own-t mask (2048) + out-zero t-slice (16384 f4) + prepw (82720) ----
  // prepw is redundant per group: identical-value stores, benign race.
  {
    const int D0 = MM, D1 = MM + OUTSZ/(4*TT), D2 = D1 + 82720;
    for(int base = lb*256; base < D2; base += GBLK*256){
      int id = base + tid;
      if(id < D0){
        dev_mask_item(t*MM + id, mode, lane, a.eg, a.cnt, a.nact, a.aidx, a.inv);
      } else if(id < D1){
        int zid = id - D0;                      // node = zid/8, chunk = zid%8
        f32x4 z4 = {0.f,0.f,0.f,0.f};
        ((f32x4*)a.out)[(size_t)(zid>>3)*(TT*DOUT/4) + t*(DOUT/4) + (zid&7)] = z4;
      } else if(id < D2){
        dev_prepw_item(id - D1, md, a.w1,a.w2,a.qw,a.kw,a.vw,a.qb0,a.kb0,a.vb0,
                       a.ow,a.ob,a.fw,a.fb,a.tw,a.tb,a.b1,a.b2,
                       a.W1t,a.W2t,a.Wqt,a.Wkt,a.Wvt,a.Wct,
                       a.qbf,a.kbf,a.vbf,a.bcf,a.b1f,a.b2f);
      }
    }
  }
  gbar(bar, 1*GBLK);

  // ---- P1: own-t edges (512 tasks) + gemm_x (32 tiles) ----
  for(int task = lb; task < 512 + 32; task += GBLK){
    if(task < 512) dev_edges_item(t*(MM*64) + task*256 + tid, md, a.A, a.inv, a.cnt, a.edges);
    else           dev_gemm_x_tile(t*32 + (task-512), md, tid, a.x, a.nact, a.aidx, a.W1t, a.g);
  }
  gbar(bar, 2*GBLK);

  // ---- P2: gather1 (512 tasks) ----
  {
    const int wv = tid >> 6;
    for(int task = lb; task < 512; task += GBLK)
      dev_gather_task(t*MM + task*4 + wv, lane, a.g, a.edges, a.cnt, a.nact, a.b1f, a.h);
  }
  gbar(bar, 3*GBLK);

  // ---- P3: gemm_h (32 tiles) ----
  if(lb < 32) dev_gemm_h_tile(t*32 + lb, tid, a.h, a.W2t, a.g, a.nact);
  gbar(bar, 4*GBLK);

  // ---- P4: gather2 ----
  {
    const int wv = tid >> 6;
    for(int task = lb; task < 512; task += GBLK)
      dev_gather_task(t*MM + task*4 + wv, lane, a.g, a.edges, a.cnt, a.nact, a.b2f, a.h);
  }
  gbar(bar, 5*GBLK);

  // ---- P5: QKV (96 tiles) ----
  for(int task = lb; task < 96; task += GBLK)
    dev_qkv_tile(t*32 + (task & 31), task >> 5, tid, a.h,
                 a.Wqt, a.Wkt, a.Wvt, a.qbf, a.kbf, a.vbf, a.Qb, a.Kb, a.Vtc, a.nact);
  gbar(bar, 6*GBLK);

  // ---- P6: attention partials (32 qx x KS=2 -> exactly one per block) ----
  dev_attn_part_task(lb >> 1, t, lb & 1, tid, smem,
                     a.Qb, a.Kb, a.Vtc, a.nact, a.pacc, a.plr);
  gbar(bar, 7*GBLK);

  // ---- P7: combine + projection (32 tasks) ----
  if(lb < 32)
    dev_attn_fin_task(lb, t, tid, smem,
                      a.pacc, a.plr, a.nact, a.aidx, a.Wct, a.bcf, a.out);
}

// ================= launch =================

extern "C" void kernel_launch(void* const* d_in, const int* in_sizes, int n_in,
                              void* d_out, int out_size, void* d_ws, size_t ws_size,
                              hipStream_t stream)
{
  float* outp = (float*)d_out;
  static const int EXP[19] = {1572864,50331648,24576,8192,128,16384,128,16,16,
                              18432,128,18432,128,18432,128,16384,128,4096,32};
  bool ok = (n_in >= 19) && (out_size == OUTSZ);
  if(ok) for(int i=0;i<19;i++) if(in_sizes[i] != EXP[i]) { ok = false; break; }
  if(!ok){
    k_fill<<<(out_size+255)/256,256,0,stream>>>(outp, out_size, 1000.f);
    return;
  }
  const void* x   = d_in[0];
  const void* A   = d_in[1];
  const void* eg  = d_in[2];
  const void* w1  = d_in[3];
  const void* b1  = d_in[4];
  const void* w2  = d_in[5];
  const void* b2  = d_in[6];
  const void* tw  = d_in[7];
  const void* tb  = d_in[8];
  const void* qw  = d_in[9];
  const void* qb0 = d_in[10];
  const void* kw  = d_in[11];
  const void* kb0 = d_in[12];
  const void* vw  = d_in[13];
  const void* vb0 = d_in[14];
  const void* ow  = d_in[15];
  const void* ob  = d_in[16];
  const void* fw  = d_in[17];
  const void* fb  = d_in[18];

  char* w = (char*)d_ws;
  size_t off = 0;
  auto alloc = [&](size_t sz)->char*{
    char* p = w + off; off = (off + sz + 255) & ~(size_t)255; return p; };
  int*   flag  = (int*)  alloc(4);
  int*   dtf   = (int*)  alloc(4);
  int*   barp  = (int*)  alloc(TT*16*4);
  int*   nactb = (int*)  alloc(TT*4);
  int*   cnt   = (int*)  alloc((size_t)TM*4);
  int*   aidx  = (int*)  alloc((size_t)TM*4);
  int*   inv   = (int*)  alloc((size_t)TM*4);
  int*   edges = (int*)  alloc((size_t)TM*CAP*4);
  float* g     = (float*)alloc((size_t)TM*DH*4);
  unsigned short* h   = (unsigned short*)alloc((size_t)TM*DH*2);
  unsigned short* Vtc = (unsigned short*)alloc((size_t)TT*DH*MM*2);
  unsigned short* Qbuf = (unsigned short*)alloc((size_t)TM*DH*2);  // dedicated (r4 fix)
  unsigned short* Kbuf = (unsigned short*)alloc((size_t)TM*DH*2);  // dedicated (r4 fix)
  unsigned short* W1t = (unsigned short*)alloc(DH*DIN*2);
  unsigned short* W2t = (unsigned short*)alloc(DH*DH*2);
  unsigned short* Wqt = (unsigned short*)alloc(DH*DH*2);
  unsigned short* Wkt = (unsigned short*)alloc(DH*DH*2);
  unsigned short* Wvt = (unsigned short*)alloc(DH*DH*2);
  unsigned short* Wct = (unsigned short*)alloc(DOUT*DH*2);
  float* qbf = (float*)alloc(TT*DH*4);
  float* kbf = (float*)alloc(TT*DH*4);
  float* vbf = (float*)alloc(TT*DH*4);
  float* bcf = (float*)alloc(DOUT*4);
  float* b1f = (float*)alloc(DH*4);
  float* b2f = (float*)alloc(DH*4);
  float* pacc = (float*)alloc((size_t)KS*TT*32*256*32*4);  // split-K PV partials (~25MB)
  float* plr  = (float*)alloc((size_t)KS*TT*32*256*4);     // split-K l partials
  if(off > ws_size){
    k_fill<<<(out_size+255)/256,256,0,stream>>>(outp, out_size, 500.f);
    return;
  }

  // ---- preferred path: init + single cooperative kernel (per-t groups) ----
  k_init<<<1,256,0,stream>>>(barp, nactb);

  MegaArgs ma;
  ma.x=x; ma.A=A; ma.eg=eg;
  ma.w1=w1; ma.b1=b1; ma.w2=w2; ma.b2=b2; ma.tw=tw; ma.tb=tb;
  ma.qw=qw; ma.qb0=qb0; ma.kw=kw; ma.kb0=kb0; ma.vw=vw; ma.vb0=vb0;
  ma.ow=ow; ma.ob=ob; ma.fw=fw; ma.fb=fb;
  ma.nact=nactb; ma.cnt=cnt; ma.aidx=aidx; ma.inv=inv; ma.edges=edges;
  ma.g=g; ma.h=h; ma.Vtc=Vtc;
  ma.W1t=W1t; ma.W2t=W2t; ma.Wqt=Wqt; ma.Wkt=Wkt; ma.Wvt=Wvt; ma.Wct=Wct;
  ma.qbf=qbf; ma.kbf=kbf; ma.vbf=vbf; ma.bcf=bcf; ma.b1f=b1f; ma.b2f=b2f;
  ma.pacc=pacc; ma.plr=plr; ma.Qb=Qbuf; ma.Kb=Kbuf; ma.out=outp;
  ma.bar=barp;
  void* kp[] = { (void*)&ma };
  hipError_t err = hipLaunchCooperativeKernel((const void*)k_tg,
                                              dim3(GRID), dim3(256), kp, 0, stream);
  if(err == hipSuccess) return;
  (void)hipGetLastError();   // clear error state; fall back to multi-kernel path

  // ---- fallback: verified round-1 pipeline (KS=2 variants) ----
  k_detect2<<<2,256,0,stream>>>((const unsigned short*)x, (const unsigned char*)eg,
                                dtf, flag, nactb);
  k_mask<<<OUTSZ/256,256,0,stream>>>(eg, flag, cnt, nactb, aidx, inv, outp);
  k_prep_edges<<<PWB + TM*64/256,256,0,stream>>>(w1,w2,qw,kw,vw,qb0,kb0,vb0,ow,ob,fw,fb,tw,tb,
                                                 b1,b2,dtf,
                                                 W1t,W2t,Wqt,Wkt,Wvt,Wct,qbf,kbf,vbf,bcf,b1f,b2f,
                                                 A, inv, cnt, edges);
  k_gemm_x<<<TM/64,256,0,stream>>>(x, dtf, nactb, aidx, W1t, g);
  k_gather<<<TM/4,256,0,stream>>>(g, edges, cnt, nactb, b1f, h);
  k_gemm_h<<<TM/64,256,0,stream>>>(h, W2t, g, nactb);
  k_gather<<<TM/4,256,0,stream>>>(g, edges, cnt, nactb, b2f, h);
  k_gemm_qkv<<<dim3(TM/64,1,3),256,0,stream>>>(h, Wqt,Wkt,Wvt, qbf,kbf,vbf, Qbuf,Kbuf,Vtc, nactb);
  k_attn_part<<<dim3(MM/64,TT,KS),256,0,stream>>>(Qbuf, Kbuf, Vtc, nactb, pacc, plr);
  k_attn_fin<<<dim3(MM/64,TT),256,0,stream>>>(pacc, plr, nactb, aidx, Wct, bcf, outp);
}

// Round 6
// 491.477 us; speedup vs baseline: 2.5360x; 1.5873x over previous
//
#include <hip/hip_runtime.h>
#include <stdint.h>

#define TT   12
#define BB   2
#define NN   1024
#define MM   2048
#define TM   24576      // TT*MM
#define DIN  64
#define DH   128
#define DOUT 32
#define CAP  64
#define OUTSZ 786432
#define PWB  292        // prepw blocks (74528 items / 256) inside k_pex

typedef __attribute__((ext_vector_type(8))) short short8;
typedef __attribute__((ext_vector_type(4))) short short4v;
typedef __attribute__((ext_vector_type(4))) float f32x4;

#define MFMA(a,b,c) __builtin_amdgcn_mfma_f32_16x16x32_bf16((a),(b),(c),0,0,0)

__device__ __forceinline__ float bf2f(unsigned short u){
  union { uint32_t i; float f; } x; x.i = ((uint32_t)u) << 16; return x.f;
}
__device__ __forceinline__ unsigned short f2bf(float f){
  union { float f; uint32_t i; } x; x.f = f;
  uint32_t u = x.i + 0x7FFFu + ((x.i >> 16) & 1u);   // RNE
  return (unsigned short)(u >> 16);
}
__device__ __forceinline__ float LD(const void* p, size_t i, int mode){
  return mode ? ((const float*)p)[i] : bf2f(((const unsigned short*)p)[i]);
}
// gather-load 8 input elements as bf16 (mode 1 = fp32 source)
__device__ __forceinline__ short8 ldx8(const void* x, size_t off, int md){
  if(md){
    const float4* xf = (const float4*)((const float*)x + off);
    float4 a = xf[0], b = xf[1];
    short8 o;
    o[0]=(short)f2bf(a.x); o[1]=(short)f2bf(a.y); o[2]=(short)f2bf(a.z); o[3]=(short)f2bf(a.w);
    o[4]=(short)f2bf(b.x); o[5]=(short)f2bf(b.y); o[6]=(short)f2bf(b.z); o[7]=(short)f2bf(b.w);
    return o;
  }
  return *(const short8*)((const unsigned short*)x + off);
}

// ---------------- fill (fp32, sentinels only) ----------------
__global__ void k_fill(float* __restrict__ out, int n, float val){
  int i = blockIdx.x*blockDim.x + threadIdx.x;
  if(i < n) out[i] = val;
}

// ---------------- L1: mask decode (1 block per t, deterministic prefix) + out zero ----------------
// Blocks 0..TT-1: per-block redundant mask-dtype detect (24KB eg scan, L2) then
// LDS-prefix compaction of the 2048 nodes of timestep t -- no global atomics,
// so nact needs no pre-zero (plain store at the end). All 3072 blocks zero out.
__global__ __launch_bounds__(256) void k_maskdet(
    const void* __restrict__ egom,
    int* __restrict__ cnt, int* __restrict__ nact,
    int* __restrict__ aidx, int* __restrict__ inv,
    float* __restrict__ out)
{
  const int bid = blockIdx.x, tid = threadIdx.x;
  out[(size_t)bid*256 + tid] = 0.f;          // inactive nodes stay 0
  if(bid >= TT) return;
  const int t = bid, lane = tid & 63, wv = tid >> 6;

  __shared__ int pres_s, ge2_s, wcnt_s[4];
  if(tid == 0){ pres_s = 0; ge2_s = 0; }
  __syncthreads();
  {
    int pres = 0, ge2 = 0;
    const unsigned char* egp = (const unsigned char*)egom;
    for(int i = tid; i < 24576; i += 256){
      unsigned v = egp[i];
      if(v){ pres |= 1 << (i & 7); if(v >= 2u) ge2 = 1; }
    }
    if(pres) atomicOr(&pres_s, pres);
    if(ge2)  atomicOr(&ge2_s, 1);
  }
  __syncthreads();
  int mode;
  {
    int pr = pres_s, g2 = ge2_s;
    if(!g2){
      if((pr & ~0x01) == 0)      mode = 4;   // i64
      else if((pr & ~0x11) == 0) mode = 0;   // i32
      else                       mode = 1;   // u8
    } else {
      if((pr & ~0xC0) == 0)      mode = 5;   // f64
      else if((pr & ~0xCC) == 0) mode = 3;   // f32
      else                       mode = 2;   // bf16
    }
  }

  int base = 0;                              // uniform running prefix (register)
  for(int r = 0; r < 8; r++){
    int node = r*256 + tid;
    int b = node / NN, n = node % NN;
    int src = (b*TT + t)*NN + n;
    int v;
    if(mode==0)      v = ((const int*)egom)[src] != 0;
    else if(mode==1) v = ((const unsigned char*)egom)[src] != 0;
    else if(mode==2) v = ((const unsigned short*)egom)[src] != 0;
    else if(mode==3) v = ((const float*)egom)[src] != 0.f;
    else if(mode==4) v = ((const long long*)egom)[src] != 0;
    else             v = ((const double*)egom)[src] != 0.0;
    cnt[(size_t)t*MM + node] = 0;
    unsigned long long bal = __ballot(v != 0);
    if(lane == 0) wcnt_s[wv] = __popcll(bal);
    __syncthreads();
    int mybase = base;
    for(int w2 = 0; w2 < wv; w2++) mybase += wcnt_s[w2];
    int ic = -1;
    if(v){
      ic = mybase + __popcll(bal & ((1ULL << lane) - 1ULL));
      aidx[(size_t)t*MM + ic] = node;
    }
    inv[(size_t)t*MM + node] = ic;
    base += wcnt_s[0] + wcnt_s[1] + wcnt_s[2] + wcnt_s[3];
    __syncthreads();                        // protect wcnt_s before next round
  }
  if(tid == 0) nact[t] = base;
}

// ================= device bodies (verbatim from verified round-1 code) =================

// weight prep WITHOUT the W1t segment (gemm_x reads w1 directly now). 74528 items.
__device__ __forceinline__ void dev_prepw2_item(int id, int md,
  const void* w2,
  const void* qw, const void* kw, const void* vw,
  const void* qb0, const void* kb0, const void* vb0,
  const void* ow, const void* ob, const void* fw, const void* fb,
  const void* tw, const void* tb, const void* b1, const void* b2,
  unsigned short* W2t,
  unsigned short* Wqt, unsigned short* Wkt,
  unsigned short* Wvt, unsigned short* Wct,
  float* qbf, float* kbf, float* vbf,
  float* bcf, float* b1f, float* b2f)
{
  if(id < 16384){ int n=id&127,k2=id>>7; W2t[n*128+k2]=f2bf(LD(w2,(size_t)k2*128+n,md)); return; }
  id -= 16384;
  if(id < 16384){ int n=id&127,k2=id>>7; Wqt[n*128+k2]=f2bf(LD(qw,(size_t)k2*128+n,md)); return; }
  id -= 16384;
  if(id < 16384){ int n=id&127,k2=id>>7; Wkt[n*128+k2]=f2bf(LD(kw,(size_t)k2*128+n,md)); return; }
  id -= 16384;
  if(id < 16384){ int n=id&127,k2=id>>7; Wvt[n*128+k2]=f2bf(LD(vw,(size_t)k2*128+n,md)); return; }
  id -= 16384;
  if(id < 4096){  // Wc = o_w @ fc_w, stored [oc][c]
    int oc=id&31, c=id>>5; float s=0.f;
    for(int r=0;r<128;r++) s += LD(ow,(size_t)c*128+r,md)*LD(fw,(size_t)r*32+oc,md);
    Wct[oc*128+c]=f2bf(s); return;
  }
  id -= 4096;
  if(id < 32){    // bc = o_b @ fc_w + fc_b
    float s = LD(fb,id,md);
    for(int r=0;r<128;r++) s += LD(ob,r,md)*LD(fw,(size_t)r*32+id,md);
    bcf[id]=s; return;
  }
  id -= 32;
  if(id < 4608){  // per-t fused QKV bias: b + t_vec @ W[128:144]
    int which = id/1536, rem=id%1536, t=rem/128, n=rem%128;
    const void* W  = which==0?qw:(which==1?kw:vw);
    const void* Bs = which==0?qb0:(which==1?kb0:vb0);
    float s = LD(Bs,n,md);
    for(int d=0;d<16;d++){
      float tv = sinf((float)t*LD(tw,d,md) + LD(tb,d,md));
      s += tv * LD(W,(size_t)(128+d)*128+n,md);
    }
    float* dst = which==0?qbf:(which==1?kbf:vbf);
    dst[t*128+n]=s; return;
  }
  id -= 4608;
  if(id < 256){   // GCN biases to fp32
    if(id<128) b1f[id] = LD(b1,id,md);
    else       b2f[id-128] = LD(b2,id-128,md);
    return;
  }
}

__device__ __forceinline__ void dev_edges_item(int id, int md,
    const void* A, const int* inv, int* cnt, int* edges){
  int seg = id & 63; int row = id >> 6;           // row = t*MM + j (orig)
  int t = row / MM;
  int jc = inv[row];
  if(jc < 0) return;                              // inactive source
  const int* invt = inv + (size_t)t*MM;
  int* cb = cnt + (size_t)t*MM;
  int* eb = edges + (size_t)t*MM*CAP;
  if(md){   // fp32 adjacency
    const float4* p4 = (const float4*)((const float*)A + (size_t)row*MM + seg*32);
    #pragma unroll
    for(int u=0;u<8;u++){
      float4 v = p4[u];
      float wd[4]={v.x,v.y,v.z,v.w};
      #pragma unroll
      for(int q=0;q<4;q++){
        if(wd[q]!=0.f){
          int ibc = invt[seg*32 + u*4 + q];
          if(ibc >= 0){ int s=atomicAdd(&cb[ibc],1); if(s<CAP) eb[(size_t)ibc*CAP+s]=jc; }
        }
      }
    }
  } else {    // bf16 adjacency
    const uint4* p4 = (const uint4*)((const unsigned short*)A + (size_t)row*MM + seg*32);
    #pragma unroll
    for(int u=0;u<4;u++){
      uint4 v = p4[u];
      unsigned wd[4]={v.x,v.y,v.z,v.w};
      #pragma unroll
      for(int q=0;q<4;q++){
        int ib = seg*32 + u*8 + q*2;
        if(wd[q] & 0xFFFFu){
          int ibc = invt[ib];
          if(ibc >= 0){ int s=atomicAdd(&cb[ibc],1); if(s<CAP) eb[(size_t)ibc*CAP+s]=jc; }
        }
        if(wd[q] >> 16){
          int ibc = invt[ib+1];
          if(ibc >= 0){ int s=atomicAdd(&cb[ibc],1); if(s<CAP) eb[(size_t)ibc*CAP+s]=jc; }
        }
      }
    }
  }
}

// gemm_x reading w1 DIRECTLY (transposed access; w1 is 32KB, L2-hot) -- removes
// the intra-launch dependency on prepw's W1t so it can share a launch with prepw.
__device__ __forceinline__ void dev_gemm_x_direct(int tileIdx, int md, int tid,
    const void* x, const int* nact, const int* aidx,
    const void* w1, float* g)
{
  const int tile = tileIdx*64;
  const int t = tile / MM, il = tile % MM;
  const int na = nact[t];
  if(il >= ((na+63)&~63)) return;
  const int wv=tid>>6, lane=tid&63, l15=lane&15, quad=lane>>4;
  const int r0 = tile + (wv>>1)*32;          // global compact row base
  const int c0 = (wv&1)*64;
  short8 bf[2][4];
  #pragma unroll
  for(int kk=0;kk<2;kk++)
    #pragma unroll
    for(int nt=0;nt<4;nt++){
      const int col = c0+nt*16+l15;
      short8 o;
      #pragma unroll
      for(int j=0;j<8;j++)
        o[j] = (short)f2bf(LD(w1, (size_t)(kk*32 + quad*8 + j)*DH + col, md));
      bf[kk][nt] = o;
    }
  const int il0 = (r0 % MM) + l15, il1 = (r0 % MM) + 16 + l15;
  const int n0 = aidx[(size_t)t*MM + (il0 < na ? il0 : 0)];
  const int n1 = aidx[(size_t)t*MM + (il1 < na ? il1 : 0)];
  const size_t xb0 = ((size_t)t*MM + n0)*DIN;
  const size_t xb1 = ((size_t)t*MM + n1)*DIN;
  f32x4 z = {0.f,0.f,0.f,0.f};
  f32x4 acc[2][4];
  #pragma unroll
  for(int i=0;i<2;i++){ acc[i][0]=z; acc[i][1]=z; acc[i][2]=z; acc[i][3]=z; }
  #pragma unroll
  for(int kk=0;kk<2;kk++){
    short8 a0 = ldx8(x, xb0 + kk*32 + quad*8, md);
    short8 a1 = ldx8(x, xb1 + kk*32 + quad*8, md);
    #pragma unroll
    for(int nt=0;nt<4;nt++){
      acc[0][nt]=MFMA(a0,bf[kk][nt],acc[0][nt]);
      acc[1][nt]=MFMA(a1,bf[kk][nt],acc[1][nt]);
    }
  }
  #pragma unroll
  for(int mt=0;mt<2;mt++)
    #pragma unroll
    for(int nt=0;nt<4;nt++){
      int col = c0+nt*16+l15;
      #pragma unroll
      for(int r=0;r<4;r++){
        int row = r0 + mt*16 + quad*4 + r;
        g[(size_t)row*DH + col] = acc[mt][nt][r];
      }
    }
}

// ---------------- L2: prepw + edges + gemm_x in one launch ----------------
// Every block derives the input dtype from a cheap redundant x-scan (12KB, L2).
__global__ __launch_bounds__(256) void k_pex(
  const void* __restrict__ x, const void* __restrict__ A,
  const void* __restrict__ w1, const void* __restrict__ w2,
  const void* __restrict__ qw, const void* __restrict__ kw, const void* __restrict__ vw,
  const void* __restrict__ qb0, const void* __restrict__ kb0, const void* __restrict__ vb0,
  const void* __restrict__ ow, const void* __restrict__ ob,
  const void* __restrict__ fw, const void* __restrict__ fb,
  const void* __restrict__ tw, const void* __restrict__ tb,
  const void* __restrict__ b1, const void* __restrict__ b2,
  const int* __restrict__ inv, int* __restrict__ cnt, int* __restrict__ edges,
  const int* __restrict__ nact, const int* __restrict__ aidx, float* __restrict__ g,
  unsigned short* __restrict__ W2t,
  unsigned short* __restrict__ Wqt, unsigned short* __restrict__ Wkt,
  unsigned short* __restrict__ Wvt, unsigned short* __restrict__ Wct,
  float* __restrict__ qbf, float* __restrict__ kbf, float* __restrict__ vbf,
  float* __restrict__ bcf, float* __restrict__ b1f, float* __restrict__ b2f)
{
  const int tid = threadIdx.x;
  __shared__ int cnt_s;
  if(tid == 0) cnt_s = 0;
  __syncthreads();
  {
    int c = 0;
    const unsigned short* xs = (const unsigned short*)x;
    for(int i = tid; i < 6144; i += 256){
      unsigned short hh = xs[i*2];
      unsigned e = (hh >> 7) & 0xFF;
      if(hh==0 || (e >= 0x60 && e <= 0x9F)) c++;
    }
    if(c) atomicAdd(&cnt_s, c);
  }
  __syncthreads();
  const int md = (cnt_s > 4000) ? 0 : 1;     // 0=bf16, 1=fp32

  const int b = blockIdx.x;
  if(b < PWB){
    dev_prepw2_item(b*256 + tid, md, w2, qw,kw,vw, qb0,kb0,vb0, ow,ob,fw,fb, tw,tb, b1,b2,
                    W2t, Wqt, Wkt, Wvt, Wct, qbf, kbf, vbf, bcf, b1f, b2f);
  } else if(b < PWB + TM*64/256){
    dev_edges_item((b - PWB)*256 + tid, md, A, inv, cnt, edges);
  } else {
    dev_gemm_x_direct(b - PWB - TM*64/256, md, tid, x, nact, aidx, w1, g);
  }
}

// ---------------- dense GEMM on compact rows (h -> g), KD=128 ----------------
__global__ __launch_bounds__(256) void k_gemm_h(const unsigned short* __restrict__ X,
    const unsigned short* __restrict__ Wt, float* __restrict__ g,
    const int* __restrict__ nact)
{
  const int tile = blockIdx.x*64;
  const int t = tile / MM, il = tile % MM;
  const int na = nact[t];
  if(il >= ((na+63)&~63)) return;
  const int tid=threadIdx.x, wv=tid>>6, lane=tid&63, l15=lane&15, quad=lane>>4;
  const int r0 = tile + (wv>>1)*32;
  const int c0 = (wv&1)*64;
  short8 bf[4][4];
  #pragma unroll
  for(int kk=0;kk<4;kk++)
    #pragma unroll
    for(int nt=0;nt<4;nt++)
      bf[kk][nt] = *(const short8*)(Wt + (size_t)(c0+nt*16+l15)*DH + kk*32 + quad*8);
  f32x4 z = {0.f,0.f,0.f,0.f};
  f32x4 acc[2][4];
  #pragma unroll
  for(int i=0;i<2;i++){ acc[i][0]=z; acc[i][1]=z; acc[i][2]=z; acc[i][3]=z; }
  #pragma unroll
  for(int kk=0;kk<4;kk++){
    short8 a0 = *(const short8*)(X + (size_t)(r0+l15)*DH    + kk*32 + quad*8);
    short8 a1 = *(const short8*)(X + (size_t)(r0+16+l15)*DH + kk*32 + quad*8);
    #pragma unroll
    for(int nt=0;nt<4;nt++){
      acc[0][nt]=MFMA(a0,bf[kk][nt],acc[0][nt]);
      acc[1][nt]=MFMA(a1,bf[kk][nt],acc[1][nt]);
    }
  }
  #pragma unroll
  for(int mt=0;mt<2;mt++)
    #pragma unroll
    for(int nt=0;nt<4;nt++){
      int col = c0+nt*16+l15;
      #pragma unroll
      for(int r=0;r<4;r++){
        int row = r0 + mt*16 + quad*4 + r;
        g[(size_t)row*DH + col] = acc[mt][nt][r];
      }
    }
}

// ---------------- sparse GCN aggregation on compact rows -> h (bf16) ----------------
__global__ __launch_bounds__(256) void k_gather(const float* __restrict__ g,
    const int* __restrict__ edges, const int* __restrict__ cnt,
    const int* __restrict__ nact, const float* __restrict__ bias,
    unsigned short* __restrict__ h)
{
  int wv = threadIdx.x>>6, lane = threadIdx.x&63;
  int gi = blockIdx.x*4 + wv;           // compact row, < TM
  int t = gi / MM, ic = gi % MM;
  int na = nact[t];
  if(ic >= ((na+63)&~63)) return;
  unsigned int* hp = (unsigned int*)(h + (size_t)gi*DH) + lane;
  if(ic >= na){ *hp = 0; return; }      // pad row: finite zeros
  float a0=0.f, a1=0.f;
  int cn = cnt[gi]; if(cn>CAP) cn=CAP;
  const int* eb = edges + (size_t)gi*CAP;
  #pragma unroll 2
  for(int e=0;e<cn;e++){
    int jc = eb[e];
    float nj = rsqrtf((float)cnt[(size_t)t*MM+jc] + 1.f);
    float2 gr2 = *(const float2*)(g + ((size_t)t*MM + jc)*DH + 2*lane);
    a0 += nj*gr2.x; a1 += nj*gr2.y;
  }
  float ni = rsqrtf((float)cn + 1.f);
  float2 gs2 = *(const float2*)(g + (size_t)gi*DH + 2*lane);
  float h0 = ni*(a0 + ni*gs2.x) + bias[2*lane];
  float h1 = ni*(a1 + ni*gs2.y) + bias[2*lane+1];
  h0 = h0>0.f?h0:0.f; h1 = h1>0.f?h1:0.f;
  *hp = (unsigned int)f2bf(h0) | ((unsigned int)f2bf(h1) << 16);
}

// ---------------- Q/K/V GEMMs: Q,K row-major; V written TRANSPOSED directly ----------------
__global__ __launch_bounds__(256) void k_gemm_qkv(const unsigned short* __restrict__ X,
    const unsigned short* __restrict__ Wq, const unsigned short* __restrict__ Wk,
    const unsigned short* __restrict__ Wv,
    const float* __restrict__ qb, const float* __restrict__ kb, const float* __restrict__ vb,
    unsigned short* __restrict__ Qo, unsigned short* __restrict__ Ko,
    unsigned short* __restrict__ Vtc, const int* __restrict__ nact)
{
  const int tile = blockIdx.x*64;
  const int t = tile / MM, il = tile % MM;
  const int na = nact[t];
  if(il >= ((na+63)&~63)) return;
  const int which = blockIdx.z;
  const unsigned short* Wt = which==0?Wq:(which==1?Wk:Wv);
  const float* bias = which==0?qb:(which==1?kb:vb);
  const int tid=threadIdx.x, wv=tid>>6, lane=tid&63, l15=lane&15, quad=lane>>4;
  const int r0 = tile + (wv>>1)*32;
  const int c0 = (wv&1)*64;
  short8 bf[4][4];
  #pragma unroll
  for(int kk=0;kk<4;kk++)
    #pragma unroll
    for(int nt=0;nt<4;nt++)
      bf[kk][nt] = *(const short8*)(Wt + (size_t)(c0+nt*16+l15)*DH + kk*32 + quad*8);
  f32x4 z = {0.f,0.f,0.f,0.f};
  f32x4 acc[2][4];
  #pragma unroll
  for(int i=0;i<2;i++){ acc[i][0]=z; acc[i][1]=z; acc[i][2]=z; acc[i][3]=z; }
  #pragma unroll
  for(int kk=0;kk<4;kk++){
    short8 a0 = *(const short8*)(X + (size_t)(r0+l15)*DH    + kk*32 + quad*8);
    short8 a1 = *(const short8*)(X + (size_t)(r0+16+l15)*DH + kk*32 + quad*8);
    #pragma unroll
    for(int nt=0;nt<4;nt++){
      acc[0][nt]=MFMA(a0,bf[kk][nt],acc[0][nt]);
      acc[1][nt]=MFMA(a1,bf[kk][nt],acc[1][nt]);
    }
  }
  if(which < 2){
    unsigned short* o = which==0 ? Qo : Ko;
    #pragma unroll
    for(int mt=0;mt<2;mt++)
      #pragma unroll
      for(int nt=0;nt<4;nt++){
        int col = c0+nt*16+l15;
        float bb = bias[t*DH+col];
        #pragma unroll
        for(int r=0;r<4;r++){
          int row = r0 + mt*16 + quad*4 + r;
          o[(size_t)row*DH + col] = f2bf(acc[mt][nt][r] + bb);
        }
      }
  } else {
    #pragma unroll
    for(int mt=0;mt<2;mt++)
      #pragma unroll
      for(int nt=0;nt<4;nt++){
        int col = c0+nt*16+l15;
        float bb = bias[t*DH+col];
        int node0 = il + (wv>>1)*32 + mt*16 + quad*4;   // compact local row
        short4v pk;
        #pragma unroll
        for(int r=0;r<4;r++) pk[r] = (short)f2bf(acc[mt][nt][r] + bb);
        *(short4v*)(Vtc + ((size_t)t*DH + col)*MM + node0) = pk;
      }
  }
}

// ---------------- fused attention: single pass (round-0 verified) ----------------
__global__ __launch_bounds__(256) void k_attn(
  const unsigned short* __restrict__ Q, const unsigned short* __restrict__ Kc,
  const unsigned short* __restrict__ Vtc, const int* __restrict__ nact,
  const int* __restrict__ aidx, const unsigned short* __restrict__ Wct,
  const float* __restrict__ bc, float* __restrict__ out)
{
  __shared__ unsigned short Kl[64][136];   // 64 keys x 128ch
  __shared__ unsigned short Vl[128][72];   // 128 ch x 64 keys
  __shared__ short Pl[4][16][72];          // per-wave P tile
  __shared__ short Al[4][16][136];         // per-wave accumulator (bf16) for projection
  const int tid=threadIdx.x, wv=tid>>6, lane=tid&63, l15=lane&15, quad=lane>>4;
  const int t = blockIdx.y;
  const int na = nact[t];
  const int qblk = blockIdx.x*64;
  if(qblk >= na) return;                 // block-uniform exit (before any barrier)
  const int qbase = qblk + wv*16;
  const float scale = 0.088388347648318447f;  // 1/sqrt(128)
  const int nkt = (na + 63) >> 6;

  short8 bq[4];
  #pragma unroll
  for(int kk=0;kk<4;kk++)
    bq[kk] = *(const short8*)(Q + ((size_t)t*MM + qbase + l15)*DH + kk*32 + quad*8);

  f32x4 zz = {0.f,0.f,0.f,0.f};
  f32x4 accPV[8];
  #pragma unroll
  for(int i=0;i<8;i++) accPV[i]=zz;
  float l_run = 0.f;

  const int srow = tid >> 2, sseg = tid & 3;   // K stage: 64 rows x 4 segs
  const int vch  = tid >> 1, vhalf = tid & 1;  // V stage: 128 ch x 2 halves

  short8 kreg[4], vreg[4];
  {  // preload tile 0 into registers
    const unsigned short* gk = Kc + ((size_t)t*MM + srow)*DH + sseg*32;
    const unsigned short* gv = Vtc + ((size_t)t*DH + vch)*MM + vhalf*32;
    #pragma unroll
    for(int j=0;j<4;j++){ kreg[j] = *(const short8*)(gk + j*8);
                          vreg[j] = *(const short8*)(gv + j*8); }
  }

  for(int kt=0; kt<nkt; kt++){
    const int key0 = kt*64;
    __syncthreads();   // previous tile fully consumed before restage
    {  // write prefetched registers to LDS
      short8* kd = (short8*)&Kl[srow][sseg*32];
      short8* vd = (short8*)&Vl[vch][vhalf*32];
      #pragma unroll
      for(int j=0;j<4;j++){ kd[j] = kreg[j]; vd[j] = vreg[j]; }
    }
    __syncthreads();
    if(kt+1 < nkt){   // issue next tile's global loads; they overlap compute below
      const int key1 = key0 + 64;
      const unsigned short* gk = Kc + ((size_t)t*MM + key1 + srow)*DH + sseg*32;
      const unsigned short* gv = Vtc + ((size_t)t*DH + vch)*MM + key1 + vhalf*32;
      #pragma unroll
      for(int j=0;j<4;j++){ kreg[j] = *(const short8*)(gk + j*8);
                            vreg[j] = *(const short8*)(gv + j*8); }
    }
    // S^T = K · Q^T from LDS
    #pragma unroll
    for(int mt=0;mt<4;mt++){
      f32x4 s = zz;
      #pragma unroll
      for(int kk=0;kk<4;kk++){
        short8 ak = *(const short8*)&Kl[mt*16+l15][kk*32 + quad*8];
        s = MFMA(ak, bq[kk], s);
      }
      short4v pk;
      #pragma unroll
      for(int r=0;r<4;r++){
        float sv = fminf(fmaxf(s[r]*scale, -15.f), 15.f);
        float valid = (key0 + mt*16 + quad*4 + r < na) ? 1.f : 0.f;
        float p = __expf(sv) * valid;
        pk[r] = (short)f2bf(p);
        l_run += bf2f((unsigned short)pk[r]);
      }
      *(short4v*)&Pl[wv][l15][mt*16 + quad*4] = pk;
    }
    // PV from LDS
    #pragma unroll
    for(int kk=0;kk<2;kk++){
      short8 ap = *(const short8*)&Pl[wv][l15][kk*32 + quad*8];
      #pragma unroll
      for(int nt=0;nt<8;nt++){
        short8 bv = *(const short8*)&Vl[nt*16+l15][kk*32 + quad*8];
        accPV[nt] = MFMA(ap, bv, accPV[nt]);
      }
    }
  }
  l_run += __shfl_xor(l_run, 16, 64);
  l_run += __shfl_xor(l_run, 32, 64);

  // per-wave projection (Al slice is wave-private; no cross-wave barrier needed)
  #pragma unroll
  for(int nt=0;nt<8;nt++)
    #pragma unroll
    for(int r=0;r<4;r++){
      float av = fminf(fmaxf(accPV[nt][r], -1e30f), 1e30f);
      Al[wv][quad*4+r][nt*16+l15] = (short)f2bf(av);
    }

  const int qc = qbase + l15;
  const bool qok = (qc < na);                // predicate loads of aidx + stores only
  const float linv = (l_run > 0.f) ? 1.f/l_run : 0.f;
  const int node = aidx[(size_t)t*MM + (qok ? qc : 0)];
  #pragma unroll
  for(int mt2=0;mt2<2;mt2++){
    f32x4 d = zz;
    #pragma unroll
    for(int kk=0;kk<4;kk++){
      short8 aw = *(const short8*)(Wct + (size_t)(mt2*16+l15)*DH + kk*32 + quad*8);
      short8 bl = *(const short8*)&Al[wv][l15][kk*32 + quad*8];
      d = MFMA(aw, bl, d);
    }
    f32x4 bcv = *(const f32x4*)(bc + mt2*16 + quad*4);
    f32x4 o4;
    #pragma unroll
    for(int r=0;r<4;r++) o4[r] = d[r]*linv + bcv[r];
    if(qok)
      *(f32x4*)(out + (size_t)node*(TT*DOUT) + (size_t)t*DOUT + mt2*16 + quad*4) = o4;
  }
}

// ================= launch: 7 kernels (was 10) =================

extern "C" void kernel_launch(void* const* d_in, const int* in_sizes, int n_in,
                              void* d_out, int out_size, void* d_ws, size_t ws_size,
                              hipStream_t stream)
{
  float* outp = (float*)d_out;   // reference output dtype is float32
  static const int EXP[19] = {1572864,50331648,24576,8192,128,16384,128,16,16,
                              18432,128,18432,128,18432,128,16384,128,4096,32};
  bool ok = (n_in >= 19) && (out_size == OUTSZ);
  if(ok) for(int i=0;i<19;i++) if(in_sizes[i] != EXP[i]) { ok = false; break; }
  if(!ok){
    k_fill<<<(out_size+255)/256,256,0,stream>>>(outp, out_size, 1000.f);
    return;
  }
  const void* x   = d_in[0];
  const void* A   = d_in[1];
  const void* eg  = d_in[2];
  const void* w1  = d_in[3];
  const void* b1  = d_in[4];
  const void* w2  = d_in[5];
  const void* b2  = d_in[6];
  const void* tw  = d_in[7];
  const void* tb  = d_in[8];
  const void* qw  = d_in[9];
  const void* qb0 = d_in[10];
  const void* kw  = d_in[11];
  const void* kb0 = d_in[12];
  const void* vw  = d_in[13];
  const void* vb0 = d_in[14];
  const void* ow  = d_in[15];
  const void* ob  = d_in[16];
  const void* fw  = d_in[17];
  const void* fb  = d_in[18];

  char* w = (char*)d_ws;
  size_t off = 0;
  auto alloc = [&](size_t sz)->char*{
    char* p = w + off; off = (off + sz + 255) & ~(size_t)255; return p; };
  int*   nactb = (int*)  alloc(TT*4);
  int*   cnt   = (int*)  alloc((size_t)TM*4);
  int*   aidx  = (int*)  alloc((size_t)TM*4);
  int*   inv   = (int*)  alloc((size_t)TM*4);
  int*   edges = (int*)  alloc((size_t)TM*CAP*4);
  float* g     = (float*)alloc((size_t)TM*DH*4);   // reused as Qb+Kb after 2nd gather
  unsigned short* h   = (unsigned short*)alloc((size_t)TM*DH*2);
  unsigned short* Vtc = (unsigned short*)alloc((size_t)TT*DH*MM*2);
  unsigned short* W2t = (unsigned short*)alloc(DH*DH*2);
  unsigned short* Wqt = (unsigned short*)alloc(DH*DH*2);
  unsigned short* Wkt = (unsigned short*)alloc(DH*DH*2);
  unsigned short* Wvt = (unsigned short*)alloc(DH*DH*2);
  unsigned short* Wct = (unsigned short*)alloc(DOUT*DH*2);
  float* qbf = (float*)alloc(TT*DH*4);
  float* kbf = (float*)alloc(TT*DH*4);
  float* vbf = (float*)alloc(TT*DH*4);
  float* bcf = (float*)alloc(DOUT*4);
  float* b1f = (float*)alloc(DH*4);
  float* b2f = (float*)alloc(DH*4);
  if(off > ws_size){
    k_fill<<<(out_size+255)/256,256,0,stream>>>(outp, out_size, 500.f);
    return;
  }

  unsigned short* Qb = (unsigned short*)g;                       // TM*DH*2 bytes
  unsigned short* Kb = (unsigned short*)((char*)g + (size_t)TM*DH*2);

  // L1: mask (deterministic per-t compaction, redundant dtype detect) + out zero
  k_maskdet<<<OUTSZ/256,256,0,stream>>>(eg, cnt, nactb, aidx, inv, outp);
  // L2: weight prep + edge build + gemm_x (direct w1 reads), one launch
  k_pex<<<PWB + TM*64/256 + TM/64,256,0,stream>>>(
      x, A, w1, w2, qw, kw, vw, qb0, kb0, vb0, ow, ob, fw, fb, tw, tb, b1, b2,
      inv, cnt, edges, nactb, aidx, g,
      W2t, Wqt, Wkt, Wvt, Wct, qbf, kbf, vbf, bcf, b1f, b2f);
  // L3..L6: GCN + QKV
  k_gather<<<TM/4,256,0,stream>>>(g, edges, cnt, nactb, b1f, h);
  k_gemm_h<<<TM/64,256,0,stream>>>(h, W2t, g, nactb);
  k_gather<<<TM/4,256,0,stream>>>(g, edges, cnt, nactb, b2f, h);
  k_gemm_qkv<<<dim3(TM/64,1,3),256,0,stream>>>(h, Wqt,Wkt,Wvt, qbf,kbf,vbf, Qb,Kb,Vtc, nactb);
  // L7: single-pass fused attention + projection
  k_attn<<<dim3(MM/64,TT),256,0,stream>>>(Qb, Kb, Vtc, nactb, aidx, Wct, bcf, outp);
}

// Round 7
// 472.751 us; speedup vs baseline: 2.6365x; 1.0396x over previous
//
#include <hip/hip_runtime.h>
#include <stdint.h>

#define TT   12
#define BB   2
#define NN   1024
#define MM   2048
#define TM   24576      // TT*MM
#define DIN  64
#define DH   128
#define DOUT 32
#define CAP  64
#define OUTSZ 786432
#define PWB  292        // prepw blocks (74528 items / 256) inside k_pex

typedef __attribute__((ext_vector_type(8))) short short8;
typedef __attribute__((ext_vector_type(4))) short short4v;
typedef __attribute__((ext_vector_type(4))) float f32x4;

#define MFMA(a,b,c) __builtin_amdgcn_mfma_f32_16x16x32_bf16((a),(b),(c),0,0,0)

__device__ __forceinline__ float bf2f(unsigned short u){
  union { uint32_t i; float f; } x; x.i = ((uint32_t)u) << 16; return x.f;
}
__device__ __forceinline__ unsigned short f2bf(float f){
  union { float f; uint32_t i; } x; x.f = f;
  uint32_t u = x.i + 0x7FFFu + ((x.i >> 16) & 1u);   // RNE
  return (unsigned short)(u >> 16);
}
__device__ __forceinline__ float LD(const void* p, size_t i, int mode){
  return mode ? ((const float*)p)[i] : bf2f(((const unsigned short*)p)[i]);
}
// gather-load 8 input elements as bf16 (mode 1 = fp32 source)
__device__ __forceinline__ short8 ldx8(const void* x, size_t off, int md){
  if(md){
    const float4* xf = (const float4*)((const float*)x + off);
    float4 a = xf[0], b = xf[1];
    short8 o;
    o[0]=(short)f2bf(a.x); o[1]=(short)f2bf(a.y); o[2]=(short)f2bf(a.z); o[3]=(short)f2bf(a.w);
    o[4]=(short)f2bf(b.x); o[5]=(short)f2bf(b.y); o[6]=(short)f2bf(b.z); o[7]=(short)f2bf(b.w);
    return o;
  }
  return *(const short8*)((const unsigned short*)x + off);
}

// ---------------- fill (fp32, sentinels only) ----------------
__global__ void k_fill(float* __restrict__ out, int n, float val){
  int i = blockIdx.x*blockDim.x + threadIdx.x;
  if(i < n) out[i] = val;
}

// ---------------- L1: mask decode + x-dtype detect + out zero ----------------
// Blocks 0..TT-1: per-block redundant mask-dtype detect (24KB eg scan, L2) then
// LDS-prefix compaction of timestep t (deterministic, no global atomics).
// Block TT: x dtype detect -> dtf (hoisted out of k_pex's 6820 blocks).
// All 3072 blocks zero out.
__global__ __launch_bounds__(256) void k_maskdet(
    const void* __restrict__ egom, const unsigned short* __restrict__ xs,
    int* __restrict__ dtf,
    int* __restrict__ cnt, int* __restrict__ nact,
    int* __restrict__ aidx, int* __restrict__ inv,
    float* __restrict__ out)
{
  const int bid = blockIdx.x, tid = threadIdx.x;
  out[(size_t)bid*256 + tid] = 0.f;          // inactive nodes stay 0
  if(bid > TT) return;
  if(bid == TT){                             // x dtype detect
    __shared__ int cnt_s;
    if(tid == 0) cnt_s = 0;
    __syncthreads();
    int c = 0;
    for(int i = tid; i < 6144; i += 256){
      unsigned short hh = xs[i*2];
      unsigned e = (hh >> 7) & 0xFF;
      if(hh==0 || (e >= 0x60 && e <= 0x9F)) c++;
    }
    if(c) atomicAdd(&cnt_s, c);
    __syncthreads();
    if(tid == 0) *dtf = (cnt_s > 4000) ? 0 : 1;   // 0=bf16, 1=fp32
    return;
  }
  const int t = bid, lane = tid & 63, wv = tid >> 6;

  __shared__ int pres_s, ge2_s, wcnt_s[4];
  if(tid == 0){ pres_s = 0; ge2_s = 0; }
  __syncthreads();
  {
    int pres = 0, ge2 = 0;
    const unsigned char* egp = (const unsigned char*)egom;
    for(int i = tid; i < 24576; i += 256){
      unsigned v = egp[i];
      if(v){ pres |= 1 << (i & 7); if(v >= 2u) ge2 = 1; }
    }
    if(pres) atomicOr(&pres_s, pres);
    if(ge2)  atomicOr(&ge2_s, 1);
  }
  __syncthreads();
  int mode;
  {
    int pr = pres_s, g2 = ge2_s;
    if(!g2){
      if((pr & ~0x01) == 0)      mode = 4;   // i64
      else if((pr & ~0x11) == 0) mode = 0;   // i32
      else                       mode = 1;   // u8
    } else {
      if((pr & ~0xC0) == 0)      mode = 5;   // f64
      else if((pr & ~0xCC) == 0) mode = 3;   // f32
      else                       mode = 2;   // bf16
    }
  }

  int base = 0;                              // uniform running prefix (register)
  for(int r = 0; r < 8; r++){
    int node = r*256 + tid;
    int b = node / NN, n = node % NN;
    int src = (b*TT + t)*NN + n;
    int v;
    if(mode==0)      v = ((const int*)egom)[src] != 0;
    else if(mode==1) v = ((const unsigned char*)egom)[src] != 0;
    else if(mode==2) v = ((const unsigned short*)egom)[src] != 0;
    else if(mode==3) v = ((const float*)egom)[src] != 0.f;
    else if(mode==4) v = ((const long long*)egom)[src] != 0;
    else             v = ((const double*)egom)[src] != 0.0;
    cnt[(size_t)t*MM + node] = 0;
    unsigned long long bal = __ballot(v != 0);
    if(lane == 0) wcnt_s[wv] = __popcll(bal);
    __syncthreads();
    int mybase = base;
    for(int w2 = 0; w2 < wv; w2++) mybase += wcnt_s[w2];
    int ic = -1;
    if(v){
      ic = mybase + __popcll(bal & ((1ULL << lane) - 1ULL));
      aidx[(size_t)t*MM + ic] = node;
    }
    inv[(size_t)t*MM + node] = ic;
    base += wcnt_s[0] + wcnt_s[1] + wcnt_s[2] + wcnt_s[3];
    __syncthreads();                        // protect wcnt_s before next round
  }
  if(tid == 0) nact[t] = base;
}

// ================= device bodies =================

// weight prep WITHOUT the W1t segment (gemm_x reads w1 directly now). 74528 items.
__device__ __forceinline__ void dev_prepw2_item(int id, int md,
  const void* w2,
  const void* qw, const void* kw, const void* vw,
  const void* qb0, const void* kb0, const void* vb0,
  const void* ow, const void* ob, const void* fw, const void* fb,
  const void* tw, const void* tb, const void* b1, const void* b2,
  unsigned short* W2t,
  unsigned short* Wqt, unsigned short* Wkt,
  unsigned short* Wvt, unsigned short* Wct,
  float* qbf, float* kbf, float* vbf,
  float* bcf, float* b1f, float* b2f)
{
  if(id < 16384){ int n=id&127,k2=id>>7; W2t[n*128+k2]=f2bf(LD(w2,(size_t)k2*128+n,md)); return; }
  id -= 16384;
  if(id < 16384){ int n=id&127,k2=id>>7; Wqt[n*128+k2]=f2bf(LD(qw,(size_t)k2*128+n,md)); return; }
  id -= 16384;
  if(id < 16384){ int n=id&127,k2=id>>7; Wkt[n*128+k2]=f2bf(LD(kw,(size_t)k2*128+n,md)); return; }
  id -= 16384;
  if(id < 16384){ int n=id&127,k2=id>>7; Wvt[n*128+k2]=f2bf(LD(vw,(size_t)k2*128+n,md)); return; }
  id -= 16384;
  if(id < 4096){  // Wc = o_w @ fc_w, stored [oc][c]
    int oc=id&31, c=id>>5; float s=0.f;
    for(int r=0;r<128;r++) s += LD(ow,(size_t)c*128+r,md)*LD(fw,(size_t)r*32+oc,md);
    Wct[oc*128+c]=f2bf(s); return;
  }
  id -= 4096;
  if(id < 32){    // bc = o_b @ fc_w + fc_b
    float s = LD(fb,id,md);
    for(int r=0;r<128;r++) s += LD(ob,r,md)*LD(fw,(size_t)r*32+id,md);
    bcf[id]=s; return;
  }
  id -= 32;
  if(id < 4608){  // per-t fused QKV bias: b + t_vec @ W[128:144]
    int which = id/1536, rem=id%1536, t=rem/128, n=rem%128;
    const void* W  = which==0?qw:(which==1?kw:vw);
    const void* Bs = which==0?qb0:(which==1?kb0:vb0);
    float s = LD(Bs,n,md);
    for(int d=0;d<16;d++){
      float tv = sinf((float)t*LD(tw,d,md) + LD(tb,d,md));
      s += tv * LD(W,(size_t)(128+d)*128+n,md);
    }
    float* dst = which==0?qbf:(which==1?kbf:vbf);
    dst[t*128+n]=s; return;
  }
  id -= 4608;
  if(id < 256){   // GCN biases to fp32
    if(id<128) b1f[id] = LD(b1,id,md);
    else       b2f[id-128] = LD(b2,id-128,md);
    return;
  }
}

// COALESCED edge scan: one wave per row, lane i + iter u reads vector index
// u*64+i -> consecutive lanes touch consecutive 16B (1KB/wave-instruction),
// vs the old per-lane-contiguous-chunk pattern (64 cache lines per instr).
__device__ __forceinline__ void dev_edges_item(int id, int md,
    const void* A, const int* inv, int* cnt, int* edges){
  int lane = id & 63; int row = id >> 6;          // row = t*MM + j (orig)
  int t = row / MM;
  int jc = inv[row];
  if(jc < 0) return;                              // inactive source
  const int* invt = inv + (size_t)t*MM;
  int* cb = cnt + (size_t)t*MM;
  int* eb = edges + (size_t)t*MM*CAP;
  if(md){   // fp32 adjacency: 512 float4 per row
    const float4* p4 = (const float4*)((const float*)A + (size_t)row*MM);
    #pragma unroll
    for(int u=0;u<8;u++){
      float4 v = p4[u*64 + lane];
      float wd[4]={v.x,v.y,v.z,v.w};
      #pragma unroll
      for(int q=0;q<4;q++){
        if(wd[q]!=0.f){
          int ibc = invt[(u*64 + lane)*4 + q];
          if(ibc >= 0){ int s=atomicAdd(&cb[ibc],1); if(s<CAP) eb[(size_t)ibc*CAP+s]=jc; }
        }
      }
    }
  } else {    // bf16 adjacency: 256 uint4 per row (8 bf16 each)
    const uint4* p4 = (const uint4*)((const unsigned short*)A + (size_t)row*MM);
    #pragma unroll
    for(int u=0;u<4;u++){
      uint4 v = p4[u*64 + lane];
      unsigned wd[4]={v.x,v.y,v.z,v.w};
      #pragma unroll
      for(int q=0;q<4;q++){
        int ib = (u*64 + lane)*8 + q*2;
        if(wd[q] & 0xFFFFu){
          int ibc = invt[ib];
          if(ibc >= 0){ int s=atomicAdd(&cb[ibc],1); if(s<CAP) eb[(size_t)ibc*CAP+s]=jc; }
        }
        if(wd[q] >> 16){
          int ibc = invt[ib+1];
          if(ibc >= 0){ int s=atomicAdd(&cb[ibc],1); if(s<CAP) eb[(size_t)ibc*CAP+s]=jc; }
        }
      }
    }
  }
}

// gemm_x reading w1 DIRECTLY (transposed access; w1 is 32KB, L2-hot)
__device__ __forceinline__ void dev_gemm_x_direct(int tileIdx, int md, int tid,
    const void* x, const int* nact, const int* aidx,
    const void* w1, float* g)
{
  const int tile = tileIdx*64;
  const int t = tile / MM, il = tile % MM;
  const int na = nact[t];
  if(il >= ((na+63)&~63)) return;
  const int wv=tid>>6, lane=tid&63, l15=lane&15, quad=lane>>4;
  const int r0 = tile + (wv>>1)*32;          // global compact row base
  const int c0 = (wv&1)*64;
  short8 bf[2][4];
  #pragma unroll
  for(int kk=0;kk<2;kk++)
    #pragma unroll
    for(int nt=0;nt<4;nt++){
      const int col = c0+nt*16+l15;
      short8 o;
      #pragma unroll
      for(int j=0;j<8;j++)
        o[j] = (short)f2bf(LD(w1, (size_t)(kk*32 + quad*8 + j)*DH + col, md));
      bf[kk][nt] = o;
    }
  const int il0 = (r0 % MM) + l15, il1 = (r0 % MM) + 16 + l15;
  const int n0 = aidx[(size_t)t*MM + (il0 < na ? il0 : 0)];
  const int n1 = aidx[(size_t)t*MM + (il1 < na ? il1 : 0)];
  const size_t xb0 = ((size_t)t*MM + n0)*DIN;
  const size_t xb1 = ((size_t)t*MM + n1)*DIN;
  f32x4 z = {0.f,0.f,0.f,0.f};
  f32x4 acc[2][4];
  #pragma unroll
  for(int i=0;i<2;i++){ acc[i][0]=z; acc[i][1]=z; acc[i][2]=z; acc[i][3]=z; }
  #pragma unroll
  for(int kk=0;kk<2;kk++){
    short8 a0 = ldx8(x, xb0 + kk*32 + quad*8, md);
    short8 a1 = ldx8(x, xb1 + kk*32 + quad*8, md);
    #pragma unroll
    for(int nt=0;nt<4;nt++){
      acc[0][nt]=MFMA(a0,bf[kk][nt],acc[0][nt]);
      acc[1][nt]=MFMA(a1,bf[kk][nt],acc[1][nt]);
    }
  }
  #pragma unroll
  for(int mt=0;mt<2;mt++)
    #pragma unroll
    for(int nt=0;nt<4;nt++){
      int col = c0+nt*16+l15;
      #pragma unroll
      for(int r=0;r<4;r++){
        int row = r0 + mt*16 + quad*4 + r;
        g[(size_t)row*DH + col] = acc[mt][nt][r];
      }
    }
}

// ---------------- L2: prepw + edges + gemm_x in one launch ----------------
__global__ __launch_bounds__(256) void k_pex(
  const void* __restrict__ x, const void* __restrict__ A,
  const void* __restrict__ w1, const void* __restrict__ w2,
  const void* __restrict__ qw, const void* __restrict__ kw, const void* __restrict__ vw,
  const void* __restrict__ qb0, const void* __restrict__ kb0, const void* __restrict__ vb0,
  const void* __restrict__ ow, const void* __restrict__ ob,
  const void* __restrict__ fw, const void* __restrict__ fb,
  const void* __restrict__ tw, const void* __restrict__ tb,
  const void* __restrict__ b1, const void* __restrict__ b2,
  const int* __restrict__ dtf,
  const int* __restrict__ inv, int* __restrict__ cnt, int* __restrict__ edges,
  const int* __restrict__ nact, const int* __restrict__ aidx, float* __restrict__ g,
  unsigned short* __restrict__ W2t,
  unsigned short* __restrict__ Wqt, unsigned short* __restrict__ Wkt,
  unsigned short* __restrict__ Wvt, unsigned short* __restrict__ Wct,
  float* __restrict__ qbf, float* __restrict__ kbf, float* __restrict__ vbf,
  float* __restrict__ bcf, float* __restrict__ b1f, float* __restrict__ b2f)
{
  const int tid = threadIdx.x;
  const int md = *dtf;                       // produced by k_maskdet block TT
  const int b = blockIdx.x;
  if(b < PWB){
    dev_prepw2_item(b*256 + tid, md, w2, qw,kw,vw, qb0,kb0,vb0, ow,ob,fw,fb, tw,tb, b1,b2,
                    W2t, Wqt, Wkt, Wvt, Wct, qbf, kbf, vbf, bcf, b1f, b2f);
  } else if(b < PWB + TM*64/256){
    dev_edges_item((b - PWB)*256 + tid, md, A, inv, cnt, edges);
  } else {
    dev_gemm_x_direct(b - PWB - TM*64/256, md, tid, x, nact, aidx, w1, g);
  }
}

// ---------------- dense GEMM on compact rows (h -> g), KD=128 ----------------
__global__ __launch_bounds__(256) void k_gemm_h(const unsigned short* __restrict__ X,
    const unsigned short* __restrict__ Wt, float* __restrict__ g,
    const int* __restrict__ nact)
{
  const int tile = blockIdx.x*64;
  const int t = tile / MM, il = tile % MM;
  const int na = nact[t];
  if(il >= ((na+63)&~63)) return;
  const int tid=threadIdx.x, wv=tid>>6, lane=tid&63, l15=lane&15, quad=lane>>4;
  const int r0 = tile + (wv>>1)*32;
  const int c0 = (wv&1)*64;
  short8 bf[4][4];
  #pragma unroll
  for(int kk=0;kk<4;kk++)
    #pragma unroll
    for(int nt=0;nt<4;nt++)
      bf[kk][nt] = *(const short8*)(Wt + (size_t)(c0+nt*16+l15)*DH + kk*32 + quad*8);
  f32x4 z = {0.f,0.f,0.f,0.f};
  f32x4 acc[2][4];
  #pragma unroll
  for(int i=0;i<2;i++){ acc[i][0]=z; acc[i][1]=z; acc[i][2]=z; acc[i][3]=z; }
  #pragma unroll
  for(int kk=0;kk<4;kk++){
    short8 a0 = *(const short8*)(X + (size_t)(r0+l15)*DH    + kk*32 + quad*8);
    short8 a1 = *(const short8*)(X + (size_t)(r0+16+l15)*DH + kk*32 + quad*8);
    #pragma unroll
    for(int nt=0;nt<4;nt++){
      acc[0][nt]=MFMA(a0,bf[kk][nt],acc[0][nt]);
      acc[1][nt]=MFMA(a1,bf[kk][nt],acc[1][nt]);
    }
  }
  #pragma unroll
  for(int mt=0;mt<2;mt++)
    #pragma unroll
    for(int nt=0;nt<4;nt++){
      int col = c0+nt*16+l15;
      #pragma unroll
      for(int r=0;r<4;r++){
        int row = r0 + mt*16 + quad*4 + r;
        g[(size_t)row*DH + col] = acc[mt][nt][r];
      }
    }
}

// ---------------- sparse GCN aggregation on compact rows -> h (bf16) ----------------
__global__ __launch_bounds__(256) void k_gather(const float* __restrict__ g,
    const int* __restrict__ edges, const int* __restrict__ cnt,
    const int* __restrict__ nact, const float* __restrict__ bias,
    unsigned short* __restrict__ h)
{
  int wv = threadIdx.x>>6, lane = threadIdx.x&63;
  int gi = blockIdx.x*4 + wv;           // compact row, < TM
  int t = gi / MM, ic = gi % MM;
  int na = nact[t];
  if(ic >= ((na+63)&~63)) return;
  unsigned int* hp = (unsigned int*)(h + (size_t)gi*DH) + lane;
  if(ic >= na){ *hp = 0; return; }      // pad row: finite zeros
  float a0=0.f, a1=0.f;
  int cn = cnt[gi]; if(cn>CAP) cn=CAP;
  const int* eb = edges + (size_t)gi*CAP;
  #pragma unroll 2
  for(int e=0;e<cn;e++){
    int jc = eb[e];
    float nj = rsqrtf((float)cnt[(size_t)t*MM+jc] + 1.f);
    float2 gr2 = *(const float2*)(g + ((size_t)t*MM + jc)*DH + 2*lane);
    a0 += nj*gr2.x; a1 += nj*gr2.y;
  }
  float ni = rsqrtf((float)cn + 1.f);
  float2 gs2 = *(const float2*)(g + (size_t)gi*DH + 2*lane);
  float h0 = ni*(a0 + ni*gs2.x) + bias[2*lane];
  float h1 = ni*(a1 + ni*gs2.y) + bias[2*lane+1];
  h0 = h0>0.f?h0:0.f; h1 = h1>0.f?h1:0.f;
  *hp = (unsigned int)f2bf(h0) | ((unsigned int)f2bf(h1) << 16);
}

// ---------------- Q/K/V GEMMs: Q,K row-major; V written TRANSPOSED directly ----------------
__global__ __launch_bounds__(256) void k_gemm_qkv(const unsigned short* __restrict__ X,
    const unsigned short* __restrict__ Wq, const unsigned short* __restrict__ Wk,
    const unsigned short* __restrict__ Wv,
    const float* __restrict__ qb, const float* __restrict__ kb, const float* __restrict__ vb,
    unsigned short* __restrict__ Qo, unsigned short* __restrict__ Ko,
    unsigned short* __restrict__ Vtc, const int* __restrict__ nact)
{
  const int tile = blockIdx.x*64;
  const int t = tile / MM, il = tile % MM;
  const int na = nact[t];
  if(il >= ((na+63)&~63)) return;
  const int which = blockIdx.z;
  const unsigned short* Wt = which==0?Wq:(which==1?Wk:Wv);
  const float* bias = which==0?qb:(which==1?kb:vb);
  const int tid=threadIdx.x, wv=tid>>6, lane=tid&63, l15=lane&15, quad=lane>>4;
  const int r0 = tile + (wv>>1)*32;
  const int c0 = (wv&1)*64;
  short8 bf[4][4];
  #pragma unroll
  for(int kk=0;kk<4;kk++)
    #pragma unroll
    for(int nt=0;nt<4;nt++)
      bf[kk][nt] = *(const short8*)(Wt + (size_t)(c0+nt*16+l15)*DH + kk*32 + quad*8);
  f32x4 z = {0.f,0.f,0.f,0.f};
  f32x4 acc[2][4];
  #pragma unroll
  for(int i=0;i<2;i++){ acc[i][0]=z; acc[i][1]=z; acc[i][2]=z; acc[i][3]=z; }
  #pragma unroll
  for(int kk=0;kk<4;kk++){
    short8 a0 = *(const short8*)(X + (size_t)(r0+l15)*DH    + kk*32 + quad*8);
    short8 a1 = *(const short8*)(X + (size_t)(r0+16+l15)*DH + kk*32 + quad*8);
    #pragma unroll
    for(int nt=0;nt<4;nt++){
      acc[0][nt]=MFMA(a0,bf[kk][nt],acc[0][nt]);
      acc[1][nt]=MFMA(a1,bf[kk][nt],acc[1][nt]);
    }
  }
  if(which < 2){
    unsigned short* o = which==0 ? Qo : Ko;
    #pragma unroll
    for(int mt=0;mt<2;mt++)
      #pragma unroll
      for(int nt=0;nt<4;nt++){
        int col = c0+nt*16+l15;
        float bb = bias[t*DH+col];
        #pragma unroll
        for(int r=0;r<4;r++){
          int row = r0 + mt*16 + quad*4 + r;
          o[(size_t)row*DH + col] = f2bf(acc[mt][nt][r] + bb);
        }
      }
  } else {
    #pragma unroll
    for(int mt=0;mt<2;mt++)
      #pragma unroll
      for(int nt=0;nt<4;nt++){
        int col = c0+nt*16+l15;
        float bb = bias[t*DH+col];
        int node0 = il + (wv>>1)*32 + mt*16 + quad*4;   // compact local row
        short4v pk;
        #pragma unroll
        for(int r=0;r<4;r++) pk[r] = (short)f2bf(acc[mt][nt][r] + bb);
        *(short4v*)(Vtc + ((size_t)t*DH + col)*MM + node0) = pk;
      }
  }
}

// ---------------- fused attention: single pass (round-0 verified) ----------------
__global__ __launch_bounds__(256) void k_attn(
  const unsigned short* __restrict__ Q, const unsigned short* __restrict__ Kc,
  const unsigned short* __restrict__ Vtc, const int* __restrict__ nact,
  const int* __restrict__ aidx, const unsigned short* __restrict__ Wct,
  const float* __restrict__ bc, float* __restrict__ out)
{
  __shared__ unsigned short Kl[64][136];   // 64 keys x 128ch
  __shared__ unsigned short Vl[128][72];   // 128 ch x 64 keys
  __shared__ short Pl[4][16][72];          // per-wave P tile
  __shared__ short Al[4][16][136];         // per-wave accumulator (bf16) for projection
  const int tid=threadIdx.x, wv=tid>>6, lane=tid&63, l15=lane&15, quad=lane>>4;
  const int t = blockIdx.y;
  const int na = nact[t];
  const int qblk = blockIdx.x*64;
  if(qblk >= na) return;                 // block-uniform exit (before any barrier)
  const int qbase = qblk + wv*16;
  const float scale = 0.088388347648318447f;  // 1/sqrt(128)
  const int nkt = (na + 63) >> 6;

  short8 bq[4];
  #pragma unroll
  for(int kk=0;kk<4;kk++)
    bq[kk] = *(const short8*)(Q + ((size_t)t*MM + qbase + l15)*DH + kk*32 + quad*8);

  f32x4 zz = {0.f,0.f,0.f,0.f};
  f32x4 accPV[8];
  #pragma unroll
  for(int i=0;i<8;i++) accPV[i]=zz;
  float l_run = 0.f;

  const int srow = tid >> 2, sseg = tid & 3;   // K stage: 64 rows x 4 segs
  const int vch  = tid >> 1, vhalf = tid & 1;  // V stage: 128 ch x 2 halves

  short8 kreg[4], vreg[4];
  {  // preload tile 0 into registers
    const unsigned short* gk = Kc + ((size_t)t*MM + srow)*DH + sseg*32;
    const unsigned short* gv = Vtc + ((size_t)t*DH + vch)*MM + vhalf*32;
    #pragma unroll
    for(int j=0;j<4;j++){ kreg[j] = *(const short8*)(gk + j*8);
                          vreg[j] = *(const short8*)(gv + j*8); }
  }

  for(int kt=0; kt<nkt; kt++){
    const int key0 = kt*64;
    __syncthreads();   // previous tile fully consumed before restage
    {  // write prefetched registers to LDS
      short8* kd = (short8*)&Kl[srow][sseg*32];
      short8* vd = (short8*)&Vl[vch][vhalf*32];
      #pragma unroll
      for(int j=0;j<4;j++){ kd[j] = kreg[j]; vd[j] = vreg[j]; }
    }
    __syncthreads();
    if(kt+1 < nkt){   // issue next tile's global loads; they overlap compute below
      const int key1 = key0 + 64;
      const unsigned short* gk = Kc + ((size_t)t*MM + key1 + srow)*DH + sseg*32;
      const unsigned short* gv = Vtc + ((size_t)t*DH + vch)*MM + key1 + vhalf*32;
      #pragma unroll
      for(int j=0;j<4;j++){ kreg[j] = *(const short8*)(gk + j*8);
                            vreg[j] = *(const short8*)(gv + j*8); }
    }
    // S^T = K · Q^T from LDS
    #pragma unroll
    for(int mt=0;mt<4;mt++){
      f32x4 s = zz;
      #pragma unroll
      for(int kk=0;kk<4;kk++){
        short8 ak = *(const short8*)&Kl[mt*16+l15][kk*32 + quad*8];
        s = MFMA(ak, bq[kk], s);
      }
      short4v pk;
      #pragma unroll
      for(int r=0;r<4;r++){
        float sv = fminf(fmaxf(s[r]*scale, -15.f), 15.f);
        float valid = (key0 + mt*16 + quad*4 + r < na) ? 1.f : 0.f;
        float p = __expf(sv) * valid;
        pk[r] = (short)f2bf(p);
        l_run += bf2f((unsigned short)pk[r]);
      }
      *(short4v*)&Pl[wv][l15][mt*16 + quad*4] = pk;
    }
    // PV from LDS
    #pragma unroll
    for(int kk=0;kk<2;kk++){
      short8 ap = *(const short8*)&Pl[wv][l15][kk*32 + quad*8];
      #pragma unroll
      for(int nt=0;nt<8;nt++){
        short8 bv = *(const short8*)&Vl[nt*16+l15][kk*32 + quad*8];
        accPV[nt] = MFMA(ap, bv, accPV[nt]);
      }
    }
  }
  l_run += __shfl_xor(l_run, 16, 64);
  l_run += __shfl_xor(l_run, 32, 64);

  // per-wave projection (Al slice is wave-private; no cross-wave barrier needed)
  #pragma unroll
  for(int nt=0;nt<8;nt++)
    #pragma unroll
    for(int r=0;r<4;r++){
      float av = fminf(fmaxf(accPV[nt][r], -1e30f), 1e30f);
      Al[wv][quad*4+r][nt*16+l15] = (short)f2bf(av);
    }

  const int qc = qbase + l15;
  const bool qok = (qc < na);                // predicate loads of aidx + stores only
  const float linv = (l_run > 0.f) ? 1.f/l_run : 0.f;
  const int node = aidx[(size_t)t*MM + (qok ? qc : 0)];
  #pragma unroll
  for(int mt2=0;mt2<2;mt2++){
    f32x4 d = zz;
    #pragma unroll
    for(int kk=0;kk<4;kk++){
      short8 aw = *(const short8*)(Wct + (size_t)(mt2*16+l15)*DH + kk*32 + quad*8);
      short8 bl = *(const short8*)&Al[wv][l15][kk*32 + quad*8];
      d = MFMA(aw, bl, d);
    }
    f32x4 bcv = *(const f32x4*)(bc + mt2*16 + quad*4);
    f32x4 o4;
    #pragma unroll
    for(int r=0;r<4;r++) o4[r] = d[r]*linv + bcv[r];
    if(qok)
      *(f32x4*)(out + (size_t)node*(TT*DOUT) + (size_t)t*DOUT + mt2*16 + quad*4) = o4;
  }
}

// ================= launch: 7 kernels =================

extern "C" void kernel_launch(void* const* d_in, const int* in_sizes, int n_in,
                              void* d_out, int out_size, void* d_ws, size_t ws_size,
                              hipStream_t stream)
{
  float* outp = (float*)d_out;   // reference output dtype is float32
  static const int EXP[19] = {1572864,50331648,24576,8192,128,16384,128,16,16,
                              18432,128,18432,128,18432,128,16384,128,4096,32};
  bool ok = (n_in >= 19) && (out_size == OUTSZ);
  if(ok) for(int i=0;i<19;i++) if(in_sizes[i] != EXP[i]) { ok = false; break; }
  if(!ok){
    k_fill<<<(out_size+255)/256,256,0,stream>>>(outp, out_size, 1000.f);
    return;
  }
  const void* x   = d_in[0];
  const void* A   = d_in[1];
  const void* eg  = d_in[2];
  const void* w1  = d_in[3];
  const void* b1  = d_in[4];
  const void* w2  = d_in[5];
  const void* b2  = d_in[6];
  const void* tw  = d_in[7];
  const void* tb  = d_in[8];
  const void* qw  = d_in[9];
  const void* qb0 = d_in[10];
  const void* kw  = d_in[11];
  const void* kb0 = d_in[12];
  const void* vw  = d_in[13];
  const void* vb0 = d_in[14];
  const void* ow  = d_in[15];
  const void* ob  = d_in[16];
  const void* fw  = d_in[17];
  const void* fb  = d_in[18];

  char* w = (char*)d_ws;
  size_t off = 0;
  auto alloc = [&](size_t sz)->char*{
    char* p = w + off; off = (off + sz + 255) & ~(size_t)255; return p; };
  int*   dtf   = (int*)  alloc(4);
  int*   nactb = (int*)  alloc(TT*4);
  int*   cnt   = (int*)  alloc((size_t)TM*4);
  int*   aidx  = (int*)  alloc((size_t)TM*4);
  int*   inv   = (int*)  alloc((size_t)TM*4);
  int*   edges = (int*)  alloc((size_t)TM*CAP*4);
  float* g     = (float*)alloc((size_t)TM*DH*4);   // reused as Qb+Kb after 2nd gather
  unsigned short* h   = (unsigned short*)alloc((size_t)TM*DH*2);
  unsigned short* Vtc = (unsigned short*)alloc((size_t)TT*DH*MM*2);
  unsigned short* W2t = (unsigned short*)alloc(DH*DH*2);
  unsigned short* Wqt = (unsigned short*)alloc(DH*DH*2);
  unsigned short* Wkt = (unsigned short*)alloc(DH*DH*2);
  unsigned short* Wvt = (unsigned short*)alloc(DH*DH*2);
  unsigned short* Wct = (unsigned short*)alloc(DOUT*DH*2);
  float* qbf = (float*)alloc(TT*DH*4);
  float* kbf = (float*)alloc(TT*DH*4);
  float* vbf = (float*)alloc(TT*DH*4);
  float* bcf = (float*)alloc(DOUT*4);
  float* b1f = (float*)alloc(DH*4);
  float* b2f = (float*)alloc(DH*4);
  if(off > ws_size){
    k_fill<<<(out_size+255)/256,256,0,stream>>>(outp, out_size, 500.f);
    return;
  }

  unsigned short* Qb = (unsigned short*)g;                       // TM*DH*2 bytes
  unsigned short* Kb = (unsigned short*)((char*)g + (size_t)TM*DH*2);

  // L1: mask (deterministic per-t compaction) + x dtype detect + out zero
  k_maskdet<<<OUTSZ/256,256,0,stream>>>(eg, (const unsigned short*)x, dtf,
                                        cnt, nactb, aidx, inv, outp);
  // L2: weight prep + COALESCED edge build + gemm_x (direct w1 reads), one launch
  k_pex<<<PWB + TM*64/256 + TM/64,256,0,stream>>>(
      x, A, w1, w2, qw, kw, vw, qb0, kb0, vb0, ow, ob, fw, fb, tw, tb, b1, b2,
      dtf, inv, cnt, edges, nactb, aidx, g,
      W2t, Wqt, Wkt, Wvt, Wct, qbf, kbf, vbf, bcf, b1f, b2f);
  // L3..L6: GCN + QKV
  k_gather<<<TM/4,256,0,stream>>>(g, edges, cnt, nactb, b1f, h);
  k_gemm_h<<<TM/64,256,0,stream>>>(h, W2t, g, nactb);
  k_gather<<<TM/4,256,0,stream>>>(g, edges, cnt, nactb, b2f, h);
  k_gemm_qkv<<<dim3(TM/64,1,3),256,0,stream>>>(h, Wqt,Wkt,Wvt, qbf,kbf,vbf, Qb,Kb,Vtc, nactb);
  // L7: single-pass fused attention + projection
  k_attn<<<dim3(MM/64,TT),256,0,stream>>>(Qb, Kb, Vtc, nactb, aidx, Wct, bcf, outp);
}